// Round 10
// baseline (1065.577 us; speedup 1.0000x reference)
//
#include <hip/hip_runtime.h>

#define NN 100000
#define NE 1600000
#define D 32

typedef short short8 __attribute__((ext_vector_type(8)));
typedef float f32x4 __attribute__((ext_vector_type(4)));

union ABfrag { int4 i; short8 s; };

// ---------------- bf16 helpers ----------------

__device__ inline unsigned short f2b(float f) {
  unsigned int u = __float_as_uint(f);
  u = (u + 0x7FFFu + ((u >> 16) & 1u)) >> 16;
  return (unsigned short)u;
}
__device__ inline float b2f(unsigned short s) {
  return __uint_as_float(((unsigned int)s) << 16);
}
__device__ inline unsigned cvt_pk_bf16(float lo, float hi) {
  unsigned r;
  asm("v_cvt_pk_bf16_f32 %0, %1, %2" : "=v"(r) : "v"(lo), "v"(hi));
  return r;
}
__device__ inline void splitw(float w, unsigned short& h, unsigned short& l) {
  h = f2b(w);
  l = f2b(w - b2f(h));
}

// ============================ CSR build ============================

__global__ void k_deg(const int* __restrict__ dst, int* __restrict__ cnt) {
  int i = blockIdx.x * blockDim.x + threadIdx.x;
  int stride = gridDim.x * blockDim.x;
  for (int e = i; e < NE; e += stride) atomicAdd(&cnt[dst[e]], 1);
}

__global__ void k_invdeg(const int* __restrict__ cnt, float* __restrict__ inv) {
  int v = blockIdx.x * blockDim.x + threadIdx.x;
  if (v < NN) inv[v] = 1.0f / (float)max(cnt[v], 1);
}

__global__ __launch_bounds__(1024) void k_scanA(const int* __restrict__ cnt,
                                                int* __restrict__ rowptr,
                                                int* __restrict__ partial) {
  __shared__ int lds[1024];
  int t = threadIdx.x;
  int i = blockIdx.x * 1024 + t;
  int v = (i < NN) ? cnt[i] : 0;
  lds[t] = v;
  __syncthreads();
  for (int off = 1; off < 1024; off <<= 1) {
    int add = (t >= off) ? lds[t - off] : 0;
    __syncthreads();
    lds[t] += add;
    __syncthreads();
  }
  if (i < NN) rowptr[i] = lds[t] - v;
  if (t == 1023) partial[blockIdx.x] = lds[1023];
}

__global__ __launch_bounds__(128) void k_scanB(int* __restrict__ partial, int nb) {
  __shared__ int s[128];
  int t = threadIdx.x;
  int v = (t < nb) ? partial[t] : 0;
  s[t] = v;
  __syncthreads();
  for (int off = 1; off < 128; off <<= 1) {
    int add = (t >= off) ? s[t - off] : 0;
    __syncthreads();
    s[t] += add;
    __syncthreads();
  }
  if (t < nb) partial[t] = s[t] - v;  // exclusive
}

__global__ __launch_bounds__(1024) void k_scanC(int* __restrict__ rowptr,
                                                const int* __restrict__ partial) {
  int t = threadIdx.x;
  int i = blockIdx.x * 1024 + t;
  if (i < NN) rowptr[i] += partial[blockIdx.x];
  if (i == 0) rowptr[NN] = NE;
}

// phase A: scatter only perm (4B); inv_p coalesced by e
__global__ void k_fillA(const int* __restrict__ dst, const int* __restrict__ rowptr,
                        int* __restrict__ fill, int* __restrict__ perm,
                        int* __restrict__ inv_p) {
  int i = blockIdx.x * blockDim.x + threadIdx.x;
  int stride = gridDim.x * blockDim.x;
  for (int e = i; e < NE; e += stride) {
    int d = dst[e];
    int slot = atomicAdd(&fill[d], 1);
    int p = rowptr[d] + slot;
    perm[p] = e;
    inv_p[e] = p;
  }
}

// phase B: coalesced writes; scattered READS (L2/L3-absorbed)
__global__ void k_fillB(const int* __restrict__ perm, const int* __restrict__ src,
                        const int* __restrict__ dst, const float* __restrict__ ea,
                        int* __restrict__ src_p, int* __restrict__ dst_p,
                        float4* __restrict__ ea4) {
  int i = blockIdx.x * blockDim.x + threadIdx.x;
  int stride = gridDim.x * blockDim.x;
  for (int p = i; p < NE; p += stride) {
    int e = perm[p];
    src_p[p] = src[e];
    dst_p[p] = dst[e];
    ea4[p] = make_float4(ea[(size_t)e * 3 + 0], ea[(size_t)e * 3 + 1],
                         ea[(size_t)e * 3 + 2], 0.f);
  }
}

// ============================ VALU dot helper (node kernels) ============================

template <int K4>
__device__ inline float dot_lds(const float* __restrict__ lv, const float* __restrict__ Wc) {
  float acc = 0.f;
  const float4* v4 = (const float4*)lv;
#pragma unroll
  for (int kk = 0; kk < K4; kk++) {
    float4 h = v4[kk];
    acc = fmaf(h.x, Wc[4 * kk + 0], acc);
    acc = fmaf(h.y, Wc[4 * kk + 1], acc);
    acc = fmaf(h.z, Wc[4 * kk + 2], acc);
    acc = fmaf(h.w, Wc[4 * kk + 3], acc);
  }
  return acc;
}

// ============ node encoder + Q0 projection (Q0 interleaved: [v*32 + ch*2 + half]) ============

__global__ __launch_bounds__(256) void k_node_enc_fin(
    const float* __restrict__ x,
    const float* __restrict__ ws, const float* __restrict__ bs,
    const float* __restrict__ wh, const float* __restrict__ bh,
    const float* __restrict__ we, const float* __restrict__ be,
    const float* __restrict__ Wn,  // w_node_s, rows 0..31
    float* __restrict__ Q0) {
  __shared__ float hrow[8][D];
  int t = threadIdx.x, j = t & 31, g = t >> 5;
  float Ws = ws[j], Bs = bs[j], Bh = bh[j], Be = be[j];
  float Wh[D], We_[D], Wq[D];
#pragma unroll
  for (int k = 0; k < D; k++) {
    Wh[k] = wh[k * D + j];
    We_[k] = we[k * D + j];
    Wq[k] = Wn[k * D + j];
  }
  int qidx = (j & 15) * 2 + (j >> 4);
  for (int v = blockIdx.x * 8 + g; v < NN; v += gridDim.x * 8) {
    float h = fmaxf(fmaf(x[v], Ws, Bs), 0.f);
#pragma unroll
    for (int L = 0; L < 2; L++) {
      hrow[g][j] = h;
      h = fmaxf(dot_lds<8>(hrow[g], Wh) + Bh, 0.f);
    }
    hrow[g][j] = h;
    h = fmaxf(dot_lds<8>(hrow[g], We_) + Be, 0.f);
    hrow[g][j] = h;
    Q0[(size_t)v * 32 + qidx] = dot_lds<8>(hrow[g], Wq);
  }
}

// ==== node finalize: h = acc/deg; project P2/Q (float4-packed R2) and P3 (float2-packed) ====

__global__ __launch_bounds__(256) void k_fin(
    float* __restrict__ acc, const float* __restrict__ inv_deg,
    const float* __restrict__ We,  // [96][32] NEXT edge layer (rows 32..95 used)
    const float* __restrict__ Wn,  // [64][32] NEXT node msg (rows 0..31 used)
    float2* __restrict__ R2,       // [NN*32] float2: (p2,q) at [v*32 + ch*2 + half]
    float* __restrict__ P3out) {   // [NN*32] float: p3 at [v*32 + ch*2 + half]
  __shared__ float hrow[8][D];
  int t = threadIdx.x, j = t & 31, g = t >> 5;
  float Wp2[D], Wp3[D], Wq[D];
#pragma unroll
  for (int k = 0; k < D; k++) {
    Wp2[k] = We[(32 + k) * D + j];
    Wp3[k] = We[(64 + k) * D + j];
    Wq[k] = Wn[k * D + j];
  }
  int qidx = (j & 15) * 2 + (j >> 4);
  for (int v = blockIdx.x * 8 + g; v < NN; v += gridDim.x * 8) {
    float h = acc[(size_t)v * D + j] * inv_deg[v];
    acc[(size_t)v * D + j] = 0.f;
    hrow[g][j] = h;
    float p2 = dot_lds<8>(hrow[g], Wp2);
    float q = dot_lds<8>(hrow[g], Wq);
    float p3 = dot_lds<8>(hrow[g], Wp3);
    R2[(size_t)v * 32 + qidx] = make_float2(p2, q);
    P3out[(size_t)v * 32 + qidx] = p3;
  }
}

// ==== final node finalize: P2f/P3f [NN,3] ====

__global__ __launch_bounds__(256) void k_fin4(
    float* __restrict__ acc, const float* __restrict__ inv_deg,
    const float* __restrict__ We,  // w_edge_e [96][3]
    float* __restrict__ P2f, float* __restrict__ P3f) {
  __shared__ float hrow[8][D];
  int t = threadIdx.x, j = t & 31, g = t >> 5;
  for (int v = blockIdx.x * 8 + g; v < NN; v += gridDim.x * 8) {
    float h = acc[(size_t)v * D + j] * inv_deg[v];
    hrow[g][j] = h;
    if (j < 6) {
      int c = j % 3;
      int off = (j < 3) ? 32 : 64;
      float s = 0.f;
#pragma unroll
      for (int k = 0; k < D; k++) s = fmaf(hrow[g][k], We[(off + k) * 3 + c], s);
      if (j < 3) P2f[(size_t)v * 3 + c] = s;
      else       P3f[(size_t)v * 3 + c] = s;
    }
  }
}

// ============================ MFMA helpers ============================
// D layout (mfma_f32_16x16x32_bf16): col = lane&15, row = (lane>>4)*4 + reg
// A layout: row = lane&15, k = (lane>>4)*8 + i ;  B layout: col = lane&15, k = (lane>>4)*8 + i
// h_edge stores channels interleaved: position 2*c+h <-> channel c + 16*h (c=0..15)

__device__ inline void ep_xpose_write(float* __restrict__ xw, f32x4 da, f32x4 db,
                                      float ba, float bb, int cl, int ch) {
#pragma unroll
  for (int r = 0; r < 4; r++) {
    xw[(cl * 4 + r) * 36 + ch] = fmaxf(da[r] + ba, 0.f);
    xw[(cl * 4 + r) * 36 + ch + 16] = fmaxf(db[r] + bb, 0.f);
  }
}

__device__ inline ABfrag xpose_read(const float* __restrict__ xw, int lane) {
  const float4* p = (const float4*)(xw + (lane & 15) * 36 + (lane >> 4) * 8);
  float4 v0 = p[0], v1 = p[1];
  ABfrag A;
  A.i = make_int4(cvt_pk_bf16(v0.x, v0.y), cvt_pk_bf16(v0.z, v0.w),
                  cvt_pk_bf16(v1.x, v1.y), cvt_pk_bf16(v1.z, v1.w));
  return A;
}

// gather bundle for one 16-edge tile (packed R2 float4 + P3 float2)
struct G8 { float4 r2[4]; float2 p3[4]; };

__device__ inline void gath(G8& g, const float4* __restrict__ R2,
                            const float2* __restrict__ P3, int4 sv, int4 dv, int ch) {
  int sa[4] = {sv.x, sv.y, sv.z, sv.w};
  int da[4] = {dv.x, dv.y, dv.z, dv.w};
#pragma unroll
  for (int r = 0; r < 4; r++) {
    g.r2[r] = R2[(size_t)sa[r] * 16 + ch];   // (p2_lo, q_lo, p2_hi, q_hi)
    g.p3[r] = P3[(size_t)da[r] * 16 + ch];   // (p3_lo, p3_hi)
  }
}

// ==== MFMA fused: edge encoder + first message + scatter ====

__global__ __launch_bounds__(256) void k_fe0_m(
    const float4* __restrict__ ea4, const float2* __restrict__ Q0,
    const int* __restrict__ src_p, const int* __restrict__ dst_p,
    float* __restrict__ acc,
    const float* __restrict__ ws, const float* __restrict__ bs,
    const float* __restrict__ wh, const float* __restrict__ bh,
    const float* __restrict__ we, const float* __restrict__ be,
    const float* __restrict__ Wn,  // w_node_s rows 32..63
    unsigned int* __restrict__ h_edge) {  // packed interleaved bf16 pairs
  __shared__ float xp[4][16 * 36];
  int lane = threadIdx.x & 63, wid = threadIdx.x >> 6;
  int cl = lane >> 4, ch = lane & 15;
  // layer-1 weights packed bf16x2
  unsigned wp01[8], wp2b[8];
#pragma unroll
  for (int kk = 0; kk < 8; kk++) {
    int c = cl * 8 + kk;
    wp01[kk] = ((unsigned)f2b(ws[32 + c]) << 16) | f2b(ws[c]);
    wp2b[kk] = ((unsigned)f2b(bs[c]) << 16) | f2b(ws[64 + c]);
  }
  ABfrag wha, whb, wea, web, w2a, w2b;
#pragma unroll
  for (int kk = 0; kk < 8; kk++) {
    int k = cl * 8 + kk;
    wha.s[kk] = (short)f2b(wh[k * 32 + ch]);
    whb.s[kk] = (short)f2b(wh[k * 32 + ch + 16]);
    wea.s[kk] = (short)f2b(we[k * 32 + ch]);
    web.s[kk] = (short)f2b(we[k * 32 + ch + 16]);
    w2a.s[kk] = (short)f2b(Wn[(32 + k) * 32 + ch]);
    w2b.s[kk] = (short)f2b(Wn[(32 + k) * 32 + ch + 16]);
  }
  float bha = bh[ch], bhb = bh[ch + 16], bea = be[ch], beb = be[ch + 16];
  int p0 = (blockIdx.x * 4 + wid) * 64;
  f32x4 z = {0.f, 0.f, 0.f, 0.f};
  float* xw = xp[wid];
#pragma unroll
  for (int t = 0; t < 4; ++t) {
    int pb = p0 + t * 16;
    float4 av = ea4[pb + ch];
    int4 sv = *(const int4*)(src_p + pb + cl * 4);
    int4 dv = *(const int4*)(dst_p + pb + cl * 4);
    float h1[8];
#pragma unroll
    for (int kk = 0; kk < 8; kk++) {
      float w0 = b2f((unsigned short)(wp01[kk] & 0xFFFFu));
      float w1 = b2f((unsigned short)(wp01[kk] >> 16));
      float w2 = b2f((unsigned short)(wp2b[kk] & 0xFFFFu));
      float bb = b2f((unsigned short)(wp2b[kk] >> 16));
      h1[kk] = fmaxf(fmaf(av.x, w0, fmaf(av.y, w1, fmaf(av.z, w2, bb))), 0.f);
    }
    ABfrag A;
    A.i = make_int4(cvt_pk_bf16(h1[0], h1[1]), cvt_pk_bf16(h1[2], h1[3]),
                    cvt_pk_bf16(h1[4], h1[5]), cvt_pk_bf16(h1[6], h1[7]));
    f32x4 da = __builtin_amdgcn_mfma_f32_16x16x32_bf16(A.s, wha.s, z, 0, 0, 0);
    f32x4 db = __builtin_amdgcn_mfma_f32_16x16x32_bf16(A.s, whb.s, z, 0, 0, 0);
    ep_xpose_write(xw, da, db, bha, bhb, cl, ch);
    A = xpose_read(xw, lane);
    da = __builtin_amdgcn_mfma_f32_16x16x32_bf16(A.s, wha.s, z, 0, 0, 0);
    db = __builtin_amdgcn_mfma_f32_16x16x32_bf16(A.s, whb.s, z, 0, 0, 0);
    ep_xpose_write(xw, da, db, bha, bhb, cl, ch);
    A = xpose_read(xw, lane);
    da = __builtin_amdgcn_mfma_f32_16x16x32_bf16(A.s, wea.s, z, 0, 0, 0);
    db = __builtin_amdgcn_mfma_f32_16x16x32_bf16(A.s, web.s, z, 0, 0, 0);
#pragma unroll
    for (int r = 0; r < 4; r++) {
      float h0 = fmaxf(da[r] + bea, 0.f);
      float hv = fmaxf(db[r] + beb, 0.f);
      int p = pb + cl * 4 + r;
      h_edge[(size_t)p * 16 + ch] = cvt_pk_bf16(h0, hv);  // one 4B store
      xw[(cl * 4 + r) * 36 + ch] = h0;
      xw[(cl * 4 + r) * 36 + ch + 16] = hv;
    }
    A = xpose_read(xw, lane);
    f32x4 ma = __builtin_amdgcn_mfma_f32_16x16x32_bf16(A.s, w2a.s, z, 0, 0, 0);
    f32x4 mb = __builtin_amdgcn_mfma_f32_16x16x32_bf16(A.s, w2b.s, z, 0, 0, 0);
    int sa[4] = {sv.x, sv.y, sv.z, sv.w};
    int dda[4] = {dv.x, dv.y, dv.z, dv.w};
    float va = 0.f, vb = 0.f;
    int cur = dda[0];
#pragma unroll
    for (int r = 0; r < 4; r++) {
      float2 qv = Q0[(size_t)sa[r] * 16 + ch];
      float xa = fmaxf(ma[r] + qv.x, 0.f);
      float xb = fmaxf(mb[r] + qv.y, 0.f);
      if (dda[r] != cur) {
        atomicAdd(&acc[(size_t)cur * 32 + ch], va);
        atomicAdd(&acc[(size_t)cur * 32 + ch + 16], vb);
        va = 0.f; vb = 0.f; cur = dda[r];
      }
      va += xa; vb += xb;
    }
    atomicAdd(&acc[(size_t)cur * 32 + ch], va);
    atomicAdd(&acc[(size_t)cur * 32 + ch + 16], vb);
  }
}

// ==== MFMA fused: edge update + message + scatter ====
// A-frag from interleaved h_edge: frag pos cl*8+kk holds channel kp = cl*4 + (kk>>1) + (kk&1)*16

template <int LAST>
__global__ __launch_bounds__(256) void k_fe_t(
    unsigned int* __restrict__ h_edge, const float4* __restrict__ R2,
    const float2* __restrict__ P3, const int* __restrict__ src_p,
    const int* __restrict__ dst_p, float* __restrict__ acc,
    const float* __restrict__ We, const float* __restrict__ be,
    const float* __restrict__ Wn, const float* __restrict__ We3,
    float* __restrict__ partialE) {
  __shared__ float xp[4][16 * 36];
  int lane = threadIdx.x & 63, wid = threadIdx.x >> 6;
  int cl = lane >> 4, ch = lane & 15;
  ABfrag b1a, b1b, b2a, b2b, w3h, w3l;
#pragma unroll
  for (int kk = 0; kk < 8; kk++) {
    int k = cl * 8 + kk;
    int kp = cl * 4 + (kk >> 1) + (kk & 1) * 16;  // interleaved h_edge k-perm
    b1a.s[kk] = (short)f2b(We[kp * 32 + ch]);
    b1b.s[kk] = (short)f2b(We[kp * 32 + ch + 16]);
    b2a.s[kk] = (short)f2b(Wn[(32 + k) * 32 + ch]);
    b2b.s[kk] = (short)f2b(Wn[(32 + k) * 32 + ch + 16]);
    if (LAST) {
      unsigned short hi_, lo_;
      float v = (ch < 3) ? We3[k * 3 + ch] : 0.f;
      splitw(v, hi_, lo_); w3h.s[kk] = (short)hi_; w3l.s[kk] = (short)lo_;
    }
  }
  float bea = be[ch], beb = be[ch + 16];
  int p0 = (blockIdx.x * 4 + wid) * 64;
  f32x4 z = {0.f, 0.f, 0.f, 0.f};
  float* xw = xp[wid];
#pragma unroll
  for (int t = 0; t < 4; ++t) {
    int pb = p0 + t * 16;
    ABfrag A;
    A.i = *(const int4*)(h_edge + (size_t)(pb + ch) * 16 + cl * 4);
    int4 sv = *(const int4*)(src_p + pb + cl * 4);
    int4 dv = *(const int4*)(dst_p + pb + cl * 4);
    G8 g;
    gath(g, R2, P3, sv, dv, ch);
    f32x4 da = __builtin_amdgcn_mfma_f32_16x16x32_bf16(A.s, b1a.s, z, 0, 0, 0);
    f32x4 db = __builtin_amdgcn_mfma_f32_16x16x32_bf16(A.s, b1b.s, z, 0, 0, 0);
#pragma unroll
    for (int r = 0; r < 4; r++) {
      float h0 = fmaxf(da[r] + g.r2[r].x + g.p3[r].x + bea, 0.f);
      float hv = fmaxf(db[r] + g.r2[r].z + g.p3[r].y + beb, 0.f);
      int p = pb + cl * 4 + r;
      if (!LAST) h_edge[(size_t)p * 16 + ch] = cvt_pk_bf16(h0, hv);
      xw[(cl * 4 + r) * 36 + ch] = h0;
      xw[(cl * 4 + r) * 36 + ch + 16] = hv;
    }
    ABfrag A2 = xpose_read(xw, lane);
    f32x4 ma = __builtin_amdgcn_mfma_f32_16x16x32_bf16(A2.s, b2a.s, z, 0, 0, 0);
    f32x4 mb = __builtin_amdgcn_mfma_f32_16x16x32_bf16(A2.s, b2b.s, z, 0, 0, 0);
    if (LAST) {
      f32x4 dc = __builtin_amdgcn_mfma_f32_16x16x32_bf16(A2.s, w3l.s, z, 0, 0, 0);
      dc = __builtin_amdgcn_mfma_f32_16x16x32_bf16(A2.s, w3h.s, dc, 0, 0, 0);
      if (ch < 3) {
#pragma unroll
        for (int r = 0; r < 4; r++)
          partialE[(size_t)(pb + cl * 4 + r) * 3 + ch] = dc[r];
      }
    }
    int dda[4] = {dv.x, dv.y, dv.z, dv.w};
    float va = 0.f, vb = 0.f;
    int cur = dda[0];
#pragma unroll
    for (int r = 0; r < 4; r++) {
      float xa = fmaxf(ma[r] + g.r2[r].y, 0.f);
      float xb = fmaxf(mb[r] + g.r2[r].w, 0.f);
      if (dda[r] != cur) {
        atomicAdd(&acc[(size_t)cur * 32 + ch], va);
        atomicAdd(&acc[(size_t)cur * 32 + ch + 16], vb);
        va = 0.f; vb = 0.f; cur = dda[r];
      }
      va += xa; vb += xb;
    }
    atomicAdd(&acc[(size_t)cur * 32 + ch], va);
    atomicAdd(&acc[(size_t)cur * 32 + ch + 16], vb);
  }
}

// ==== final: out[e] = ea[e] + partialE[inv[e]] + P2f[src[e]] + P3f[dst[e]] + b ====

__global__ __launch_bounds__(256) void k_fe4e(
    const float* __restrict__ partialE, const int* __restrict__ inv_p,
    const float* __restrict__ edge_attr, const int* __restrict__ src,
    const int* __restrict__ dstv, const float* __restrict__ P2f,
    const float* __restrict__ P3f, const float* __restrict__ be,
    float* __restrict__ out) {
  int e = blockIdx.x * blockDim.x + threadIdx.x;
  if (e >= NE) return;
  int p = inv_p[e];
  int s = src[e], d = dstv[e];
  float c0 = partialE[(size_t)p * 3 + 0];
  float c1 = partialE[(size_t)p * 3 + 1];
  float c2 = partialE[(size_t)p * 3 + 2];
  out[(size_t)e * 3 + 0] = edge_attr[(size_t)e * 3 + 0] + c0 + P2f[(size_t)s * 3 + 0] + P3f[(size_t)d * 3 + 0] + be[0];
  out[(size_t)e * 3 + 1] = edge_attr[(size_t)e * 3 + 1] + c1 + P2f[(size_t)s * 3 + 1] + P3f[(size_t)d * 3 + 1] + be[1];
  out[(size_t)e * 3 + 2] = edge_attr[(size_t)e * 3 + 2] + c2 + P2f[(size_t)s * 3 + 2] + P3f[(size_t)d * 3 + 2] + be[2];
}

// ============================ launch ============================

extern "C" void kernel_launch(void* const* d_in, const int* in_sizes, int n_in,
                              void* d_out, int out_size, void* d_ws, size_t ws_size,
                              hipStream_t stream) {
  const float* x = (const float*)d_in[0];
  const float* edge_attr = (const float*)d_in[1];
  const int* ei = (const int*)d_in[2];
  const int* src = ei;
  const int* dst = ei + NE;
  const float* w_enc_node_s = (const float*)d_in[3];
  const float* b_enc_node_s = (const float*)d_in[4];
  const float* w_enc_node_h = (const float*)d_in[5];
  const float* b_enc_node_h = (const float*)d_in[6];
  const float* w_enc_node_e = (const float*)d_in[7];
  const float* b_enc_node_e = (const float*)d_in[8];
  const float* w_enc_edge_s = (const float*)d_in[9];
  const float* b_enc_edge_s = (const float*)d_in[10];
  const float* w_enc_edge_h = (const float*)d_in[11];
  const float* b_enc_edge_h = (const float*)d_in[12];
  const float* w_enc_edge_e = (const float*)d_in[13];
  const float* b_enc_edge_e = (const float*)d_in[14];
  const float* w_node_s = (const float*)d_in[15];
  const float* w_node_h = (const float*)d_in[16];
  const float* w_node_e = (const float*)d_in[17];
  const float* w_edge_s = (const float*)d_in[18];
  const float* b_edge_s = (const float*)d_in[19];
  const float* w_edge_h = (const float*)d_in[20];
  const float* b_edge_h = (const float*)d_in[21];
  const float* w_edge_e = (const float*)d_in[22];
  const float* b_edge_e = (const float*)d_in[23];

  // workspace layout (~219 MB; 238 MB proven safe in round 1)
  char* w = (char*)d_ws;
  unsigned int* h_edge = (unsigned int*)w; w += (size_t)NE * 16 * 4;  // 102.4 MB (packed pairs)
  int* inv_p = (int*)w;       w += (size_t)NE * 4;            // 6.4
  int* src_p = (int*)w;       w += (size_t)NE * 4;            // 6.4
  int* dst_p = (int*)w;       w += (size_t)NE * 4;            // 6.4
  int* perm = (int*)w;        w += (size_t)NE * 4;            // 6.4
  float4* ea4 = (float4*)w;   w += (size_t)NE * 16;           // 25.6 (aliased by partialE later)
  float* acc = (float*)w;     w += (size_t)NN * D * 4;        // 12.8
  float4* R2 = (float4*)w;    w += (size_t)NN * 16 * 16;      // 25.6
  float* P3 = (float*)w;      w += (size_t)NN * D * 4;        // 12.8
  float* Q0 = (float*)w;      w += (size_t)NN * D * 4;        // 12.8
  float* P2f = P3;
  float* P3f = P3 + (size_t)NN * 3;
  int* cnt = (int*)w;         w += (size_t)NN * 4;
  float* inv_deg = (float*)w; w += (size_t)NN * 4;
  int* rowptr = (int*)w;      w += (size_t)(NN + 1) * 4;
  int* fill = (int*)w;        w += (size_t)NN * 4;
  int* partial = (int*)w;     w += 4096;
  float* partialE = (float*)ea4;  // alias: ea4 dead after k_fe0_m

  hipMemsetAsync(cnt, 0, (size_t)NN * 4, stream);
  hipMemsetAsync(fill, 0, (size_t)NN * 4, stream);
  hipMemsetAsync(acc, 0, (size_t)NN * D * 4, stream);

  k_deg<<<1024, 256, 0, stream>>>(dst, cnt);
  k_invdeg<<<(NN + 255) / 256, 256, 0, stream>>>(cnt, inv_deg);
  int nb = (NN + 1023) / 1024;  // 98
  k_scanA<<<nb, 1024, 0, stream>>>(cnt, rowptr, partial);
  k_scanB<<<1, 128, 0, stream>>>(partial, nb);
  k_scanC<<<nb, 1024, 0, stream>>>(rowptr, partial);
  k_fillA<<<1024, 256, 0, stream>>>(dst, rowptr, fill, perm, inv_p);
  k_fillB<<<2048, 256, 0, stream>>>(perm, src, dst, edge_attr, src_p, dst_p, ea4);

  k_node_enc_fin<<<1024, 256, 0, stream>>>(x, w_enc_node_s, b_enc_node_s,
                                           w_enc_node_h, b_enc_node_h,
                                           w_enc_node_e, b_enc_node_e,
                                           w_node_s, Q0);

  int feb = NE / 256;  // 6250 blocks: 4 waves x 64 edges

  k_fe0_m<<<feb, 256, 0, stream>>>(ea4, (const float2*)Q0, src_p, dst_p, acc,
                                   w_enc_edge_s, b_enc_edge_s,
                                   w_enc_edge_h, b_enc_edge_h,
                                   w_enc_edge_e, b_enc_edge_e,
                                   w_node_s, h_edge);
  k_fin<<<1024, 256, 0, stream>>>(acc, inv_deg, w_edge_s, w_node_h, (float2*)R2, P3);
  k_fe_t<0><<<feb, 256, 0, stream>>>(h_edge, R2, (const float2*)P3, src_p, dst_p, acc,
                                     w_edge_s, b_edge_s, w_node_h, nullptr, nullptr);
  k_fin<<<1024, 256, 0, stream>>>(acc, inv_deg, w_edge_h, w_node_h, (float2*)R2, P3);
  k_fe_t<0><<<feb, 256, 0, stream>>>(h_edge, R2, (const float2*)P3, src_p, dst_p, acc,
                                     w_edge_h, b_edge_h, w_node_h, nullptr, nullptr);
  k_fin<<<1024, 256, 0, stream>>>(acc, inv_deg, w_edge_h, w_node_e, (float2*)R2, P3);
  k_fe_t<1><<<feb, 256, 0, stream>>>(h_edge, R2, (const float2*)P3, src_p, dst_p, acc,
                                     w_edge_h, b_edge_h, w_node_e, w_edge_e, partialE);
  k_fin4<<<1024, 256, 0, stream>>>(acc, inv_deg, w_edge_e, P2f, P3f);
  k_fe4e<<<(NE + 255) / 256, 256, 0, stream>>>(partialE, inv_p, edge_attr, src, dst,
                                               P2f, P3f, b_edge_e, (float*)d_out);
}

// Round 11
// 937.230 us; speedup vs baseline: 1.1369x; 1.1369x over previous
//
#include <hip/hip_runtime.h>

#define NN 100000
#define NE 1600000
#define D 32

typedef short short8 __attribute__((ext_vector_type(8)));
typedef float f32x4 __attribute__((ext_vector_type(4)));

union ABfrag { int4 i; short8 s; };

// ---------------- bf16 helpers ----------------

__device__ inline unsigned short f2b(float f) {
  unsigned int u = __float_as_uint(f);
  u = (u + 0x7FFFu + ((u >> 16) & 1u)) >> 16;
  return (unsigned short)u;
}
__device__ inline float b2f(unsigned short s) {
  return __uint_as_float(((unsigned int)s) << 16);
}
__device__ inline unsigned cvt_pk_bf16(float lo, float hi) {
  unsigned r;
  asm("v_cvt_pk_bf16_f32 %0, %1, %2" : "=v"(r) : "v"(lo), "v"(hi));
  return r;
}
__device__ inline void splitw(float w, unsigned short& h, unsigned short& l) {
  h = f2b(w);
  l = f2b(w - b2f(h));
}
__device__ inline float unpk_lo(unsigned u) { return b2f((unsigned short)(u & 0xFFFFu)); }
__device__ inline float unpk_hi(unsigned u) { return b2f((unsigned short)(u >> 16)); }

// ============================ CSR build ============================

__global__ void k_deg(const int* __restrict__ dst, int* __restrict__ cnt) {
  int i = blockIdx.x * blockDim.x + threadIdx.x;
  int stride = gridDim.x * blockDim.x;
  for (int e = i; e < NE; e += stride) atomicAdd(&cnt[dst[e]], 1);
}

__global__ void k_invdeg(const int* __restrict__ cnt, float* __restrict__ inv) {
  int v = blockIdx.x * blockDim.x + threadIdx.x;
  if (v < NN) inv[v] = 1.0f / (float)max(cnt[v], 1);
}

__global__ __launch_bounds__(1024) void k_scanA(const int* __restrict__ cnt,
                                                int* __restrict__ rowptr,
                                                int* __restrict__ partial) {
  __shared__ int lds[1024];
  int t = threadIdx.x;
  int i = blockIdx.x * 1024 + t;
  int v = (i < NN) ? cnt[i] : 0;
  lds[t] = v;
  __syncthreads();
  for (int off = 1; off < 1024; off <<= 1) {
    int add = (t >= off) ? lds[t - off] : 0;
    __syncthreads();
    lds[t] += add;
    __syncthreads();
  }
  if (i < NN) rowptr[i] = lds[t] - v;
  if (t == 1023) partial[blockIdx.x] = lds[1023];
}

__global__ __launch_bounds__(128) void k_scanB(int* __restrict__ partial, int nb) {
  __shared__ int s[128];
  int t = threadIdx.x;
  int v = (t < nb) ? partial[t] : 0;
  s[t] = v;
  __syncthreads();
  for (int off = 1; off < 128; off <<= 1) {
    int add = (t >= off) ? s[t - off] : 0;
    __syncthreads();
    s[t] += add;
    __syncthreads();
  }
  if (t < nb) partial[t] = s[t] - v;  // exclusive
}

__global__ __launch_bounds__(1024) void k_scanC(int* __restrict__ rowptr,
                                                const int* __restrict__ partial) {
  int t = threadIdx.x;
  int i = blockIdx.x * 1024 + t;
  if (i < NN) rowptr[i] += partial[blockIdx.x];
  if (i == 0) rowptr[NN] = NE;
}

// phase A: scatter only perm (4B); inv_p coalesced by e
__global__ void k_fillA(const int* __restrict__ dst, const int* __restrict__ rowptr,
                        int* __restrict__ fill, int* __restrict__ perm,
                        int* __restrict__ inv_p) {
  int i = blockIdx.x * blockDim.x + threadIdx.x;
  int stride = gridDim.x * blockDim.x;
  for (int e = i; e < NE; e += stride) {
    int d = dst[e];
    int slot = atomicAdd(&fill[d], 1);
    int p = rowptr[d] + slot;
    perm[p] = e;
    inv_p[e] = p;
  }
}

// phase B: coalesced writes; scattered READS (L2/L3-absorbed)
__global__ void k_fillB(const int* __restrict__ perm, const int* __restrict__ src,
                        const int* __restrict__ dst, const float* __restrict__ ea,
                        int* __restrict__ src_p, int* __restrict__ dst_p,
                        float4* __restrict__ ea4) {
  int i = blockIdx.x * blockDim.x + threadIdx.x;
  int stride = gridDim.x * blockDim.x;
  for (int p = i; p < NE; p += stride) {
    int e = perm[p];
    src_p[p] = src[e];
    dst_p[p] = dst[e];
    ea4[p] = make_float4(ea[(size_t)e * 3 + 0], ea[(size_t)e * 3 + 1],
                         ea[(size_t)e * 3 + 2], 0.f);
  }
}

// ============================ VALU dot helper (node kernels) ============================

template <int K4>
__device__ inline float dot_lds(const float* __restrict__ lv, const float* __restrict__ Wc) {
  float acc = 0.f;
  const float4* v4 = (const float4*)lv;
#pragma unroll
  for (int kk = 0; kk < K4; kk++) {
    float4 h = v4[kk];
    acc = fmaf(h.x, Wc[4 * kk + 0], acc);
    acc = fmaf(h.y, Wc[4 * kk + 1], acc);
    acc = fmaf(h.z, Wc[4 * kk + 2], acc);
    acc = fmaf(h.w, Wc[4 * kk + 3], acc);
  }
  return acc;
}

// ============ node encoder + Q0 projection (packed bf16 pairs) ============

__global__ __launch_bounds__(256) void k_node_enc_fin(
    const float* __restrict__ x,
    const float* __restrict__ ws, const float* __restrict__ bs,
    const float* __restrict__ wh, const float* __restrict__ bh,
    const float* __restrict__ we, const float* __restrict__ be,
    const float* __restrict__ Wn,  // w_node_s, rows 0..31
    unsigned* __restrict__ Q0b) {  // [NN*16]: pk(q_ch, q_ch+16)
  __shared__ float hrow[8][D];
  int t = threadIdx.x, j = t & 31, g = t >> 5;
  float Ws = ws[j], Bs = bs[j], Bh = bh[j], Be = be[j];
  float Wh[D], We_[D], Wq[D];
#pragma unroll
  for (int k = 0; k < D; k++) {
    Wh[k] = wh[k * D + j];
    We_[k] = we[k * D + j];
    Wq[k] = Wn[k * D + j];
  }
  for (int v = blockIdx.x * 8 + g; v < NN; v += gridDim.x * 8) {
    float h = fmaxf(fmaf(x[v], Ws, Bs), 0.f);
#pragma unroll
    for (int L = 0; L < 2; L++) {
      hrow[g][j] = h;
      h = fmaxf(dot_lds<8>(hrow[g], Wh) + Bh, 0.f);
    }
    hrow[g][j] = h;
    h = fmaxf(dot_lds<8>(hrow[g], We_) + Be, 0.f);
    hrow[g][j] = h;
    float q = dot_lds<8>(hrow[g], Wq);
    hrow[g][j] = q;  // wave-sync staging (dot complete for all lanes)
    if (j < 16) Q0b[(size_t)v * 16 + j] = cvt_pk_bf16(hrow[g][j], hrow[g][j + 16]);
  }
}

// ==== node finalize: h = acc/deg; project P2/Q and P3, packed bf16 ====

__global__ __launch_bounds__(256) void k_fin(
    float* __restrict__ acc, const float* __restrict__ inv_deg,
    const float* __restrict__ We,  // [96][32] NEXT edge layer (rows 32..95 used)
    const float* __restrict__ Wn,  // [64][32] NEXT node msg (rows 0..31 used)
    uint2* __restrict__ R2b,       // [NN*16]: {pk(p2lo,qlo), pk(p2hi,qhi)}
    unsigned* __restrict__ P3b) {  // [NN*16]: pk(p3lo,p3hi)
  __shared__ float hrow[8][D];
  __shared__ float st[8][3][D];
  int t = threadIdx.x, j = t & 31, g = t >> 5;
  float Wp2[D], Wp3[D], Wq[D];
#pragma unroll
  for (int k = 0; k < D; k++) {
    Wp2[k] = We[(32 + k) * D + j];
    Wp3[k] = We[(64 + k) * D + j];
    Wq[k] = Wn[k * D + j];
  }
  for (int v = blockIdx.x * 8 + g; v < NN; v += gridDim.x * 8) {
    float h = acc[(size_t)v * D + j] * inv_deg[v];
    acc[(size_t)v * D + j] = 0.f;
    hrow[g][j] = h;
    float p2 = dot_lds<8>(hrow[g], Wp2);
    float q = dot_lds<8>(hrow[g], Wq);
    float p3 = dot_lds<8>(hrow[g], Wp3);
    st[g][0][j] = p2; st[g][1][j] = q; st[g][2][j] = p3;
    if (j < 16) {
      R2b[(size_t)v * 16 + j] = make_uint2(cvt_pk_bf16(st[g][0][j], st[g][1][j]),
                                           cvt_pk_bf16(st[g][0][j + 16], st[g][1][j + 16]));
      P3b[(size_t)v * 16 + j] = cvt_pk_bf16(st[g][2][j], st[g][2][j + 16]);
    }
  }
}

// ==== final node finalize: P2f/P3f [NN,3] ====

__global__ __launch_bounds__(256) void k_fin4(
    float* __restrict__ acc, const float* __restrict__ inv_deg,
    const float* __restrict__ We,  // w_edge_e [96][3]
    float* __restrict__ P2f, float* __restrict__ P3f) {
  __shared__ float hrow[8][D];
  int t = threadIdx.x, j = t & 31, g = t >> 5;
  for (int v = blockIdx.x * 8 + g; v < NN; v += gridDim.x * 8) {
    float h = acc[(size_t)v * D + j] * inv_deg[v];
    hrow[g][j] = h;
    if (j < 6) {
      int c = j % 3;
      int off = (j < 3) ? 32 : 64;
      float s = 0.f;
#pragma unroll
      for (int k = 0; k < D; k++) s = fmaf(hrow[g][k], We[(off + k) * 3 + c], s);
      if (j < 3) P2f[(size_t)v * 3 + c] = s;
      else       P3f[(size_t)v * 3 + c] = s;
    }
  }
}

// ============================ MFMA helpers ============================
// D layout (mfma_f32_16x16x32_bf16): col = lane&15, row = (lane>>4)*4 + reg
// A layout: row = lane&15, k = (lane>>4)*8 + i ;  B layout: col = lane&15, k = (lane>>4)*8 + i
// h_edge stores channels interleaved: position 2*c+h <-> channel c + 16*h (c=0..15)

__device__ inline void ep_xpose_write(float* __restrict__ xw, f32x4 da, f32x4 db,
                                      float ba, float bb, int cl, int ch) {
#pragma unroll
  for (int r = 0; r < 4; r++) {
    xw[(cl * 4 + r) * 36 + ch] = fmaxf(da[r] + ba, 0.f);
    xw[(cl * 4 + r) * 36 + ch + 16] = fmaxf(db[r] + bb, 0.f);
  }
}

__device__ inline ABfrag xpose_read(const float* __restrict__ xw, int lane) {
  const float4* p = (const float4*)(xw + (lane & 15) * 36 + (lane >> 4) * 8);
  float4 v0 = p[0], v1 = p[1];
  ABfrag A;
  A.i = make_int4(cvt_pk_bf16(v0.x, v0.y), cvt_pk_bf16(v0.z, v0.w),
                  cvt_pk_bf16(v1.x, v1.y), cvt_pk_bf16(v1.z, v1.w));
  return A;
}

// gather bundle for one 16-edge tile (packed bf16 node rows)
struct G8 { uint2 r2[4]; unsigned p3[4]; };

__device__ inline void gath(G8& g, const uint2* __restrict__ R2b,
                            const unsigned* __restrict__ P3b, int4 sv, int4 dv, int ch) {
  int sa[4] = {sv.x, sv.y, sv.z, sv.w};
  int da[4] = {dv.x, dv.y, dv.z, dv.w};
#pragma unroll
  for (int r = 0; r < 4; r++) {
    g.r2[r] = R2b[(size_t)sa[r] * 16 + ch];
    g.p3[r] = P3b[(size_t)da[r] * 16 + ch];
  }
}

// ==== MFMA fused: edge encoder + first message + scatter ====

__global__ __launch_bounds__(256) void k_fe0_m(
    const float4* __restrict__ ea4, const unsigned* __restrict__ Q0b,
    const int* __restrict__ src_p, const int* __restrict__ dst_p,
    float* __restrict__ acc,
    const float* __restrict__ ws, const float* __restrict__ bs,
    const float* __restrict__ wh, const float* __restrict__ bh,
    const float* __restrict__ we, const float* __restrict__ be,
    const float* __restrict__ Wn,  // w_node_s rows 32..63
    unsigned int* __restrict__ h_edge) {  // packed interleaved bf16 pairs
  __shared__ float xp[4][16 * 36];
  int lane = threadIdx.x & 63, wid = threadIdx.x >> 6;
  int cl = lane >> 4, ch = lane & 15;
  unsigned wp01[8], wp2b[8];
#pragma unroll
  for (int kk = 0; kk < 8; kk++) {
    int c = cl * 8 + kk;
    wp01[kk] = ((unsigned)f2b(ws[32 + c]) << 16) | f2b(ws[c]);
    wp2b[kk] = ((unsigned)f2b(bs[c]) << 16) | f2b(ws[64 + c]);
  }
  ABfrag wha, whb, wea, web, w2a, w2b;
#pragma unroll
  for (int kk = 0; kk < 8; kk++) {
    int k = cl * 8 + kk;
    wha.s[kk] = (short)f2b(wh[k * 32 + ch]);
    whb.s[kk] = (short)f2b(wh[k * 32 + ch + 16]);
    wea.s[kk] = (short)f2b(we[k * 32 + ch]);
    web.s[kk] = (short)f2b(we[k * 32 + ch + 16]);
    w2a.s[kk] = (short)f2b(Wn[(32 + k) * 32 + ch]);
    w2b.s[kk] = (short)f2b(Wn[(32 + k) * 32 + ch + 16]);
  }
  float bha = bh[ch], bhb = bh[ch + 16], bea = be[ch], beb = be[ch + 16];
  int p0 = (blockIdx.x * 4 + wid) * 64;
  f32x4 z = {0.f, 0.f, 0.f, 0.f};
  float* xw = xp[wid];
  // dst-run accumulator carried across ALL 4 tiles
  float va = 0.f, vb = 0.f;
  int cur = dst_p[p0 + cl * 4];
#pragma unroll
  for (int t = 0; t < 4; ++t) {
    int pb = p0 + t * 16;
    float4 av = ea4[pb + ch];
    int4 sv = *(const int4*)(src_p + pb + cl * 4);
    int4 dv = *(const int4*)(dst_p + pb + cl * 4);
    float h1[8];
#pragma unroll
    for (int kk = 0; kk < 8; kk++) {
      float w0 = unpk_lo(wp01[kk]), w1 = unpk_hi(wp01[kk]);
      float w2 = unpk_lo(wp2b[kk]), bb = unpk_hi(wp2b[kk]);
      h1[kk] = fmaxf(fmaf(av.x, w0, fmaf(av.y, w1, fmaf(av.z, w2, bb))), 0.f);
    }
    ABfrag A;
    A.i = make_int4(cvt_pk_bf16(h1[0], h1[1]), cvt_pk_bf16(h1[2], h1[3]),
                    cvt_pk_bf16(h1[4], h1[5]), cvt_pk_bf16(h1[6], h1[7]));
    f32x4 da = __builtin_amdgcn_mfma_f32_16x16x32_bf16(A.s, wha.s, z, 0, 0, 0);
    f32x4 db = __builtin_amdgcn_mfma_f32_16x16x32_bf16(A.s, whb.s, z, 0, 0, 0);
    ep_xpose_write(xw, da, db, bha, bhb, cl, ch);
    A = xpose_read(xw, lane);
    da = __builtin_amdgcn_mfma_f32_16x16x32_bf16(A.s, wha.s, z, 0, 0, 0);
    db = __builtin_amdgcn_mfma_f32_16x16x32_bf16(A.s, whb.s, z, 0, 0, 0);
    ep_xpose_write(xw, da, db, bha, bhb, cl, ch);
    A = xpose_read(xw, lane);
    da = __builtin_amdgcn_mfma_f32_16x16x32_bf16(A.s, wea.s, z, 0, 0, 0);
    db = __builtin_amdgcn_mfma_f32_16x16x32_bf16(A.s, web.s, z, 0, 0, 0);
#pragma unroll
    for (int r = 0; r < 4; r++) {
      float h0 = fmaxf(da[r] + bea, 0.f);
      float hv = fmaxf(db[r] + beb, 0.f);
      int p = pb + cl * 4 + r;
      h_edge[(size_t)p * 16 + ch] = cvt_pk_bf16(h0, hv);
      xw[(cl * 4 + r) * 36 + ch] = h0;
      xw[(cl * 4 + r) * 36 + ch + 16] = hv;
    }
    A = xpose_read(xw, lane);
    f32x4 ma = __builtin_amdgcn_mfma_f32_16x16x32_bf16(A.s, w2a.s, z, 0, 0, 0);
    f32x4 mb = __builtin_amdgcn_mfma_f32_16x16x32_bf16(A.s, w2b.s, z, 0, 0, 0);
    int sa[4] = {sv.x, sv.y, sv.z, sv.w};
    int dda[4] = {dv.x, dv.y, dv.z, dv.w};
#pragma unroll
    for (int r = 0; r < 4; r++) {
      unsigned qv = Q0b[(size_t)sa[r] * 16 + ch];
      float xa = fmaxf(ma[r] + unpk_lo(qv), 0.f);
      float xb = fmaxf(mb[r] + unpk_hi(qv), 0.f);
      if (dda[r] != cur) {
        atomicAdd(&acc[(size_t)cur * 32 + ch], va);
        atomicAdd(&acc[(size_t)cur * 32 + ch + 16], vb);
        va = 0.f; vb = 0.f; cur = dda[r];
      }
      va += xa; vb += xb;
    }
  }
  atomicAdd(&acc[(size_t)cur * 32 + ch], va);
  atomicAdd(&acc[(size_t)cur * 32 + ch + 16], vb);
}

// ==== MFMA fused: edge update + message + scatter ====
// A-frag from interleaved h_edge: frag pos cl*8+kk holds channel kp = cl*4 + (kk>>1) + (kk&1)*16

template <int LAST>
__global__ __launch_bounds__(256) void k_fe_t(
    unsigned int* __restrict__ h_edge, const uint2* __restrict__ R2b,
    const unsigned* __restrict__ P3b, const int* __restrict__ src_p,
    const int* __restrict__ dst_p, float* __restrict__ acc,
    const float* __restrict__ We, const float* __restrict__ be,
    const float* __restrict__ Wn, const float* __restrict__ We3,
    float* __restrict__ partialE) {
  __shared__ float xp[4][16 * 36];
  int lane = threadIdx.x & 63, wid = threadIdx.x >> 6;
  int cl = lane >> 4, ch = lane & 15;
  ABfrag b1a, b1b, b2a, b2b, w3h, w3l;
#pragma unroll
  for (int kk = 0; kk < 8; kk++) {
    int k = cl * 8 + kk;
    int kp = cl * 4 + (kk >> 1) + (kk & 1) * 16;  // interleaved h_edge k-perm
    b1a.s[kk] = (short)f2b(We[kp * 32 + ch]);
    b1b.s[kk] = (short)f2b(We[kp * 32 + ch + 16]);
    b2a.s[kk] = (short)f2b(Wn[(32 + k) * 32 + ch]);
    b2b.s[kk] = (short)f2b(Wn[(32 + k) * 32 + ch + 16]);
    if (LAST) {
      unsigned short hi_, lo_;
      float v = (ch < 3) ? We3[k * 3 + ch] : 0.f;
      splitw(v, hi_, lo_); w3h.s[kk] = (short)hi_; w3l.s[kk] = (short)lo_;
    }
  }
  float bea = be[ch], beb = be[ch + 16];
  int p0 = (blockIdx.x * 4 + wid) * 64;
  f32x4 z = {0.f, 0.f, 0.f, 0.f};
  float* xw = xp[wid];
  // dst-run accumulator carried across ALL 4 tiles
  float va = 0.f, vb = 0.f;
  int cur = dst_p[p0 + cl * 4];
#pragma unroll
  for (int t = 0; t < 4; ++t) {
    int pb = p0 + t * 16;
    ABfrag A;
    A.i = *(const int4*)(h_edge + (size_t)(pb + ch) * 16 + cl * 4);
    int4 sv = *(const int4*)(src_p + pb + cl * 4);
    int4 dv = *(const int4*)(dst_p + pb + cl * 4);
    G8 g;
    gath(g, R2b, P3b, sv, dv, ch);
    f32x4 da = __builtin_amdgcn_mfma_f32_16x16x32_bf16(A.s, b1a.s, z, 0, 0, 0);
    f32x4 db = __builtin_amdgcn_mfma_f32_16x16x32_bf16(A.s, b1b.s, z, 0, 0, 0);
#pragma unroll
    for (int r = 0; r < 4; r++) {
      float h0 = fmaxf(da[r] + unpk_lo(g.r2[r].x) + unpk_lo(g.p3[r]) + bea, 0.f);
      float hv = fmaxf(db[r] + unpk_lo(g.r2[r].y) + unpk_hi(g.p3[r]) + beb, 0.f);
      int p = pb + cl * 4 + r;
      if (!LAST) h_edge[(size_t)p * 16 + ch] = cvt_pk_bf16(h0, hv);
      xw[(cl * 4 + r) * 36 + ch] = h0;
      xw[(cl * 4 + r) * 36 + ch + 16] = hv;
    }
    ABfrag A2 = xpose_read(xw, lane);
    f32x4 ma = __builtin_amdgcn_mfma_f32_16x16x32_bf16(A2.s, b2a.s, z, 0, 0, 0);
    f32x4 mb = __builtin_amdgcn_mfma_f32_16x16x32_bf16(A2.s, b2b.s, z, 0, 0, 0);
    if (LAST) {
      f32x4 dc = __builtin_amdgcn_mfma_f32_16x16x32_bf16(A2.s, w3l.s, z, 0, 0, 0);
      dc = __builtin_amdgcn_mfma_f32_16x16x32_bf16(A2.s, w3h.s, dc, 0, 0, 0);
      if (ch < 3) {
#pragma unroll
        for (int r = 0; r < 4; r++)
          partialE[(size_t)(pb + cl * 4 + r) * 3 + ch] = dc[r];
      }
    }
    int dda[4] = {dv.x, dv.y, dv.z, dv.w};
#pragma unroll
    for (int r = 0; r < 4; r++) {
      float xa = fmaxf(ma[r] + unpk_hi(g.r2[r].x), 0.f);
      float xb = fmaxf(mb[r] + unpk_hi(g.r2[r].y), 0.f);
      if (dda[r] != cur) {
        atomicAdd(&acc[(size_t)cur * 32 + ch], va);
        atomicAdd(&acc[(size_t)cur * 32 + ch + 16], vb);
        va = 0.f; vb = 0.f; cur = dda[r];
      }
      va += xa; vb += xb;
    }
  }
  atomicAdd(&acc[(size_t)cur * 32 + ch], va);
  atomicAdd(&acc[(size_t)cur * 32 + ch + 16], vb);
}

// ==== final: out[e] = ea[e] + partialE[inv[e]] + P2f[src[e]] + P3f[dst[e]] + b ====

__global__ __launch_bounds__(256) void k_fe4e(
    const float* __restrict__ partialE, const int* __restrict__ inv_p,
    const float* __restrict__ edge_attr, const int* __restrict__ src,
    const int* __restrict__ dstv, const float* __restrict__ P2f,
    const float* __restrict__ P3f, const float* __restrict__ be,
    float* __restrict__ out) {
  int e = blockIdx.x * blockDim.x + threadIdx.x;
  if (e >= NE) return;
  int p = inv_p[e];
  int s = src[e], d = dstv[e];
  float c0 = partialE[(size_t)p * 3 + 0];
  float c1 = partialE[(size_t)p * 3 + 1];
  float c2 = partialE[(size_t)p * 3 + 2];
  out[(size_t)e * 3 + 0] = edge_attr[(size_t)e * 3 + 0] + c0 + P2f[(size_t)s * 3 + 0] + P3f[(size_t)d * 3 + 0] + be[0];
  out[(size_t)e * 3 + 1] = edge_attr[(size_t)e * 3 + 1] + c1 + P2f[(size_t)s * 3 + 1] + P3f[(size_t)d * 3 + 1] + be[1];
  out[(size_t)e * 3 + 2] = edge_attr[(size_t)e * 3 + 2] + c2 + P2f[(size_t)s * 3 + 2] + P3f[(size_t)d * 3 + 2] + be[2];
}

// ============================ launch ============================

extern "C" void kernel_launch(void* const* d_in, const int* in_sizes, int n_in,
                              void* d_out, int out_size, void* d_ws, size_t ws_size,
                              hipStream_t stream) {
  const float* x = (const float*)d_in[0];
  const float* edge_attr = (const float*)d_in[1];
  const int* ei = (const int*)d_in[2];
  const int* src = ei;
  const int* dst = ei + NE;
  const float* w_enc_node_s = (const float*)d_in[3];
  const float* b_enc_node_s = (const float*)d_in[4];
  const float* w_enc_node_h = (const float*)d_in[5];
  const float* b_enc_node_h = (const float*)d_in[6];
  const float* w_enc_node_e = (const float*)d_in[7];
  const float* b_enc_node_e = (const float*)d_in[8];
  const float* w_enc_edge_s = (const float*)d_in[9];
  const float* b_enc_edge_s = (const float*)d_in[10];
  const float* w_enc_edge_h = (const float*)d_in[11];
  const float* b_enc_edge_h = (const float*)d_in[12];
  const float* w_enc_edge_e = (const float*)d_in[13];
  const float* b_enc_edge_e = (const float*)d_in[14];
  const float* w_node_s = (const float*)d_in[15];
  const float* w_node_h = (const float*)d_in[16];
  const float* w_node_e = (const float*)d_in[17];
  const float* w_edge_s = (const float*)d_in[18];
  const float* b_edge_s = (const float*)d_in[19];
  const float* w_edge_h = (const float*)d_in[20];
  const float* b_edge_h = (const float*)d_in[21];
  const float* w_edge_e = (const float*)d_in[22];
  const float* b_edge_e = (const float*)d_in[23];

  // workspace layout (~193 MB; 238 MB proven safe)
  char* w = (char*)d_ws;
  unsigned int* h_edge = (unsigned int*)w; w += (size_t)NE * 16 * 4;  // 102.4 MB
  int* inv_p = (int*)w;       w += (size_t)NE * 4;            // 6.4
  int* src_p = (int*)w;       w += (size_t)NE * 4;            // 6.4
  int* dst_p = (int*)w;       w += (size_t)NE * 4;            // 6.4
  int* perm = (int*)w;        w += (size_t)NE * 4;            // 6.4
  float4* ea4 = (float4*)w;   w += (size_t)NE * 16;           // 25.6 (aliased by partialE)
  float* acc = (float*)w;     w += (size_t)NN * D * 4;        // 12.8
  uint2* R2b = (uint2*)w;     w += (size_t)NN * 16 * 8;       // 12.8
  unsigned* P3b = (unsigned*)w; w += (size_t)NN * 16 * 4;     // 6.4 (aliased by P2f/P3f)
  unsigned* Q0b = (unsigned*)w; w += (size_t)NN * 16 * 4;     // 6.4
  float* P2f = (float*)P3b;
  float* P3f = (float*)P3b + (size_t)NN * 3;
  int* cnt = (int*)w;         w += (size_t)NN * 4;
  float* inv_deg = (float*)w; w += (size_t)NN * 4;
  int* rowptr = (int*)w;      w += (size_t)(NN + 1) * 4;
  int* fill = (int*)w;        w += (size_t)NN * 4;
  int* partial = (int*)w;     w += 4096;
  float* partialE = (float*)ea4;  // alias: ea4 dead after k_fe0_m

  hipMemsetAsync(cnt, 0, (size_t)NN * 4, stream);
  hipMemsetAsync(fill, 0, (size_t)NN * 4, stream);
  hipMemsetAsync(acc, 0, (size_t)NN * D * 4, stream);

  k_deg<<<1024, 256, 0, stream>>>(dst, cnt);
  k_invdeg<<<(NN + 255) / 256, 256, 0, stream>>>(cnt, inv_deg);
  int nb = (NN + 1023) / 1024;  // 98
  k_scanA<<<nb, 1024, 0, stream>>>(cnt, rowptr, partial);
  k_scanB<<<1, 128, 0, stream>>>(partial, nb);
  k_scanC<<<nb, 1024, 0, stream>>>(rowptr, partial);
  k_fillA<<<1024, 256, 0, stream>>>(dst, rowptr, fill, perm, inv_p);
  k_fillB<<<2048, 256, 0, stream>>>(perm, src, dst, edge_attr, src_p, dst_p, ea4);

  k_node_enc_fin<<<1024, 256, 0, stream>>>(x, w_enc_node_s, b_enc_node_s,
                                           w_enc_node_h, b_enc_node_h,
                                           w_enc_node_e, b_enc_node_e,
                                           w_node_s, Q0b);

  int feb = NE / 256;  // 6250 blocks: 4 waves x 64 edges

  k_fe0_m<<<feb, 256, 0, stream>>>(ea4, Q0b, src_p, dst_p, acc,
                                   w_enc_edge_s, b_enc_edge_s,
                                   w_enc_edge_h, b_enc_edge_h,
                                   w_enc_edge_e, b_enc_edge_e,
                                   w_node_s, h_edge);
  k_fin<<<1024, 256, 0, stream>>>(acc, inv_deg, w_edge_s, w_node_h, R2b, P3b);
  k_fe_t<0><<<feb, 256, 0, stream>>>(h_edge, R2b, P3b, src_p, dst_p, acc,
                                     w_edge_s, b_edge_s, w_node_h, nullptr, nullptr);
  k_fin<<<1024, 256, 0, stream>>>(acc, inv_deg, w_edge_h, w_node_h, R2b, P3b);
  k_fe_t<0><<<feb, 256, 0, stream>>>(h_edge, R2b, P3b, src_p, dst_p, acc,
                                     w_edge_h, b_edge_h, w_node_h, nullptr, nullptr);
  k_fin<<<1024, 256, 0, stream>>>(acc, inv_deg, w_edge_h, w_node_e, R2b, P3b);
  k_fe_t<1><<<feb, 256, 0, stream>>>(h_edge, R2b, P3b, src_p, dst_p, acc,
                                     w_edge_h, b_edge_h, w_node_e, w_edge_e, partialE);
  k_fin4<<<1024, 256, 0, stream>>>(acc, inv_deg, w_edge_e, P2f, P3f);
  k_fe4e<<<(NE + 255) / 256, 256, 0, stream>>>(partialE, inv_p, edge_attr, src, dst,
                                               P2f, P3f, b_edge_e, (float*)d_out);
}

// Round 12
// 930.609 us; speedup vs baseline: 1.1450x; 1.0071x over previous
//
#include <hip/hip_runtime.h>

#define NN 100000
#define NE 1600000
#define D 32

typedef short short8 __attribute__((ext_vector_type(8)));
typedef float f32x4 __attribute__((ext_vector_type(4)));

union ABfrag { int4 i; short8 s; };

// ---------------- bf16 helpers ----------------

__device__ inline unsigned short f2b(float f) {
  unsigned int u = __float_as_uint(f);
  u = (u + 0x7FFFu + ((u >> 16) & 1u)) >> 16;
  return (unsigned short)u;
}
__device__ inline float b2f(unsigned short s) {
  return __uint_as_float(((unsigned int)s) << 16);
}
__device__ inline unsigned cvt_pk_bf16(float lo, float hi) {
  unsigned r;
  asm("v_cvt_pk_bf16_f32 %0, %1, %2" : "=v"(r) : "v"(lo), "v"(hi));
  return r;
}
__device__ inline void splitw(float w, unsigned short& h, unsigned short& l) {
  h = f2b(w);
  l = f2b(w - b2f(h));
}
__device__ inline float unpk_lo(unsigned u) { return b2f((unsigned short)(u & 0xFFFFu)); }
__device__ inline float unpk_hi(unsigned u) { return b2f((unsigned short)(u >> 16)); }

// XCD-aware bijective block swizzle (m204): contiguous chunk ranges per XCD.
// nwg = 6250, q = 781, r = 2.
__device__ inline int xcd_swz(int bid, int nwg) {
  int q = nwg >> 3, r = nwg & 7;
  int xcd = bid & 7, j = bid >> 3;
  int base = (xcd < r) ? xcd * (q + 1) : r * (q + 1) + (xcd - r) * q;
  return base + j;
}

// ============================ CSR build ============================

__global__ void k_deg(const int* __restrict__ dst, int* __restrict__ cnt) {
  int i = blockIdx.x * blockDim.x + threadIdx.x;
  int stride = gridDim.x * blockDim.x;
  for (int e = i; e < NE; e += stride) atomicAdd(&cnt[dst[e]], 1);
}

__global__ void k_invdeg(const int* __restrict__ cnt, float* __restrict__ inv) {
  int v = blockIdx.x * blockDim.x + threadIdx.x;
  if (v < NN) inv[v] = 1.0f / (float)max(cnt[v], 1);
}

__global__ __launch_bounds__(1024) void k_scanA(const int* __restrict__ cnt,
                                                int* __restrict__ rowptr,
                                                int* __restrict__ partial) {
  __shared__ int lds[1024];
  int t = threadIdx.x;
  int i = blockIdx.x * 1024 + t;
  int v = (i < NN) ? cnt[i] : 0;
  lds[t] = v;
  __syncthreads();
  for (int off = 1; off < 1024; off <<= 1) {
    int add = (t >= off) ? lds[t - off] : 0;
    __syncthreads();
    lds[t] += add;
    __syncthreads();
  }
  if (i < NN) rowptr[i] = lds[t] - v;
  if (t == 1023) partial[blockIdx.x] = lds[1023];
}

__global__ __launch_bounds__(128) void k_scanB(int* __restrict__ partial, int nb) {
  __shared__ int s[128];
  int t = threadIdx.x;
  int v = (t < nb) ? partial[t] : 0;
  s[t] = v;
  __syncthreads();
  for (int off = 1; off < 128; off <<= 1) {
    int add = (t >= off) ? s[t - off] : 0;
    __syncthreads();
    s[t] += add;
    __syncthreads();
  }
  if (t < nb) partial[t] = s[t] - v;  // exclusive
}

__global__ __launch_bounds__(1024) void k_scanC(int* __restrict__ rowptr,
                                                const int* __restrict__ partial) {
  int t = threadIdx.x;
  int i = blockIdx.x * 1024 + t;
  if (i < NN) rowptr[i] += partial[blockIdx.x];
  if (i == 0) rowptr[NN] = NE;
}

// phase A: scatter only perm (4B); inv_p coalesced by e
__global__ void k_fillA(const int* __restrict__ dst, const int* __restrict__ rowptr,
                        int* __restrict__ fill, int* __restrict__ perm,
                        int* __restrict__ inv_p) {
  int i = blockIdx.x * blockDim.x + threadIdx.x;
  int stride = gridDim.x * blockDim.x;
  for (int e = i; e < NE; e += stride) {
    int d = dst[e];
    int slot = atomicAdd(&fill[d], 1);
    int p = rowptr[d] + slot;
    perm[p] = e;
    inv_p[e] = p;
  }
}

// phase B: coalesced writes; scattered READS (L2/L3-absorbed)
__global__ void k_fillB(const int* __restrict__ perm, const int* __restrict__ src,
                        const int* __restrict__ dst, const float* __restrict__ ea,
                        int* __restrict__ src_p, int* __restrict__ dst_p,
                        float4* __restrict__ ea4) {
  int i = blockIdx.x * blockDim.x + threadIdx.x;
  int stride = gridDim.x * blockDim.x;
  for (int p = i; p < NE; p += stride) {
    int e = perm[p];
    src_p[p] = src[e];
    dst_p[p] = dst[e];
    ea4[p] = make_float4(ea[(size_t)e * 3 + 0], ea[(size_t)e * 3 + 1],
                         ea[(size_t)e * 3 + 2], 0.f);
  }
}

// ============================ VALU dot helper (node kernels) ============================

template <int K4>
__device__ inline float dot_lds(const float* __restrict__ lv, const float* __restrict__ Wc) {
  float acc = 0.f;
  const float4* v4 = (const float4*)lv;
#pragma unroll
  for (int kk = 0; kk < K4; kk++) {
    float4 h = v4[kk];
    acc = fmaf(h.x, Wc[4 * kk + 0], acc);
    acc = fmaf(h.y, Wc[4 * kk + 1], acc);
    acc = fmaf(h.z, Wc[4 * kk + 2], acc);
    acc = fmaf(h.w, Wc[4 * kk + 3], acc);
  }
  return acc;
}

// ============ node encoder + Q0 projection (packed bf16 pairs) ============

__global__ __launch_bounds__(256) void k_node_enc_fin(
    const float* __restrict__ x,
    const float* __restrict__ ws, const float* __restrict__ bs,
    const float* __restrict__ wh, const float* __restrict__ bh,
    const float* __restrict__ we, const float* __restrict__ be,
    const float* __restrict__ Wn,  // w_node_s, rows 0..31
    unsigned* __restrict__ Q0b) {  // [NN*16]: pk(q_ch, q_ch+16)
  __shared__ float hrow[8][D];
  int t = threadIdx.x, j = t & 31, g = t >> 5;
  float Ws = ws[j], Bs = bs[j], Bh = bh[j], Be = be[j];
  float Wh[D], We_[D], Wq[D];
#pragma unroll
  for (int k = 0; k < D; k++) {
    Wh[k] = wh[k * D + j];
    We_[k] = we[k * D + j];
    Wq[k] = Wn[k * D + j];
  }
  for (int v = blockIdx.x * 8 + g; v < NN; v += gridDim.x * 8) {
    float h = fmaxf(fmaf(x[v], Ws, Bs), 0.f);
#pragma unroll
    for (int L = 0; L < 2; L++) {
      hrow[g][j] = h;
      h = fmaxf(dot_lds<8>(hrow[g], Wh) + Bh, 0.f);
    }
    hrow[g][j] = h;
    h = fmaxf(dot_lds<8>(hrow[g], We_) + Be, 0.f);
    hrow[g][j] = h;
    float q = dot_lds<8>(hrow[g], Wq);
    hrow[g][j] = q;  // wave-sync staging (dot complete for all lanes)
    if (j < 16) Q0b[(size_t)v * 16 + j] = cvt_pk_bf16(hrow[g][j], hrow[g][j + 16]);
  }
}

// ==== node finalize: h = acc/deg; project P2/Q and P3, packed bf16 ====

__global__ __launch_bounds__(256) void k_fin(
    float* __restrict__ acc, const float* __restrict__ inv_deg,
    const float* __restrict__ We,  // [96][32] NEXT edge layer (rows 32..95 used)
    const float* __restrict__ Wn,  // [64][32] NEXT node msg (rows 0..31 used)
    uint2* __restrict__ R2b,       // [NN*16]: {pk(p2lo,qlo), pk(p2hi,qhi)}
    unsigned* __restrict__ P3b) {  // [NN*16]: pk(p3lo,p3hi)
  __shared__ float hrow[8][D];
  __shared__ float st[8][3][D];
  int t = threadIdx.x, j = t & 31, g = t >> 5;
  float Wp2[D], Wp3[D], Wq[D];
#pragma unroll
  for (int k = 0; k < D; k++) {
    Wp2[k] = We[(32 + k) * D + j];
    Wp3[k] = We[(64 + k) * D + j];
    Wq[k] = Wn[k * D + j];
  }
  for (int v = blockIdx.x * 8 + g; v < NN; v += gridDim.x * 8) {
    float h = acc[(size_t)v * D + j] * inv_deg[v];
    acc[(size_t)v * D + j] = 0.f;
    hrow[g][j] = h;
    float p2 = dot_lds<8>(hrow[g], Wp2);
    float q = dot_lds<8>(hrow[g], Wq);
    float p3 = dot_lds<8>(hrow[g], Wp3);
    st[g][0][j] = p2; st[g][1][j] = q; st[g][2][j] = p3;
    if (j < 16) {
      R2b[(size_t)v * 16 + j] = make_uint2(cvt_pk_bf16(st[g][0][j], st[g][1][j]),
                                           cvt_pk_bf16(st[g][0][j + 16], st[g][1][j + 16]));
      P3b[(size_t)v * 16 + j] = cvt_pk_bf16(st[g][2][j], st[g][2][j + 16]);
    }
  }
}

// ==== final node finalize: P2f/P3f [NN,3] ====

__global__ __launch_bounds__(256) void k_fin4(
    float* __restrict__ acc, const float* __restrict__ inv_deg,
    const float* __restrict__ We,  // w_edge_e [96][3]
    float* __restrict__ P2f, float* __restrict__ P3f) {
  __shared__ float hrow[8][D];
  int t = threadIdx.x, j = t & 31, g = t >> 5;
  for (int v = blockIdx.x * 8 + g; v < NN; v += gridDim.x * 8) {
    float h = acc[(size_t)v * D + j] * inv_deg[v];
    hrow[g][j] = h;
    if (j < 6) {
      int c = j % 3;
      int off = (j < 3) ? 32 : 64;
      float s = 0.f;
#pragma unroll
      for (int k = 0; k < D; k++) s = fmaf(hrow[g][k], We[(off + k) * 3 + c], s);
      if (j < 3) P2f[(size_t)v * 3 + c] = s;
      else       P3f[(size_t)v * 3 + c] = s;
    }
  }
}

// ============================ MFMA helpers ============================
// D layout (mfma_f32_16x16x32_bf16): col = lane&15, row = (lane>>4)*4 + reg
// A layout: row = lane&15, k = (lane>>4)*8 + i ;  B layout: col = lane&15, k = (lane>>4)*8 + i
// h_edge stores channels interleaved: position 2*c+h <-> channel c + 16*h (c=0..15)

__device__ inline void ep_xpose_write(float* __restrict__ xw, f32x4 da, f32x4 db,
                                      float ba, float bb, int cl, int ch) {
#pragma unroll
  for (int r = 0; r < 4; r++) {
    xw[(cl * 4 + r) * 36 + ch] = fmaxf(da[r] + ba, 0.f);
    xw[(cl * 4 + r) * 36 + ch + 16] = fmaxf(db[r] + bb, 0.f);
  }
}

__device__ inline ABfrag xpose_read(const float* __restrict__ xw, int lane) {
  const float4* p = (const float4*)(xw + (lane & 15) * 36 + (lane >> 4) * 8);
  float4 v0 = p[0], v1 = p[1];
  ABfrag A;
  A.i = make_int4(cvt_pk_bf16(v0.x, v0.y), cvt_pk_bf16(v0.z, v0.w),
                  cvt_pk_bf16(v1.x, v1.y), cvt_pk_bf16(v1.z, v1.w));
  return A;
}

// gather bundle for one 16-edge tile (packed bf16 node rows)
struct G8 { uint2 r2[4]; unsigned p3[4]; };

__device__ inline void gath(G8& g, const uint2* __restrict__ R2b,
                            const unsigned* __restrict__ P3b, int4 sv, int4 dv, int ch) {
  int sa[4] = {sv.x, sv.y, sv.z, sv.w};
  int da[4] = {dv.x, dv.y, dv.z, dv.w};
#pragma unroll
  for (int r = 0; r < 4; r++) {
    g.r2[r] = R2b[(size_t)sa[r] * 16 + ch];
    g.p3[r] = P3b[(size_t)da[r] * 16 + ch];
  }
}

// ==== MFMA fused: edge encoder + first message + scatter ====

__global__ __launch_bounds__(256) void k_fe0_m(
    const float4* __restrict__ ea4, const unsigned* __restrict__ Q0b,
    const int* __restrict__ src_p, const int* __restrict__ dst_p,
    float* __restrict__ acc,
    const float* __restrict__ ws, const float* __restrict__ bs,
    const float* __restrict__ wh, const float* __restrict__ bh,
    const float* __restrict__ we, const float* __restrict__ be,
    const float* __restrict__ Wn,  // w_node_s rows 32..63
    unsigned int* __restrict__ h_edge) {  // packed interleaved bf16 pairs
  __shared__ float xp[4][16 * 36];
  int lane = threadIdx.x & 63, wid = threadIdx.x >> 6;
  int cl = lane >> 4, ch = lane & 15;
  unsigned wp01[8], wp2b[8];
#pragma unroll
  for (int kk = 0; kk < 8; kk++) {
    int c = cl * 8 + kk;
    wp01[kk] = ((unsigned)f2b(ws[32 + c]) << 16) | f2b(ws[c]);
    wp2b[kk] = ((unsigned)f2b(bs[c]) << 16) | f2b(ws[64 + c]);
  }
  ABfrag wha, whb, wea, web, w2a, w2b;
#pragma unroll
  for (int kk = 0; kk < 8; kk++) {
    int k = cl * 8 + kk;
    wha.s[kk] = (short)f2b(wh[k * 32 + ch]);
    whb.s[kk] = (short)f2b(wh[k * 32 + ch + 16]);
    wea.s[kk] = (short)f2b(we[k * 32 + ch]);
    web.s[kk] = (short)f2b(we[k * 32 + ch + 16]);
    w2a.s[kk] = (short)f2b(Wn[(32 + k) * 32 + ch]);
    w2b.s[kk] = (short)f2b(Wn[(32 + k) * 32 + ch + 16]);
  }
  float bha = bh[ch], bhb = bh[ch + 16], bea = be[ch], beb = be[ch + 16];
  int blk = xcd_swz(blockIdx.x, gridDim.x);
  int p0 = (blk * 4 + wid) * 64;
  f32x4 z = {0.f, 0.f, 0.f, 0.f};
  float* xw = xp[wid];
  float va = 0.f, vb = 0.f;
  int cur = dst_p[p0 + cl * 4];
#pragma unroll
  for (int t = 0; t < 4; ++t) {
    int pb = p0 + t * 16;
    float4 av = ea4[pb + ch];
    int4 sv = *(const int4*)(src_p + pb + cl * 4);
    int4 dv = *(const int4*)(dst_p + pb + cl * 4);
    float h1[8];
#pragma unroll
    for (int kk = 0; kk < 8; kk++) {
      float w0 = unpk_lo(wp01[kk]), w1 = unpk_hi(wp01[kk]);
      float w2 = unpk_lo(wp2b[kk]), bb = unpk_hi(wp2b[kk]);
      h1[kk] = fmaxf(fmaf(av.x, w0, fmaf(av.y, w1, fmaf(av.z, w2, bb))), 0.f);
    }
    ABfrag A;
    A.i = make_int4(cvt_pk_bf16(h1[0], h1[1]), cvt_pk_bf16(h1[2], h1[3]),
                    cvt_pk_bf16(h1[4], h1[5]), cvt_pk_bf16(h1[6], h1[7]));
    f32x4 da = __builtin_amdgcn_mfma_f32_16x16x32_bf16(A.s, wha.s, z, 0, 0, 0);
    f32x4 db = __builtin_amdgcn_mfma_f32_16x16x32_bf16(A.s, whb.s, z, 0, 0, 0);
    ep_xpose_write(xw, da, db, bha, bhb, cl, ch);
    A = xpose_read(xw, lane);
    da = __builtin_amdgcn_mfma_f32_16x16x32_bf16(A.s, wha.s, z, 0, 0, 0);
    db = __builtin_amdgcn_mfma_f32_16x16x32_bf16(A.s, whb.s, z, 0, 0, 0);
    ep_xpose_write(xw, da, db, bha, bhb, cl, ch);
    A = xpose_read(xw, lane);
    da = __builtin_amdgcn_mfma_f32_16x16x32_bf16(A.s, wea.s, z, 0, 0, 0);
    db = __builtin_amdgcn_mfma_f32_16x16x32_bf16(A.s, web.s, z, 0, 0, 0);
#pragma unroll
    for (int r = 0; r < 4; r++) {
      float h0 = fmaxf(da[r] + bea, 0.f);
      float hv = fmaxf(db[r] + beb, 0.f);
      int p = pb + cl * 4 + r;
      h_edge[(size_t)p * 16 + ch] = cvt_pk_bf16(h0, hv);
      xw[(cl * 4 + r) * 36 + ch] = h0;
      xw[(cl * 4 + r) * 36 + ch + 16] = hv;
    }
    A = xpose_read(xw, lane);
    f32x4 ma = __builtin_amdgcn_mfma_f32_16x16x32_bf16(A.s, w2a.s, z, 0, 0, 0);
    f32x4 mb = __builtin_amdgcn_mfma_f32_16x16x32_bf16(A.s, w2b.s, z, 0, 0, 0);
    int sa[4] = {sv.x, sv.y, sv.z, sv.w};
    int dda[4] = {dv.x, dv.y, dv.z, dv.w};
#pragma unroll
    for (int r = 0; r < 4; r++) {
      unsigned qv = Q0b[(size_t)sa[r] * 16 + ch];
      float xa = fmaxf(ma[r] + unpk_lo(qv), 0.f);
      float xb = fmaxf(mb[r] + unpk_hi(qv), 0.f);
      if (dda[r] != cur) {
        atomicAdd(&acc[(size_t)cur * 32 + ch], va);
        atomicAdd(&acc[(size_t)cur * 32 + ch + 16], vb);
        va = 0.f; vb = 0.f; cur = dda[r];
      }
      va += xa; vb += xb;
    }
  }
  atomicAdd(&acc[(size_t)cur * 32 + ch], va);
  atomicAdd(&acc[(size_t)cur * 32 + ch + 16], vb);
}

// ==== MFMA fused: edge update + message + scatter ====
// A-frag from interleaved h_edge: frag pos cl*8+kk holds channel kp = cl*4 + (kk>>1) + (kk&1)*16

template <int LAST>
__global__ __launch_bounds__(256) void k_fe_t(
    unsigned int* __restrict__ h_edge, const uint2* __restrict__ R2b,
    const unsigned* __restrict__ P3b, const int* __restrict__ src_p,
    const int* __restrict__ dst_p, float* __restrict__ acc,
    const float* __restrict__ We, const float* __restrict__ be,
    const float* __restrict__ Wn, const float* __restrict__ We3,
    float* __restrict__ partialE) {
  __shared__ float xp[4][16 * 36];
  int lane = threadIdx.x & 63, wid = threadIdx.x >> 6;
  int cl = lane >> 4, ch = lane & 15;
  ABfrag b1a, b1b, b2a, b2b, w3h, w3l;
#pragma unroll
  for (int kk = 0; kk < 8; kk++) {
    int k = cl * 8 + kk;
    int kp = cl * 4 + (kk >> 1) + (kk & 1) * 16;  // interleaved h_edge k-perm
    b1a.s[kk] = (short)f2b(We[kp * 32 + ch]);
    b1b.s[kk] = (short)f2b(We[kp * 32 + ch + 16]);
    b2a.s[kk] = (short)f2b(Wn[(32 + k) * 32 + ch]);
    b2b.s[kk] = (short)f2b(Wn[(32 + k) * 32 + ch + 16]);
    if (LAST) {
      unsigned short hi_, lo_;
      float v = (ch < 3) ? We3[k * 3 + ch] : 0.f;
      splitw(v, hi_, lo_); w3h.s[kk] = (short)hi_; w3l.s[kk] = (short)lo_;
    }
  }
  float bea = be[ch], beb = be[ch + 16];
  int blk = xcd_swz(blockIdx.x, gridDim.x);
  int p0 = (blk * 4 + wid) * 64;
  f32x4 z = {0.f, 0.f, 0.f, 0.f};
  float* xw = xp[wid];
  float va = 0.f, vb = 0.f;
  int cur = dst_p[p0 + cl * 4];
#pragma unroll
  for (int t = 0; t < 4; ++t) {
    int pb = p0 + t * 16;
    ABfrag A;
    A.i = *(const int4*)(h_edge + (size_t)(pb + ch) * 16 + cl * 4);
    int4 sv = *(const int4*)(src_p + pb + cl * 4);
    int4 dv = *(const int4*)(dst_p + pb + cl * 4);
    G8 g;
    gath(g, R2b, P3b, sv, dv, ch);
    f32x4 da = __builtin_amdgcn_mfma_f32_16x16x32_bf16(A.s, b1a.s, z, 0, 0, 0);
    f32x4 db = __builtin_amdgcn_mfma_f32_16x16x32_bf16(A.s, b1b.s, z, 0, 0, 0);
#pragma unroll
    for (int r = 0; r < 4; r++) {
      float h0 = fmaxf(da[r] + unpk_lo(g.r2[r].x) + unpk_lo(g.p3[r]) + bea, 0.f);
      float hv = fmaxf(db[r] + unpk_lo(g.r2[r].y) + unpk_hi(g.p3[r]) + beb, 0.f);
      int p = pb + cl * 4 + r;
      if (!LAST) h_edge[(size_t)p * 16 + ch] = cvt_pk_bf16(h0, hv);
      xw[(cl * 4 + r) * 36 + ch] = h0;
      xw[(cl * 4 + r) * 36 + ch + 16] = hv;
    }
    ABfrag A2 = xpose_read(xw, lane);
    f32x4 ma = __builtin_amdgcn_mfma_f32_16x16x32_bf16(A2.s, b2a.s, z, 0, 0, 0);
    f32x4 mb = __builtin_amdgcn_mfma_f32_16x16x32_bf16(A2.s, b2b.s, z, 0, 0, 0);
    if (LAST) {
      f32x4 dc = __builtin_amdgcn_mfma_f32_16x16x32_bf16(A2.s, w3l.s, z, 0, 0, 0);
      dc = __builtin_amdgcn_mfma_f32_16x16x32_bf16(A2.s, w3h.s, dc, 0, 0, 0);
      if (ch < 3) {
#pragma unroll
        for (int r = 0; r < 4; r++)
          partialE[(size_t)(pb + cl * 4 + r) * 3 + ch] = dc[r];
      }
    }
    int dda[4] = {dv.x, dv.y, dv.z, dv.w};
#pragma unroll
    for (int r = 0; r < 4; r++) {
      float xa = fmaxf(ma[r] + unpk_hi(g.r2[r].x), 0.f);
      float xb = fmaxf(mb[r] + unpk_hi(g.r2[r].y), 0.f);
      if (dda[r] != cur) {
        atomicAdd(&acc[(size_t)cur * 32 + ch], va);
        atomicAdd(&acc[(size_t)cur * 32 + ch + 16], vb);
        va = 0.f; vb = 0.f; cur = dda[r];
      }
      va += xa; vb += xb;
    }
  }
  atomicAdd(&acc[(size_t)cur * 32 + ch], va);
  atomicAdd(&acc[(size_t)cur * 32 + ch + 16], vb);
}

// ==== final: out[e] = ea[e] + partialE[inv[e]] + P2f[src[e]] + P3f[dst[e]] + b ====

__global__ __launch_bounds__(256) void k_fe4e(
    const float* __restrict__ partialE, const int* __restrict__ inv_p,
    const float* __restrict__ edge_attr, const int* __restrict__ src,
    const int* __restrict__ dstv, const float* __restrict__ P2f,
    const float* __restrict__ P3f, const float* __restrict__ be,
    float* __restrict__ out) {
  int e = blockIdx.x * blockDim.x + threadIdx.x;
  if (e >= NE) return;
  int p = inv_p[e];
  int s = src[e], d = dstv[e];
  float c0 = partialE[(size_t)p * 3 + 0];
  float c1 = partialE[(size_t)p * 3 + 1];
  float c2 = partialE[(size_t)p * 3 + 2];
  out[(size_t)e * 3 + 0] = edge_attr[(size_t)e * 3 + 0] + c0 + P2f[(size_t)s * 3 + 0] + P3f[(size_t)d * 3 + 0] + be[0];
  out[(size_t)e * 3 + 1] = edge_attr[(size_t)e * 3 + 1] + c1 + P2f[(size_t)s * 3 + 1] + P3f[(size_t)d * 3 + 1] + be[1];
  out[(size_t)e * 3 + 2] = edge_attr[(size_t)e * 3 + 2] + c2 + P2f[(size_t)s * 3 + 2] + P3f[(size_t)d * 3 + 2] + be[2];
}

// ============================ launch ============================

extern "C" void kernel_launch(void* const* d_in, const int* in_sizes, int n_in,
                              void* d_out, int out_size, void* d_ws, size_t ws_size,
                              hipStream_t stream) {
  const float* x = (const float*)d_in[0];
  const float* edge_attr = (const float*)d_in[1];
  const int* ei = (const int*)d_in[2];
  const int* src = ei;
  const int* dst = ei + NE;
  const float* w_enc_node_s = (const float*)d_in[3];
  const float* b_enc_node_s = (const float*)d_in[4];
  const float* w_enc_node_h = (const float*)d_in[5];
  const float* b_enc_node_h = (const float*)d_in[6];
  const float* w_enc_node_e = (const float*)d_in[7];
  const float* b_enc_node_e = (const float*)d_in[8];
  const float* w_enc_edge_s = (const float*)d_in[9];
  const float* b_enc_edge_s = (const float*)d_in[10];
  const float* w_enc_edge_h = (const float*)d_in[11];
  const float* b_enc_edge_h = (const float*)d_in[12];
  const float* w_enc_edge_e = (const float*)d_in[13];
  const float* b_enc_edge_e = (const float*)d_in[14];
  const float* w_node_s = (const float*)d_in[15];
  const float* w_node_h = (const float*)d_in[16];
  const float* w_node_e = (const float*)d_in[17];
  const float* w_edge_s = (const float*)d_in[18];
  const float* b_edge_s = (const float*)d_in[19];
  const float* w_edge_h = (const float*)d_in[20];
  const float* b_edge_h = (const float*)d_in[21];
  const float* w_edge_e = (const float*)d_in[22];
  const float* b_edge_e = (const float*)d_in[23];

  // workspace layout (~193 MB; 238 MB proven safe)
  char* w = (char*)d_ws;
  unsigned int* h_edge = (unsigned int*)w; w += (size_t)NE * 16 * 4;  // 102.4 MB
  int* inv_p = (int*)w;       w += (size_t)NE * 4;            // 6.4
  int* src_p = (int*)w;       w += (size_t)NE * 4;            // 6.4
  int* dst_p = (int*)w;       w += (size_t)NE * 4;            // 6.4
  int* perm = (int*)w;        w += (size_t)NE * 4;            // 6.4
  float4* ea4 = (float4*)w;   w += (size_t)NE * 16;           // 25.6 (aliased by partialE)
  float* acc = (float*)w;     w += (size_t)NN * D * 4;        // 12.8
  uint2* R2b = (uint2*)w;     w += (size_t)NN * 16 * 8;       // 12.8
  unsigned* P3b = (unsigned*)w; w += (size_t)NN * 16 * 4;     // 6.4 (aliased by P2f/P3f)
  unsigned* Q0b = (unsigned*)w; w += (size_t)NN * 16 * 4;     // 6.4
  float* P2f = (float*)P3b;
  float* P3f = (float*)P3b + (size_t)NN * 3;
  int* cnt = (int*)w;         w += (size_t)NN * 4;
  float* inv_deg = (float*)w; w += (size_t)NN * 4;
  int* rowptr = (int*)w;      w += (size_t)(NN + 1) * 4;
  int* fill = (int*)w;        w += (size_t)NN * 4;
  int* partial = (int*)w;     w += 4096;
  float* partialE = (float*)ea4;  // alias: ea4 dead after k_fe0_m

  hipMemsetAsync(cnt, 0, (size_t)NN * 4, stream);
  hipMemsetAsync(fill, 0, (size_t)NN * 4, stream);
  hipMemsetAsync(acc, 0, (size_t)NN * D * 4, stream);

  k_deg<<<1024, 256, 0, stream>>>(dst, cnt);
  k_invdeg<<<(NN + 255) / 256, 256, 0, stream>>>(cnt, inv_deg);
  int nb = (NN + 1023) / 1024;  // 98
  k_scanA<<<nb, 1024, 0, stream>>>(cnt, rowptr, partial);
  k_scanB<<<1, 128, 0, stream>>>(partial, nb);
  k_scanC<<<nb, 1024, 0, stream>>>(rowptr, partial);
  k_fillA<<<1024, 256, 0, stream>>>(dst, rowptr, fill, perm, inv_p);
  k_fillB<<<2048, 256, 0, stream>>>(perm, src, dst, edge_attr, src_p, dst_p, ea4);

  k_node_enc_fin<<<1024, 256, 0, stream>>>(x, w_enc_node_s, b_enc_node_s,
                                           w_enc_node_h, b_enc_node_h,
                                           w_enc_node_e, b_enc_node_e,
                                           w_node_s, Q0b);

  int feb = NE / 256;  // 6250 blocks: 4 waves x 64 edges

  k_fe0_m<<<feb, 256, 0, stream>>>(ea4, Q0b, src_p, dst_p, acc,
                                   w_enc_edge_s, b_enc_edge_s,
                                   w_enc_edge_h, b_enc_edge_h,
                                   w_enc_edge_e, b_enc_edge_e,
                                   w_node_s, h_edge);
  k_fin<<<1024, 256, 0, stream>>>(acc, inv_deg, w_edge_s, w_node_h, R2b, P3b);
  k_fe_t<0><<<feb, 256, 0, stream>>>(h_edge, R2b, P3b, src_p, dst_p, acc,
                                     w_edge_s, b_edge_s, w_node_h, nullptr, nullptr);
  k_fin<<<1024, 256, 0, stream>>>(acc, inv_deg, w_edge_h, w_node_h, R2b, P3b);
  k_fe_t<0><<<feb, 256, 0, stream>>>(h_edge, R2b, P3b, src_p, dst_p, acc,
                                     w_edge_h, b_edge_h, w_node_h, nullptr, nullptr);
  k_fin<<<1024, 256, 0, stream>>>(acc, inv_deg, w_edge_h, w_node_e, R2b, P3b);
  k_fe_t<1><<<feb, 256, 0, stream>>>(h_edge, R2b, P3b, src_p, dst_p, acc,
                                     w_edge_h, b_edge_h, w_node_e, w_edge_e, partialE);
  k_fin4<<<1024, 256, 0, stream>>>(acc, inv_deg, w_edge_e, P2f, P3f);
  k_fe4e<<<(NE + 255) / 256, 256, 0, stream>>>(partialE, inv_p, edge_attr, src, dst,
                                               P2f, P3f, b_edge_e, (float*)d_out);
}

// Round 13
// 829.034 us; speedup vs baseline: 1.2853x; 1.1225x over previous
//
#include <hip/hip_runtime.h>

#define NN 100000
#define NE 1600000
#define D 32

typedef short short8 __attribute__((ext_vector_type(8)));
typedef float f32x4 __attribute__((ext_vector_type(4)));

union ABfrag { int4 i; short8 s; };

// ---------------- bf16 helpers ----------------

__device__ inline unsigned short f2b(float f) {
  unsigned int u = __float_as_uint(f);
  u = (u + 0x7FFFu + ((u >> 16) & 1u)) >> 16;
  return (unsigned short)u;
}
__device__ inline float b2f(unsigned short s) {
  return __uint_as_float(((unsigned int)s) << 16);
}
__device__ inline unsigned cvt_pk_bf16(float lo, float hi) {
  unsigned r;
  asm("v_cvt_pk_bf16_f32 %0, %1, %2" : "=v"(r) : "v"(lo), "v"(hi));
  return r;
}
__device__ inline void splitw(float w, unsigned short& h, unsigned short& l) {
  h = f2b(w);
  l = f2b(w - b2f(h));
}
__device__ inline float unpk_lo(unsigned u) { return b2f((unsigned short)(u & 0xFFFFu)); }
__device__ inline float unpk_hi(unsigned u) { return b2f((unsigned short)(u >> 16)); }

// XCD-aware bijective block swizzle (m204)
__device__ inline int xcd_swz(int bid, int nwg) {
  int q = nwg >> 3, r = nwg & 7;
  int xcd = bid & 7, j = bid >> 3;
  int base = (xcd < r) ? xcd * (q + 1) : r * (q + 1) + (xcd - r) * q;
  return base + j;
}

// ============================ CSR build ============================

// counting pass; ALSO records each edge's rank within its dst bucket (coalesced)
__global__ void k_deg(const int* __restrict__ dst, int* __restrict__ cnt,
                      int* __restrict__ slot) {
  int i = blockIdx.x * blockDim.x + threadIdx.x;
  int stride = gridDim.x * blockDim.x;
  for (int e = i; e < NE; e += stride) slot[e] = atomicAdd(&cnt[dst[e]], 1);
}

__global__ void k_invdeg(const int* __restrict__ cnt, float* __restrict__ inv) {
  int v = blockIdx.x * blockDim.x + threadIdx.x;
  if (v < NN) inv[v] = 1.0f / (float)max(cnt[v], 1);
}

__global__ __launch_bounds__(1024) void k_scanA(const int* __restrict__ cnt,
                                                int* __restrict__ rowptr,
                                                int* __restrict__ partial) {
  __shared__ int lds[1024];
  int t = threadIdx.x;
  int i = blockIdx.x * 1024 + t;
  int v = (i < NN) ? cnt[i] : 0;
  lds[t] = v;
  __syncthreads();
  for (int off = 1; off < 1024; off <<= 1) {
    int add = (t >= off) ? lds[t - off] : 0;
    __syncthreads();
    lds[t] += add;
    __syncthreads();
  }
  if (i < NN) rowptr[i] = lds[t] - v;
  if (t == 1023) partial[blockIdx.x] = lds[1023];
}

__global__ __launch_bounds__(128) void k_scanB(int* __restrict__ partial, int nb) {
  __shared__ int s[128];
  int t = threadIdx.x;
  int v = (t < nb) ? partial[t] : 0;
  s[t] = v;
  __syncthreads();
  for (int off = 1; off < 128; off <<= 1) {
    int add = (t >= off) ? s[t - off] : 0;
    __syncthreads();
    s[t] += add;
    __syncthreads();
  }
  if (t < nb) partial[t] = s[t] - v;  // exclusive
}

__global__ __launch_bounds__(1024) void k_scanC(int* __restrict__ rowptr,
                                                const int* __restrict__ partial) {
  int t = threadIdx.x;
  int i = blockIdx.x * 1024 + t;
  if (i < NN) rowptr[i] += partial[blockIdx.x];
  if (i == 0) rowptr[NN] = NE;
}

// phase A (ATOMIC-FREE): p = rowptr[dst[e]] + slot[e]; scatter only perm (4B)
__global__ void k_fillA(const int* __restrict__ dst, const int* __restrict__ slot,
                        const int* __restrict__ rowptr,
                        int* __restrict__ perm, int* __restrict__ inv_p) {
  int i = blockIdx.x * blockDim.x + threadIdx.x;
  int stride = gridDim.x * blockDim.x;
  for (int e = i; e < NE; e += stride) {
    int p = rowptr[dst[e]] + slot[e];
    perm[p] = e;
    inv_p[e] = p;
  }
}

// phase B: coalesced writes; scattered READS (L2/L3-absorbed)
__global__ void k_fillB(const int* __restrict__ perm, const int* __restrict__ src,
                        const int* __restrict__ dst, const float* __restrict__ ea,
                        int* __restrict__ src_p, int* __restrict__ dst_p,
                        float4* __restrict__ ea4) {
  int i = blockIdx.x * blockDim.x + threadIdx.x;
  int stride = gridDim.x * blockDim.x;
  for (int p = i; p < NE; p += stride) {
    int e = perm[p];
    src_p[p] = src[e];
    dst_p[p] = dst[e];
    ea4[p] = make_float4(ea[(size_t)e * 3 + 0], ea[(size_t)e * 3 + 1],
                         ea[(size_t)e * 3 + 2], 0.f);
  }
}

// ============================ VALU dot helper (node kernels) ============================

template <int K4>
__device__ inline float dot_lds(const float* __restrict__ lv, const float* __restrict__ Wc) {
  float acc = 0.f;
  const float4* v4 = (const float4*)lv;
#pragma unroll
  for (int kk = 0; kk < K4; kk++) {
    float4 h = v4[kk];
    acc = fmaf(h.x, Wc[4 * kk + 0], acc);
    acc = fmaf(h.y, Wc[4 * kk + 1], acc);
    acc = fmaf(h.z, Wc[4 * kk + 2], acc);
    acc = fmaf(h.w, Wc[4 * kk + 3], acc);
  }
  return acc;
}

// ============ node encoder + Q0 projection (packed bf16 pairs) ============

__global__ __launch_bounds__(256) void k_node_enc_fin(
    const float* __restrict__ x,
    const float* __restrict__ ws, const float* __restrict__ bs,
    const float* __restrict__ wh, const float* __restrict__ bh,
    const float* __restrict__ we, const float* __restrict__ be,
    const float* __restrict__ Wn,  // w_node_s, rows 0..31
    unsigned* __restrict__ Q0b) {  // [NN*16]: pk(q_ch, q_ch+16)
  __shared__ float hrow[8][D];
  int t = threadIdx.x, j = t & 31, g = t >> 5;
  float Ws = ws[j], Bs = bs[j], Bh = bh[j], Be = be[j];
  float Wh[D], We_[D], Wq[D];
#pragma unroll
  for (int k = 0; k < D; k++) {
    Wh[k] = wh[k * D + j];
    We_[k] = we[k * D + j];
    Wq[k] = Wn[k * D + j];
  }
  for (int v = blockIdx.x * 8 + g; v < NN; v += gridDim.x * 8) {
    float h = fmaxf(fmaf(x[v], Ws, Bs), 0.f);
#pragma unroll
    for (int L = 0; L < 2; L++) {
      hrow[g][j] = h;
      h = fmaxf(dot_lds<8>(hrow[g], Wh) + Bh, 0.f);
    }
    hrow[g][j] = h;
    h = fmaxf(dot_lds<8>(hrow[g], We_) + Be, 0.f);
    hrow[g][j] = h;
    float q = dot_lds<8>(hrow[g], Wq);
    hrow[g][j] = q;  // wave-sync staging (dot complete for all lanes)
    if (j < 16) Q0b[(size_t)v * 16 + j] = cvt_pk_bf16(hrow[g][j], hrow[g][j + 16]);
  }
}

// ==== node finalize: h = acc/deg; project P2/Q and P3, packed bf16 ====

__global__ __launch_bounds__(256) void k_fin(
    float* __restrict__ acc, const float* __restrict__ inv_deg,
    const float* __restrict__ We,  // [96][32] NEXT edge layer (rows 32..95 used)
    const float* __restrict__ Wn,  // [64][32] NEXT node msg (rows 0..31 used)
    uint2* __restrict__ R2b,       // [NN*16]: {pk(p2lo,qlo), pk(p2hi,qhi)}
    unsigned* __restrict__ P3b) {  // [NN*16]: pk(p3lo,p3hi)
  __shared__ float hrow[8][D];
  __shared__ float st[8][3][D];
  int t = threadIdx.x, j = t & 31, g = t >> 5;
  float Wp2[D], Wp3[D], Wq[D];
#pragma unroll
  for (int k = 0; k < D; k++) {
    Wp2[k] = We[(32 + k) * D + j];
    Wp3[k] = We[(64 + k) * D + j];
    Wq[k] = Wn[k * D + j];
  }
  for (int v = blockIdx.x * 8 + g; v < NN; v += gridDim.x * 8) {
    float h = acc[(size_t)v * D + j] * inv_deg[v];
    acc[(size_t)v * D + j] = 0.f;
    hrow[g][j] = h;
    float p2 = dot_lds<8>(hrow[g], Wp2);
    float q = dot_lds<8>(hrow[g], Wq);
    float p3 = dot_lds<8>(hrow[g], Wp3);
    st[g][0][j] = p2; st[g][1][j] = q; st[g][2][j] = p3;
    if (j < 16) {
      R2b[(size_t)v * 16 + j] = make_uint2(cvt_pk_bf16(st[g][0][j], st[g][1][j]),
                                           cvt_pk_bf16(st[g][0][j + 16], st[g][1][j + 16]));
      P3b[(size_t)v * 16 + j] = cvt_pk_bf16(st[g][2][j], st[g][2][j + 16]);
    }
  }
}

// ==== final node finalize: P2f/P3f [NN,3] ====

__global__ __launch_bounds__(256) void k_fin4(
    float* __restrict__ acc, const float* __restrict__ inv_deg,
    const float* __restrict__ We,  // w_edge_e [96][3]
    float* __restrict__ P2f, float* __restrict__ P3f) {
  __shared__ float hrow[8][D];
  int t = threadIdx.x, j = t & 31, g = t >> 5;
  for (int v = blockIdx.x * 8 + g; v < NN; v += gridDim.x * 8) {
    float h = acc[(size_t)v * D + j] * inv_deg[v];
    hrow[g][j] = h;
    if (j < 6) {
      int c = j % 3;
      int off = (j < 3) ? 32 : 64;
      float s = 0.f;
#pragma unroll
      for (int k = 0; k < D; k++) s = fmaf(hrow[g][k], We[(off + k) * 3 + c], s);
      if (j < 3) P2f[(size_t)v * 3 + c] = s;
      else       P3f[(size_t)v * 3 + c] = s;
    }
  }
}

// ============================ MFMA helpers ============================
// D layout (mfma_f32_16x16x32_bf16): col = lane&15, row = (lane>>4)*4 + reg
// A layout: row = lane&15, k = (lane>>4)*8 + i ;  B layout: col = lane&15, k = (lane>>4)*8 + i
// h_edge stores channels interleaved: position 2*c+h <-> channel c + 16*h (c=0..15)

__device__ inline void ep_xpose_write(float* __restrict__ xw, f32x4 da, f32x4 db,
                                      float ba, float bb, int cl, int ch) {
#pragma unroll
  for (int r = 0; r < 4; r++) {
    xw[(cl * 4 + r) * 36 + ch] = fmaxf(da[r] + ba, 0.f);
    xw[(cl * 4 + r) * 36 + ch + 16] = fmaxf(db[r] + bb, 0.f);
  }
}

__device__ inline ABfrag xpose_read(const float* __restrict__ xw, int lane) {
  const float4* p = (const float4*)(xw + (lane & 15) * 36 + (lane >> 4) * 8);
  float4 v0 = p[0], v1 = p[1];
  ABfrag A;
  A.i = make_int4(cvt_pk_bf16(v0.x, v0.y), cvt_pk_bf16(v0.z, v0.w),
                  cvt_pk_bf16(v1.x, v1.y), cvt_pk_bf16(v1.z, v1.w));
  return A;
}

// gather bundle for one 16-edge tile (packed bf16 node rows)
struct G8 { uint2 r2[4]; unsigned p3[4]; };

__device__ inline void gath(G8& g, const uint2* __restrict__ R2b,
                            const unsigned* __restrict__ P3b, int4 sv, int4 dv, int ch) {
  int sa[4] = {sv.x, sv.y, sv.z, sv.w};
  int da[4] = {dv.x, dv.y, dv.z, dv.w};
#pragma unroll
  for (int r = 0; r < 4; r++) {
    g.r2[r] = R2b[(size_t)sa[r] * 16 + ch];
    g.p3[r] = P3b[(size_t)da[r] * 16 + ch];
  }
}

// ==== MFMA fused: edge encoder + first message + scatter ====

__global__ __launch_bounds__(256) void k_fe0_m(
    const float4* __restrict__ ea4, const unsigned* __restrict__ Q0b,
    const int* __restrict__ src_p, const int* __restrict__ dst_p,
    float* __restrict__ acc,
    const float* __restrict__ ws, const float* __restrict__ bs,
    const float* __restrict__ wh, const float* __restrict__ bh,
    const float* __restrict__ we, const float* __restrict__ be,
    const float* __restrict__ Wn,  // w_node_s rows 32..63
    unsigned int* __restrict__ h_edge) {  // packed interleaved bf16 pairs
  __shared__ float xp[4][16 * 36];
  int lane = threadIdx.x & 63, wid = threadIdx.x >> 6;
  int cl = lane >> 4, ch = lane & 15;
  unsigned wp01[8], wp2b[8];
#pragma unroll
  for (int kk = 0; kk < 8; kk++) {
    int c = cl * 8 + kk;
    wp01[kk] = ((unsigned)f2b(ws[32 + c]) << 16) | f2b(ws[c]);
    wp2b[kk] = ((unsigned)f2b(bs[c]) << 16) | f2b(ws[64 + c]);
  }
  ABfrag wha, whb, wea, web, w2a, w2b;
#pragma unroll
  for (int kk = 0; kk < 8; kk++) {
    int k = cl * 8 + kk;
    wha.s[kk] = (short)f2b(wh[k * 32 + ch]);
    whb.s[kk] = (short)f2b(wh[k * 32 + ch + 16]);
    wea.s[kk] = (short)f2b(we[k * 32 + ch]);
    web.s[kk] = (short)f2b(we[k * 32 + ch + 16]);
    w2a.s[kk] = (short)f2b(Wn[(32 + k) * 32 + ch]);
    w2b.s[kk] = (short)f2b(Wn[(32 + k) * 32 + ch + 16]);
  }
  float bha = bh[ch], bhb = bh[ch + 16], bea = be[ch], beb = be[ch + 16];
  int blk = xcd_swz(blockIdx.x, gridDim.x);
  int p0 = (blk * 4 + wid) * 64;
  f32x4 z = {0.f, 0.f, 0.f, 0.f};
  float* xw = xp[wid];
  float va = 0.f, vb = 0.f;
  int cur = dst_p[p0 + cl * 4];
#pragma unroll
  for (int t = 0; t < 4; ++t) {
    int pb = p0 + t * 16;
    float4 av = ea4[pb + ch];
    int4 sv = *(const int4*)(src_p + pb + cl * 4);
    int4 dv = *(const int4*)(dst_p + pb + cl * 4);
    float h1[8];
#pragma unroll
    for (int kk = 0; kk < 8; kk++) {
      float w0 = unpk_lo(wp01[kk]), w1 = unpk_hi(wp01[kk]);
      float w2 = unpk_lo(wp2b[kk]), bb = unpk_hi(wp2b[kk]);
      h1[kk] = fmaxf(fmaf(av.x, w0, fmaf(av.y, w1, fmaf(av.z, w2, bb))), 0.f);
    }
    ABfrag A;
    A.i = make_int4(cvt_pk_bf16(h1[0], h1[1]), cvt_pk_bf16(h1[2], h1[3]),
                    cvt_pk_bf16(h1[4], h1[5]), cvt_pk_bf16(h1[6], h1[7]));
    f32x4 da = __builtin_amdgcn_mfma_f32_16x16x32_bf16(A.s, wha.s, z, 0, 0, 0);
    f32x4 db = __builtin_amdgcn_mfma_f32_16x16x32_bf16(A.s, whb.s, z, 0, 0, 0);
    ep_xpose_write(xw, da, db, bha, bhb, cl, ch);
    A = xpose_read(xw, lane);
    da = __builtin_amdgcn_mfma_f32_16x16x32_bf16(A.s, wha.s, z, 0, 0, 0);
    db = __builtin_amdgcn_mfma_f32_16x16x32_bf16(A.s, whb.s, z, 0, 0, 0);
    ep_xpose_write(xw, da, db, bha, bhb, cl, ch);
    A = xpose_read(xw, lane);
    da = __builtin_amdgcn_mfma_f32_16x16x32_bf16(A.s, wea.s, z, 0, 0, 0);
    db = __builtin_amdgcn_mfma_f32_16x16x32_bf16(A.s, web.s, z, 0, 0, 0);
#pragma unroll
    for (int r = 0; r < 4; r++) {
      float h0 = fmaxf(da[r] + bea, 0.f);
      float hv = fmaxf(db[r] + beb, 0.f);
      int p = pb + cl * 4 + r;
      h_edge[(size_t)p * 16 + ch] = cvt_pk_bf16(h0, hv);
      xw[(cl * 4 + r) * 36 + ch] = h0;
      xw[(cl * 4 + r) * 36 + ch + 16] = hv;
    }
    A = xpose_read(xw, lane);
    f32x4 ma = __builtin_amdgcn_mfma_f32_16x16x32_bf16(A.s, w2a.s, z, 0, 0, 0);
    f32x4 mb = __builtin_amdgcn_mfma_f32_16x16x32_bf16(A.s, w2b.s, z, 0, 0, 0);
    int sa[4] = {sv.x, sv.y, sv.z, sv.w};
    int dda[4] = {dv.x, dv.y, dv.z, dv.w};
#pragma unroll
    for (int r = 0; r < 4; r++) {
      unsigned qv = Q0b[(size_t)sa[r] * 16 + ch];
      float xa = fmaxf(ma[r] + unpk_lo(qv), 0.f);
      float xb = fmaxf(mb[r] + unpk_hi(qv), 0.f);
      if (dda[r] != cur) {
        atomicAdd(&acc[(size_t)cur * 32 + ch], va);
        atomicAdd(&acc[(size_t)cur * 32 + ch + 16], vb);
        va = 0.f; vb = 0.f; cur = dda[r];
      }
      va += xa; vb += xb;
    }
  }
  atomicAdd(&acc[(size_t)cur * 32 + ch], va);
  atomicAdd(&acc[(size_t)cur * 32 + ch + 16], vb);
}

// ==== MFMA fused: edge update + message + scatter ====
// A-frag from interleaved h_edge: frag pos cl*8+kk holds channel kp = cl*4 + (kk>>1) + (kk&1)*16

template <int LAST>
__global__ __launch_bounds__(256) void k_fe_t(
    unsigned int* __restrict__ h_edge, const uint2* __restrict__ R2b,
    const unsigned* __restrict__ P3b, const int* __restrict__ src_p,
    const int* __restrict__ dst_p, float* __restrict__ acc,
    const float* __restrict__ We, const float* __restrict__ be,
    const float* __restrict__ Wn, const float* __restrict__ We3,
    float* __restrict__ partialE) {
  __shared__ float xp[4][16 * 36];
  int lane = threadIdx.x & 63, wid = threadIdx.x >> 6;
  int cl = lane >> 4, ch = lane & 15;
  ABfrag b1a, b1b, b2a, b2b, w3h, w3l;
#pragma unroll
  for (int kk = 0; kk < 8; kk++) {
    int k = cl * 8 + kk;
    int kp = cl * 4 + (kk >> 1) + (kk & 1) * 16;  // interleaved h_edge k-perm
    b1a.s[kk] = (short)f2b(We[kp * 32 + ch]);
    b1b.s[kk] = (short)f2b(We[kp * 32 + ch + 16]);
    b2a.s[kk] = (short)f2b(Wn[(32 + k) * 32 + ch]);
    b2b.s[kk] = (short)f2b(Wn[(32 + k) * 32 + ch + 16]);
    if (LAST) {
      unsigned short hi_, lo_;
      float v = (ch < 3) ? We3[k * 3 + ch] : 0.f;
      splitw(v, hi_, lo_); w3h.s[kk] = (short)hi_; w3l.s[kk] = (short)lo_;
    }
  }
  float bea = be[ch], beb = be[ch + 16];
  int blk = xcd_swz(blockIdx.x, gridDim.x);
  int p0 = (blk * 4 + wid) * 64;
  f32x4 z = {0.f, 0.f, 0.f, 0.f};
  float* xw = xp[wid];
  float va = 0.f, vb = 0.f;
  int cur = dst_p[p0 + cl * 4];
#pragma unroll
  for (int t = 0; t < 4; ++t) {
    int pb = p0 + t * 16;
    ABfrag A;
    A.i = *(const int4*)(h_edge + (size_t)(pb + ch) * 16 + cl * 4);
    int4 sv = *(const int4*)(src_p + pb + cl * 4);
    int4 dv = *(const int4*)(dst_p + pb + cl * 4);
    G8 g;
    gath(g, R2b, P3b, sv, dv, ch);
    f32x4 da = __builtin_amdgcn_mfma_f32_16x16x32_bf16(A.s, b1a.s, z, 0, 0, 0);
    f32x4 db = __builtin_amdgcn_mfma_f32_16x16x32_bf16(A.s, b1b.s, z, 0, 0, 0);
#pragma unroll
    for (int r = 0; r < 4; r++) {
      float h0 = fmaxf(da[r] + unpk_lo(g.r2[r].x) + unpk_lo(g.p3[r]) + bea, 0.f);
      float hv = fmaxf(db[r] + unpk_lo(g.r2[r].y) + unpk_hi(g.p3[r]) + beb, 0.f);
      int p = pb + cl * 4 + r;
      if (!LAST) h_edge[(size_t)p * 16 + ch] = cvt_pk_bf16(h0, hv);
      xw[(cl * 4 + r) * 36 + ch] = h0;
      xw[(cl * 4 + r) * 36 + ch + 16] = hv;
    }
    ABfrag A2 = xpose_read(xw, lane);
    f32x4 ma = __builtin_amdgcn_mfma_f32_16x16x32_bf16(A2.s, b2a.s, z, 0, 0, 0);
    f32x4 mb = __builtin_amdgcn_mfma_f32_16x16x32_bf16(A2.s, b2b.s, z, 0, 0, 0);
    if (LAST) {
      f32x4 dc = __builtin_amdgcn_mfma_f32_16x16x32_bf16(A2.s, w3l.s, z, 0, 0, 0);
      dc = __builtin_amdgcn_mfma_f32_16x16x32_bf16(A2.s, w3h.s, dc, 0, 0, 0);
      if (ch < 3) {
#pragma unroll
        for (int r = 0; r < 4; r++)
          partialE[(size_t)(pb + cl * 4 + r) * 3 + ch] = dc[r];
      }
    }
    int dda[4] = {dv.x, dv.y, dv.z, dv.w};
#pragma unroll
    for (int r = 0; r < 4; r++) {
      float xa = fmaxf(ma[r] + unpk_hi(g.r2[r].x), 0.f);
      float xb = fmaxf(mb[r] + unpk_hi(g.r2[r].y), 0.f);
      if (dda[r] != cur) {
        atomicAdd(&acc[(size_t)cur * 32 + ch], va);
        atomicAdd(&acc[(size_t)cur * 32 + ch + 16], vb);
        va = 0.f; vb = 0.f; cur = dda[r];
      }
      va += xa; vb += xb;
    }
  }
  atomicAdd(&acc[(size_t)cur * 32 + ch], va);
  atomicAdd(&acc[(size_t)cur * 32 + ch + 16], vb);
}

// ==== final: out[e] = ea[e] + partialE[inv[e]] + P2f[src[e]] + P3f[dst[e]] + b ====

__global__ __launch_bounds__(256) void k_fe4e(
    const float* __restrict__ partialE, const int* __restrict__ inv_p,
    const float* __restrict__ edge_attr, const int* __restrict__ src,
    const int* __restrict__ dstv, const float* __restrict__ P2f,
    const float* __restrict__ P3f, const float* __restrict__ be,
    float* __restrict__ out) {
  int e = blockIdx.x * blockDim.x + threadIdx.x;
  if (e >= NE) return;
  int p = inv_p[e];
  int s = src[e], d = dstv[e];
  float c0 = partialE[(size_t)p * 3 + 0];
  float c1 = partialE[(size_t)p * 3 + 1];
  float c2 = partialE[(size_t)p * 3 + 2];
  out[(size_t)e * 3 + 0] = edge_attr[(size_t)e * 3 + 0] + c0 + P2f[(size_t)s * 3 + 0] + P3f[(size_t)d * 3 + 0] + be[0];
  out[(size_t)e * 3 + 1] = edge_attr[(size_t)e * 3 + 1] + c1 + P2f[(size_t)s * 3 + 1] + P3f[(size_t)d * 3 + 1] + be[1];
  out[(size_t)e * 3 + 2] = edge_attr[(size_t)e * 3 + 2] + c2 + P2f[(size_t)s * 3 + 2] + P3f[(size_t)d * 3 + 2] + be[2];
}

// ============================ launch ============================

extern "C" void kernel_launch(void* const* d_in, const int* in_sizes, int n_in,
                              void* d_out, int out_size, void* d_ws, size_t ws_size,
                              hipStream_t stream) {
  const float* x = (const float*)d_in[0];
  const float* edge_attr = (const float*)d_in[1];
  const int* ei = (const int*)d_in[2];
  const int* src = ei;
  const int* dst = ei + NE;
  const float* w_enc_node_s = (const float*)d_in[3];
  const float* b_enc_node_s = (const float*)d_in[4];
  const float* w_enc_node_h = (const float*)d_in[5];
  const float* b_enc_node_h = (const float*)d_in[6];
  const float* w_enc_node_e = (const float*)d_in[7];
  const float* b_enc_node_e = (const float*)d_in[8];
  const float* w_enc_edge_s = (const float*)d_in[9];
  const float* b_enc_edge_s = (const float*)d_in[10];
  const float* w_enc_edge_h = (const float*)d_in[11];
  const float* b_enc_edge_h = (const float*)d_in[12];
  const float* w_enc_edge_e = (const float*)d_in[13];
  const float* b_enc_edge_e = (const float*)d_in[14];
  const float* w_node_s = (const float*)d_in[15];
  const float* w_node_h = (const float*)d_in[16];
  const float* w_node_e = (const float*)d_in[17];
  const float* w_edge_s = (const float*)d_in[18];
  const float* b_edge_s = (const float*)d_in[19];
  const float* w_edge_h = (const float*)d_in[20];
  const float* b_edge_h = (const float*)d_in[21];
  const float* w_edge_e = (const float*)d_in[22];
  const float* b_edge_e = (const float*)d_in[23];

  // workspace layout (~200 MB; 238 MB proven safe)
  char* w = (char*)d_ws;
  unsigned int* h_edge = (unsigned int*)w; w += (size_t)NE * 16 * 4;  // 102.4 MB
  int* inv_p = (int*)w;       w += (size_t)NE * 4;            // 6.4
  int* src_p = (int*)w;       w += (size_t)NE * 4;            // 6.4
  int* dst_p = (int*)w;       w += (size_t)NE * 4;            // 6.4
  int* perm = (int*)w;        w += (size_t)NE * 4;            // 6.4 (aliased: slot)
  int* slot = (int*)w;        w += (size_t)NE * 4;            // 6.4
  float4* ea4 = (float4*)w;   w += (size_t)NE * 16;           // 25.6 (aliased by partialE)
  float* acc = (float*)w;     w += (size_t)NN * D * 4;        // 12.8
  uint2* R2b = (uint2*)w;     w += (size_t)NN * 16 * 8;       // 12.8
  unsigned* P3b = (unsigned*)w; w += (size_t)NN * 16 * 4;     // 6.4 (aliased by P2f/P3f)
  unsigned* Q0b = (unsigned*)w; w += (size_t)NN * 16 * 4;     // 6.4
  float* P2f = (float*)P3b;
  float* P3f = (float*)P3b + (size_t)NN * 3;
  int* cnt = (int*)w;         w += (size_t)NN * 4;
  float* inv_deg = (float*)w; w += (size_t)NN * 4;
  int* rowptr = (int*)w;      w += (size_t)(NN + 1) * 4;
  int* partial = (int*)w;     w += 4096;
  float* partialE = (float*)ea4;  // alias: ea4 dead after k_fe0_m

  hipMemsetAsync(cnt, 0, (size_t)NN * 4, stream);
  hipMemsetAsync(acc, 0, (size_t)NN * D * 4, stream);

  // counting pass also records per-edge slot rank (coalesced write)
  k_deg<<<1024, 256, 0, stream>>>(dst, cnt, slot);
  k_invdeg<<<(NN + 255) / 256, 256, 0, stream>>>(cnt, inv_deg);
  int nb = (NN + 1023) / 1024;  // 98
  k_scanA<<<nb, 1024, 0, stream>>>(cnt, rowptr, partial);
  k_scanB<<<1, 128, 0, stream>>>(partial, nb);
  k_scanC<<<nb, 1024, 0, stream>>>(rowptr, partial);
  k_fillA<<<2048, 256, 0, stream>>>(dst, slot, rowptr, perm, inv_p);  // atomic-free
  k_fillB<<<2048, 256, 0, stream>>>(perm, src, dst, edge_attr, src_p, dst_p, ea4);

  k_node_enc_fin<<<1024, 256, 0, stream>>>(x, w_enc_node_s, b_enc_node_s,
                                           w_enc_node_h, b_enc_node_h,
                                           w_enc_node_e, b_enc_node_e,
                                           w_node_s, Q0b);

  int feb = NE / 256;  // 6250 blocks: 4 waves x 64 edges

  k_fe0_m<<<feb, 256, 0, stream>>>(ea4, Q0b, src_p, dst_p, acc,
                                   w_enc_edge_s, b_enc_edge_s,
                                   w_enc_edge_h, b_enc_edge_h,
                                   w_enc_edge_e, b_enc_edge_e,
                                   w_node_s, h_edge);
  k_fin<<<1024, 256, 0, stream>>>(acc, inv_deg, w_edge_s, w_node_h, R2b, P3b);
  k_fe_t<0><<<feb, 256, 0, stream>>>(h_edge, R2b, P3b, src_p, dst_p, acc,
                                     w_edge_s, b_edge_s, w_node_h, nullptr, nullptr);
  k_fin<<<1024, 256, 0, stream>>>(acc, inv_deg, w_edge_h, w_node_h, R2b, P3b);
  k_fe_t<0><<<feb, 256, 0, stream>>>(h_edge, R2b, P3b, src_p, dst_p, acc,
                                     w_edge_h, b_edge_h, w_node_h, nullptr, nullptr);
  k_fin<<<1024, 256, 0, stream>>>(acc, inv_deg, w_edge_h, w_node_e, R2b, P3b);
  k_fe_t<1><<<feb, 256, 0, stream>>>(h_edge, R2b, P3b, src_p, dst_p, acc,
                                     w_edge_h, b_edge_h, w_node_e, w_edge_e, partialE);
  k_fin4<<<1024, 256, 0, stream>>>(acc, inv_deg, w_edge_e, P2f, P3f);
  k_fe4e<<<(NE + 255) / 256, 256, 0, stream>>>(partialE, inv_p, edge_attr, src, dst,
                                               P2f, P3f, b_edge_e, (float*)d_out);
}

// Round 14
// 597.735 us; speedup vs baseline: 1.7827x; 1.3870x over previous
//
#include <hip/hip_runtime.h>

#define NN 100000
#define NE 1600000
#define D 32

typedef short short8 __attribute__((ext_vector_type(8)));
typedef float f32x4 __attribute__((ext_vector_type(4)));

union ABfrag { int4 i; short8 s; };

// ---------------- bf16 helpers ----------------

__device__ inline unsigned short f2b(float f) {
  unsigned int u = __float_as_uint(f);
  u = (u + 0x7FFFu + ((u >> 16) & 1u)) >> 16;
  return (unsigned short)u;
}
__device__ inline float b2f(unsigned short s) {
  return __uint_as_float(((unsigned int)s) << 16);
}
__device__ inline unsigned cvt_pk_bf16(float lo, float hi) {
  unsigned r;
  asm("v_cvt_pk_bf16_f32 %0, %1, %2" : "=v"(r) : "v"(lo), "v"(hi));
  return r;
}
__device__ inline void splitw(float w, unsigned short& h, unsigned short& l) {
  h = f2b(w);
  l = f2b(w - b2f(h));
}
__device__ inline float unpk_lo(unsigned u) { return b2f((unsigned short)(u & 0xFFFFu)); }
__device__ inline float unpk_hi(unsigned u) { return b2f((unsigned short)(u >> 16)); }

// XCD-aware bijective block swizzle (m204)
__device__ inline int xcd_swz(int bid, int nwg) {
  int q = nwg >> 3, r = nwg & 7;
  int xcd = bid & 7, j = bid >> 3;
  int base = (xcd < r) ? xcd * (q + 1) : r * (q + 1) + (xcd - r) * q;
  return base + j;
}

// ============================ CSR build ============================

// counting pass; ALSO records each edge's rank within its dst bucket (coalesced)
__global__ void k_deg(const int* __restrict__ dst, int* __restrict__ cnt,
                      int* __restrict__ slot) {
  int i = blockIdx.x * blockDim.x + threadIdx.x;
  int stride = gridDim.x * blockDim.x;
  for (int e = i; e < NE; e += stride) slot[e] = atomicAdd(&cnt[dst[e]], 1);
}

__global__ void k_invdeg(const int* __restrict__ cnt, float* __restrict__ inv) {
  int v = blockIdx.x * blockDim.x + threadIdx.x;
  if (v < NN) inv[v] = 1.0f / (float)max(cnt[v], 1);
}

__global__ __launch_bounds__(1024) void k_scanA(const int* __restrict__ cnt,
                                                int* __restrict__ rowptr,
                                                int* __restrict__ partial) {
  __shared__ int lds[1024];
  int t = threadIdx.x;
  int i = blockIdx.x * 1024 + t;
  int v = (i < NN) ? cnt[i] : 0;
  lds[t] = v;
  __syncthreads();
  for (int off = 1; off < 1024; off <<= 1) {
    int add = (t >= off) ? lds[t - off] : 0;
    __syncthreads();
    lds[t] += add;
    __syncthreads();
  }
  if (i < NN) rowptr[i] = lds[t] - v;
  if (t == 1023) partial[blockIdx.x] = lds[1023];
}

__global__ __launch_bounds__(128) void k_scanB(int* __restrict__ partial, int nb) {
  __shared__ int s[128];
  int t = threadIdx.x;
  int v = (t < nb) ? partial[t] : 0;
  s[t] = v;
  __syncthreads();
  for (int off = 1; off < 128; off <<= 1) {
    int add = (t >= off) ? s[t - off] : 0;
    __syncthreads();
    s[t] += add;
    __syncthreads();
  }
  if (t < nb) partial[t] = s[t] - v;  // exclusive
}

__global__ __launch_bounds__(1024) void k_scanC(int* __restrict__ rowptr,
                                                const int* __restrict__ partial) {
  int t = threadIdx.x;
  int i = blockIdx.x * 1024 + t;
  if (i < NN) rowptr[i] += partial[blockIdx.x];
  if (i == 0) rowptr[NN] = NE;
}

// phase A (ATOMIC-FREE): p = rowptr[dst[e]] + slot[e]; scatter only perm (4B)
__global__ void k_fillA(const int* __restrict__ dst, const int* __restrict__ slot,
                        const int* __restrict__ rowptr,
                        int* __restrict__ perm, int* __restrict__ inv_p) {
  int i = blockIdx.x * blockDim.x + threadIdx.x;
  int stride = gridDim.x * blockDim.x;
  for (int e = i; e < NE; e += stride) {
    int p = rowptr[dst[e]] + slot[e];
    perm[p] = e;
    inv_p[e] = p;
  }
}

// phase B: coalesced writes; scattered READS (L2/L3-absorbed)
__global__ void k_fillB(const int* __restrict__ perm, const int* __restrict__ src,
                        const int* __restrict__ dst, const float* __restrict__ ea,
                        int* __restrict__ src_p, int* __restrict__ dst_p,
                        float4* __restrict__ ea4) {
  int i = blockIdx.x * blockDim.x + threadIdx.x;
  int stride = gridDim.x * blockDim.x;
  for (int p = i; p < NE; p += stride) {
    int e = perm[p];
    src_p[p] = src[e];
    dst_p[p] = dst[e];
    ea4[p] = make_float4(ea[(size_t)e * 3 + 0], ea[(size_t)e * 3 + 1],
                         ea[(size_t)e * 3 + 2], 0.f);
  }
}

// ============================ VALU dot helper (node kernels) ============================

template <int K4>
__device__ inline float dot_lds(const float* __restrict__ lv, const float* __restrict__ Wc) {
  float acc = 0.f;
  const float4* v4 = (const float4*)lv;
#pragma unroll
  for (int kk = 0; kk < K4; kk++) {
    float4 h = v4[kk];
    acc = fmaf(h.x, Wc[4 * kk + 0], acc);
    acc = fmaf(h.y, Wc[4 * kk + 1], acc);
    acc = fmaf(h.z, Wc[4 * kk + 2], acc);
    acc = fmaf(h.w, Wc[4 * kk + 3], acc);
  }
  return acc;
}

// ============ node encoder + Q0 projection (packed bf16 pairs) ============

__global__ __launch_bounds__(256) void k_node_enc_fin(
    const float* __restrict__ x,
    const float* __restrict__ ws, const float* __restrict__ bs,
    const float* __restrict__ wh, const float* __restrict__ bh,
    const float* __restrict__ we, const float* __restrict__ be,
    const float* __restrict__ Wn,  // w_node_s, rows 0..31
    unsigned* __restrict__ Q0b) {  // [NN*16]: pk(q_ch, q_ch+16)
  __shared__ float hrow[8][D];
  int t = threadIdx.x, j = t & 31, g = t >> 5;
  float Ws = ws[j], Bs = bs[j], Bh = bh[j], Be = be[j];
  float Wh[D], We_[D], Wq[D];
#pragma unroll
  for (int k = 0; k < D; k++) {
    Wh[k] = wh[k * D + j];
    We_[k] = we[k * D + j];
    Wq[k] = Wn[k * D + j];
  }
  for (int v = blockIdx.x * 8 + g; v < NN; v += gridDim.x * 8) {
    float h = fmaxf(fmaf(x[v], Ws, Bs), 0.f);
#pragma unroll
    for (int L = 0; L < 2; L++) {
      hrow[g][j] = h;
      h = fmaxf(dot_lds<8>(hrow[g], Wh) + Bh, 0.f);
    }
    hrow[g][j] = h;
    h = fmaxf(dot_lds<8>(hrow[g], We_) + Be, 0.f);
    hrow[g][j] = h;
    float q = dot_lds<8>(hrow[g], Wq);
    hrow[g][j] = q;  // wave-sync staging (dot complete for all lanes)
    if (j < 16) Q0b[(size_t)v * 16 + j] = cvt_pk_bf16(hrow[g][j], hrow[g][j + 16]);
  }
}

// ==== node finalize: h = acc/deg; project P2/Q and P3, packed bf16 ====

__global__ __launch_bounds__(256) void k_fin(
    float* __restrict__ acc, const float* __restrict__ inv_deg,
    const float* __restrict__ We,  // [96][32] NEXT edge layer (rows 32..95 used)
    const float* __restrict__ Wn,  // [64][32] NEXT node msg (rows 0..31 used)
    uint2* __restrict__ R2b,       // [NN*16]: {pk(p2lo,qlo), pk(p2hi,qhi)}
    unsigned* __restrict__ P3b) {  // [NN*16]: pk(p3lo,p3hi)
  __shared__ float hrow[8][D];
  __shared__ float st[8][3][D];
  int t = threadIdx.x, j = t & 31, g = t >> 5;
  float Wp2[D], Wp3[D], Wq[D];
#pragma unroll
  for (int k = 0; k < D; k++) {
    Wp2[k] = We[(32 + k) * D + j];
    Wp3[k] = We[(64 + k) * D + j];
    Wq[k] = Wn[k * D + j];
  }
  for (int v = blockIdx.x * 8 + g; v < NN; v += gridDim.x * 8) {
    float h = acc[(size_t)v * D + j] * inv_deg[v];
    acc[(size_t)v * D + j] = 0.f;
    hrow[g][j] = h;
    float p2 = dot_lds<8>(hrow[g], Wp2);
    float q = dot_lds<8>(hrow[g], Wq);
    float p3 = dot_lds<8>(hrow[g], Wp3);
    st[g][0][j] = p2; st[g][1][j] = q; st[g][2][j] = p3;
    if (j < 16) {
      R2b[(size_t)v * 16 + j] = make_uint2(cvt_pk_bf16(st[g][0][j], st[g][1][j]),
                                           cvt_pk_bf16(st[g][0][j + 16], st[g][1][j + 16]));
      P3b[(size_t)v * 16 + j] = cvt_pk_bf16(st[g][2][j], st[g][2][j + 16]);
    }
  }
}

// ==== final node finalize: P2f/P3f [NN,3] ====

__global__ __launch_bounds__(256) void k_fin4(
    float* __restrict__ acc, const float* __restrict__ inv_deg,
    const float* __restrict__ We,  // w_edge_e [96][3]
    float* __restrict__ P2f, float* __restrict__ P3f) {
  __shared__ float hrow[8][D];
  int t = threadIdx.x, j = t & 31, g = t >> 5;
  for (int v = blockIdx.x * 8 + g; v < NN; v += gridDim.x * 8) {
    float h = acc[(size_t)v * D + j] * inv_deg[v];
    hrow[g][j] = h;
    if (j < 6) {
      int c = j % 3;
      int off = (j < 3) ? 32 : 64;
      float s = 0.f;
#pragma unroll
      for (int k = 0; k < D; k++) s = fmaf(hrow[g][k], We[(off + k) * 3 + c], s);
      if (j < 3) P2f[(size_t)v * 3 + c] = s;
      else       P3f[(size_t)v * 3 + c] = s;
    }
  }
}

// ============================ MFMA helpers ============================
// D layout (mfma_f32_16x16x32_bf16): col = lane&15, row = (lane>>4)*4 + reg
// A layout: row = lane&15, k = (lane>>4)*8 + i ;  B layout: col = lane&15, k = (lane>>4)*8 + i
// h_edge stores channels interleaved: position 2*c+h <-> channel c + 16*h (c=0..15)
// Stripe mapping: tile t, row i  <->  edge p0 + (i>>2)*16 + t*4 + (i&3)
//   => lane group cl's outputs across t = 16 CONSECUTIVE sorted edges.

__device__ inline void ep_xpose_write(float* __restrict__ xw, f32x4 da, f32x4 db,
                                      float ba, float bb, int cl, int ch) {
#pragma unroll
  for (int r = 0; r < 4; r++) {
    xw[(cl * 4 + r) * 36 + ch] = fmaxf(da[r] + ba, 0.f);
    xw[(cl * 4 + r) * 36 + ch + 16] = fmaxf(db[r] + bb, 0.f);
  }
}

__device__ inline ABfrag xpose_read(const float* __restrict__ xw, int lane) {
  const float4* p = (const float4*)(xw + (lane & 15) * 36 + (lane >> 4) * 8);
  float4 v0 = p[0], v1 = p[1];
  ABfrag A;
  A.i = make_int4(cvt_pk_bf16(v0.x, v0.y), cvt_pk_bf16(v0.z, v0.w),
                  cvt_pk_bf16(v1.x, v1.y), cvt_pk_bf16(v1.z, v1.w));
  return A;
}

// gather bundle for one 16-edge tile (packed bf16 node rows)
struct G8 { uint2 r2[4]; unsigned p3[4]; };

__device__ inline void gath(G8& g, const uint2* __restrict__ R2b,
                            const unsigned* __restrict__ P3b, int4 sv, int4 dv, int ch) {
  int sa[4] = {sv.x, sv.y, sv.z, sv.w};
  int da[4] = {dv.x, dv.y, dv.z, dv.w};
#pragma unroll
  for (int r = 0; r < 4; r++) {
    g.r2[r] = R2b[(size_t)sa[r] * 16 + ch];
    g.p3[r] = P3b[(size_t)da[r] * 16 + ch];
  }
}

// ==== MFMA fused: edge encoder + first message + scatter (layer-major, striped) ====

__global__ __launch_bounds__(256) void k_fe0_m(
    const float4* __restrict__ ea4, const unsigned* __restrict__ Q0b,
    const int* __restrict__ src_p, const int* __restrict__ dst_p,
    float* __restrict__ acc,
    const float* __restrict__ ws, const float* __restrict__ bs,
    const float* __restrict__ wh, const float* __restrict__ bh,
    const float* __restrict__ we, const float* __restrict__ be,
    const float* __restrict__ Wn,  // w_node_s rows 32..63
    unsigned int* __restrict__ h_edge) {  // packed interleaved bf16 pairs
  __shared__ float xp[4][4][16 * 36];  // [wave][tile][...] = 36,864 B
  int lane = threadIdx.x & 63, wid = threadIdx.x >> 6;
  int cl = lane >> 4, ch = lane & 15;
  unsigned wp01[8], wp2b[8];
#pragma unroll
  for (int kk = 0; kk < 8; kk++) {
    int c = cl * 8 + kk;
    wp01[kk] = ((unsigned)f2b(ws[32 + c]) << 16) | f2b(ws[c]);
    wp2b[kk] = ((unsigned)f2b(bs[c]) << 16) | f2b(ws[64 + c]);
  }
  ABfrag wha, whb, wea, web, w2a, w2b;
#pragma unroll
  for (int kk = 0; kk < 8; kk++) {
    int k = cl * 8 + kk;
    wha.s[kk] = (short)f2b(wh[k * 32 + ch]);
    whb.s[kk] = (short)f2b(wh[k * 32 + ch + 16]);
    wea.s[kk] = (short)f2b(we[k * 32 + ch]);
    web.s[kk] = (short)f2b(we[k * 32 + ch + 16]);
    w2a.s[kk] = (short)f2b(Wn[(32 + k) * 32 + ch]);
    w2b.s[kk] = (short)f2b(Wn[(32 + k) * 32 + ch + 16]);
  }
  float bha = bh[ch], bhb = bh[ch + 16], bea = be[ch], beb = be[ch + 16];
  int blk = xcd_swz(blockIdx.x, gridDim.x);
  int p0 = (blk * 4 + wid) * 64;
  f32x4 z = {0.f, 0.f, 0.f, 0.f};
  int echA = ((ch >> 2) << 4) + (ch & 3);  // input-row edge offset (+ t*4)
  // phase 0: all coalesced edge-attr loads
  float4 av[4];
#pragma unroll
  for (int t = 0; t < 4; t++) av[t] = ea4[p0 + echA + t * 4];
  // phase 1: layer 1 (3 -> 32) in A-frag layout, all tiles
  ABfrag A[4];
#pragma unroll
  for (int t = 0; t < 4; t++) {
    float h1[8];
#pragma unroll
    for (int kk = 0; kk < 8; kk++) {
      float w0 = unpk_lo(wp01[kk]), w1 = unpk_hi(wp01[kk]);
      float w2 = unpk_lo(wp2b[kk]), bb = unpk_hi(wp2b[kk]);
      h1[kk] = fmaxf(fmaf(av[t].x, w0, fmaf(av[t].y, w1, fmaf(av[t].z, w2, bb))), 0.f);
    }
    A[t].i = make_int4(cvt_pk_bf16(h1[0], h1[1]), cvt_pk_bf16(h1[2], h1[3]),
                       cvt_pk_bf16(h1[4], h1[5]), cvt_pk_bf16(h1[6], h1[7]));
  }
  // phase 2: layer 2 (wh), layer-major
#pragma unroll
  for (int t = 0; t < 4; t++) {
    f32x4 da = __builtin_amdgcn_mfma_f32_16x16x32_bf16(A[t].s, wha.s, z, 0, 0, 0);
    f32x4 db = __builtin_amdgcn_mfma_f32_16x16x32_bf16(A[t].s, whb.s, z, 0, 0, 0);
    ep_xpose_write(xp[wid][t], da, db, bha, bhb, cl, ch);
  }
#pragma unroll
  for (int t = 0; t < 4; t++) A[t] = xpose_read(xp[wid][t], lane);
  // phase 3: layer 3 (wh)
#pragma unroll
  for (int t = 0; t < 4; t++) {
    f32x4 da = __builtin_amdgcn_mfma_f32_16x16x32_bf16(A[t].s, wha.s, z, 0, 0, 0);
    f32x4 db = __builtin_amdgcn_mfma_f32_16x16x32_bf16(A[t].s, whb.s, z, 0, 0, 0);
    ep_xpose_write(xp[wid][t], da, db, bha, bhb, cl, ch);
  }
#pragma unroll
  for (int t = 0; t < 4; t++) A[t] = xpose_read(xp[wid][t], lane);
  // phase 4: issue index + Q gathers early, then layer 4 (we) -> h_edge + xpose
  int4 dv[4];
  unsigned qg[4][4];
#pragma unroll
  for (int t = 0; t < 4; t++) {
    int base = p0 + cl * 16 + t * 4;
    int4 sv = *(const int4*)(src_p + base);
    dv[t] = *(const int4*)(dst_p + base);
    int sa[4] = {sv.x, sv.y, sv.z, sv.w};
#pragma unroll
    for (int r = 0; r < 4; r++) qg[t][r] = Q0b[(size_t)sa[r] * 16 + ch];
  }
#pragma unroll
  for (int t = 0; t < 4; t++) {
    f32x4 da = __builtin_amdgcn_mfma_f32_16x16x32_bf16(A[t].s, wea.s, z, 0, 0, 0);
    f32x4 db = __builtin_amdgcn_mfma_f32_16x16x32_bf16(A[t].s, web.s, z, 0, 0, 0);
#pragma unroll
    for (int r = 0; r < 4; r++) {
      float h0 = fmaxf(da[r] + bea, 0.f);
      float hv = fmaxf(db[r] + beb, 0.f);
      int p = p0 + cl * 16 + t * 4 + r;
      h_edge[(size_t)p * 16 + ch] = cvt_pk_bf16(h0, hv);
      xp[wid][t][(cl * 4 + r) * 36 + ch] = h0;
      xp[wid][t][(cl * 4 + r) * 36 + ch + 16] = hv;
    }
  }
#pragma unroll
  for (int t = 0; t < 4; t++) A[t] = xpose_read(xp[wid][t], lane);
  // phase 5: message + fully-merged scatter (lane's 16 edges are consecutive)
  float va = 0.f, vb = 0.f;
  int cur = dv[0].x;
#pragma unroll
  for (int t = 0; t < 4; t++) {
    f32x4 ma = __builtin_amdgcn_mfma_f32_16x16x32_bf16(A[t].s, w2a.s, z, 0, 0, 0);
    f32x4 mb = __builtin_amdgcn_mfma_f32_16x16x32_bf16(A[t].s, w2b.s, z, 0, 0, 0);
    int dda[4] = {dv[t].x, dv[t].y, dv[t].z, dv[t].w};
#pragma unroll
    for (int r = 0; r < 4; r++) {
      float xa = fmaxf(ma[r] + unpk_lo(qg[t][r]), 0.f);
      float xb = fmaxf(mb[r] + unpk_hi(qg[t][r]), 0.f);
      if (dda[r] != cur) {
        atomicAdd(&acc[(size_t)cur * 32 + ch], va);
        atomicAdd(&acc[(size_t)cur * 32 + ch + 16], vb);
        va = 0.f; vb = 0.f; cur = dda[r];
      }
      va += xa; vb += xb;
    }
  }
  atomicAdd(&acc[(size_t)cur * 32 + ch], va);
  atomicAdd(&acc[(size_t)cur * 32 + ch + 16], vb);
}

// ==== MFMA fused: edge update + message + scatter (striped) ====
// A-frag from interleaved h_edge: frag pos cl*8+kk holds channel kp = cl*4 + (kk>>1) + (kk&1)*16

template <int LAST>
__global__ __launch_bounds__(256) void k_fe_t(
    unsigned int* __restrict__ h_edge, const uint2* __restrict__ R2b,
    const unsigned* __restrict__ P3b, const int* __restrict__ src_p,
    const int* __restrict__ dst_p, float* __restrict__ acc,
    const float* __restrict__ We, const float* __restrict__ be,
    const float* __restrict__ Wn, const float* __restrict__ We3,
    float* __restrict__ partialE) {
  __shared__ float xp[4][16 * 36];
  int lane = threadIdx.x & 63, wid = threadIdx.x >> 6;
  int cl = lane >> 4, ch = lane & 15;
  ABfrag b1a, b1b, b2a, b2b, w3h, w3l;
#pragma unroll
  for (int kk = 0; kk < 8; kk++) {
    int k = cl * 8 + kk;
    int kp = cl * 4 + (kk >> 1) + (kk & 1) * 16;  // interleaved h_edge k-perm
    b1a.s[kk] = (short)f2b(We[kp * 32 + ch]);
    b1b.s[kk] = (short)f2b(We[kp * 32 + ch + 16]);
    b2a.s[kk] = (short)f2b(Wn[(32 + k) * 32 + ch]);
    b2b.s[kk] = (short)f2b(Wn[(32 + k) * 32 + ch + 16]);
    if (LAST) {
      unsigned short hi_, lo_;
      float v = (ch < 3) ? We3[k * 3 + ch] : 0.f;
      splitw(v, hi_, lo_); w3h.s[kk] = (short)hi_; w3l.s[kk] = (short)lo_;
    }
  }
  float bea = be[ch], beb = be[ch + 16];
  int blk = xcd_swz(blockIdx.x, gridDim.x);
  int p0 = (blk * 4 + wid) * 64;
  f32x4 z = {0.f, 0.f, 0.f, 0.f};
  float* xw = xp[wid];
  int echA = ((ch >> 2) << 4) + (ch & 3);  // input-row edge offset (+ t*4)
  float va = 0.f, vb = 0.f;
  int cur = dst_p[p0 + cl * 16];
#pragma unroll
  for (int t = 0; t < 4; ++t) {
    int base = p0 + cl * 16 + t * 4;
    ABfrag A;
    A.i = *(const int4*)(h_edge + (size_t)(p0 + echA + t * 4) * 16 + cl * 4);
    int4 sv = *(const int4*)(src_p + base);
    int4 dv = *(const int4*)(dst_p + base);
    G8 g;
    gath(g, R2b, P3b, sv, dv, ch);
    f32x4 da = __builtin_amdgcn_mfma_f32_16x16x32_bf16(A.s, b1a.s, z, 0, 0, 0);
    f32x4 db = __builtin_amdgcn_mfma_f32_16x16x32_bf16(A.s, b1b.s, z, 0, 0, 0);
#pragma unroll
    for (int r = 0; r < 4; r++) {
      float h0 = fmaxf(da[r] + unpk_lo(g.r2[r].x) + unpk_lo(g.p3[r]) + bea, 0.f);
      float hv = fmaxf(db[r] + unpk_lo(g.r2[r].y) + unpk_hi(g.p3[r]) + beb, 0.f);
      int p = base + r;
      if (!LAST) h_edge[(size_t)p * 16 + ch] = cvt_pk_bf16(h0, hv);
      xw[(cl * 4 + r) * 36 + ch] = h0;
      xw[(cl * 4 + r) * 36 + ch + 16] = hv;
    }
    ABfrag A2 = xpose_read(xw, lane);
    f32x4 ma = __builtin_amdgcn_mfma_f32_16x16x32_bf16(A2.s, b2a.s, z, 0, 0, 0);
    f32x4 mb = __builtin_amdgcn_mfma_f32_16x16x32_bf16(A2.s, b2b.s, z, 0, 0, 0);
    if (LAST) {
      f32x4 dc = __builtin_amdgcn_mfma_f32_16x16x32_bf16(A2.s, w3l.s, z, 0, 0, 0);
      dc = __builtin_amdgcn_mfma_f32_16x16x32_bf16(A2.s, w3h.s, dc, 0, 0, 0);
      if (ch < 3) {
#pragma unroll
        for (int r = 0; r < 4; r++)
          partialE[(size_t)(base + r) * 3 + ch] = dc[r];
      }
    }
    int dda[4] = {dv.x, dv.y, dv.z, dv.w};
#pragma unroll
    for (int r = 0; r < 4; r++) {
      float xa = fmaxf(ma[r] + unpk_hi(g.r2[r].x), 0.f);
      float xb = fmaxf(mb[r] + unpk_hi(g.r2[r].y), 0.f);
      if (dda[r] != cur) {
        atomicAdd(&acc[(size_t)cur * 32 + ch], va);
        atomicAdd(&acc[(size_t)cur * 32 + ch + 16], vb);
        va = 0.f; vb = 0.f; cur = dda[r];
      }
      va += xa; vb += xb;
    }
  }
  atomicAdd(&acc[(size_t)cur * 32 + ch], va);
  atomicAdd(&acc[(size_t)cur * 32 + ch + 16], vb);
}

// ==== final: out[e] = ea[e] + partialE[inv[e]] + P2f[src[e]] + P3f[dst[e]] + b ====

__global__ __launch_bounds__(256) void k_fe4e(
    const float* __restrict__ partialE, const int* __restrict__ inv_p,
    const float* __restrict__ edge_attr, const int* __restrict__ src,
    const int* __restrict__ dstv, const float* __restrict__ P2f,
    const float* __restrict__ P3f, const float* __restrict__ be,
    float* __restrict__ out) {
  int e = blockIdx.x * blockDim.x + threadIdx.x;
  if (e >= NE) return;
  int p = inv_p[e];
  int s = src[e], d = dstv[e];
  float c0 = partialE[(size_t)p * 3 + 0];
  float c1 = partialE[(size_t)p * 3 + 1];
  float c2 = partialE[(size_t)p * 3 + 2];
  out[(size_t)e * 3 + 0] = edge_attr[(size_t)e * 3 + 0] + c0 + P2f[(size_t)s * 3 + 0] + P3f[(size_t)d * 3 + 0] + be[0];
  out[(size_t)e * 3 + 1] = edge_attr[(size_t)e * 3 + 1] + c1 + P2f[(size_t)s * 3 + 1] + P3f[(size_t)d * 3 + 1] + be[1];
  out[(size_t)e * 3 + 2] = edge_attr[(size_t)e * 3 + 2] + c2 + P2f[(size_t)s * 3 + 2] + P3f[(size_t)d * 3 + 2] + be[2];
}

// ============================ launch ============================

extern "C" void kernel_launch(void* const* d_in, const int* in_sizes, int n_in,
                              void* d_out, int out_size, void* d_ws, size_t ws_size,
                              hipStream_t stream) {
  const float* x = (const float*)d_in[0];
  const float* edge_attr = (const float*)d_in[1];
  const int* ei = (const int*)d_in[2];
  const int* src = ei;
  const int* dst = ei + NE;
  const float* w_enc_node_s = (const float*)d_in[3];
  const float* b_enc_node_s = (const float*)d_in[4];
  const float* w_enc_node_h = (const float*)d_in[5];
  const float* b_enc_node_h = (const float*)d_in[6];
  const float* w_enc_node_e = (const float*)d_in[7];
  const float* b_enc_node_e = (const float*)d_in[8];
  const float* w_enc_edge_s = (const float*)d_in[9];
  const float* b_enc_edge_s = (const float*)d_in[10];
  const float* w_enc_edge_h = (const float*)d_in[11];
  const float* b_enc_edge_h = (const float*)d_in[12];
  const float* w_enc_edge_e = (const float*)d_in[13];
  const float* b_enc_edge_e = (const float*)d_in[14];
  const float* w_node_s = (const float*)d_in[15];
  const float* w_node_h = (const float*)d_in[16];
  const float* w_node_e = (const float*)d_in[17];
  const float* w_edge_s = (const float*)d_in[18];
  const float* b_edge_s = (const float*)d_in[19];
  const float* w_edge_h = (const float*)d_in[20];
  const float* b_edge_h = (const float*)d_in[21];
  const float* w_edge_e = (const float*)d_in[22];
  const float* b_edge_e = (const float*)d_in[23];

  // workspace layout (~200 MB; 238 MB proven safe)
  char* w = (char*)d_ws;
  unsigned int* h_edge = (unsigned int*)w; w += (size_t)NE * 16 * 4;  // 102.4 MB
  int* inv_p = (int*)w;       w += (size_t)NE * 4;            // 6.4
  int* src_p = (int*)w;       w += (size_t)NE * 4;            // 6.4
  int* dst_p = (int*)w;       w += (size_t)NE * 4;            // 6.4
  int* perm = (int*)w;        w += (size_t)NE * 4;            // 6.4
  int* slot = (int*)w;        w += (size_t)NE * 4;            // 6.4
  float4* ea4 = (float4*)w;   w += (size_t)NE * 16;           // 25.6 (aliased by partialE)
  float* acc = (float*)w;     w += (size_t)NN * D * 4;        // 12.8
  uint2* R2b = (uint2*)w;     w += (size_t)NN * 16 * 8;       // 12.8
  unsigned* P3b = (unsigned*)w; w += (size_t)NN * 16 * 4;     // 6.4 (aliased by P2f/P3f)
  unsigned* Q0b = (unsigned*)w; w += (size_t)NN * 16 * 4;     // 6.4
  float* P2f = (float*)P3b;
  float* P3f = (float*)P3b + (size_t)NN * 3;
  int* cnt = (int*)w;         w += (size_t)NN * 4;
  float* inv_deg = (float*)w; w += (size_t)NN * 4;
  int* rowptr = (int*)w;      w += (size_t)(NN + 1) * 4;
  int* partial = (int*)w;     w += 4096;
  float* partialE = (float*)ea4;  // alias: ea4 dead after k_fe0_m

  hipMemsetAsync(cnt, 0, (size_t)NN * 4, stream);
  hipMemsetAsync(acc, 0, (size_t)NN * D * 4, stream);

  k_deg<<<1024, 256, 0, stream>>>(dst, cnt, slot);
  k_invdeg<<<(NN + 255) / 256, 256, 0, stream>>>(cnt, inv_deg);
  int nb = (NN + 1023) / 1024;  // 98
  k_scanA<<<nb, 1024, 0, stream>>>(cnt, rowptr, partial);
  k_scanB<<<1, 128, 0, stream>>>(partial, nb);
  k_scanC<<<nb, 1024, 0, stream>>>(rowptr, partial);
  k_fillA<<<2048, 256, 0, stream>>>(dst, slot, rowptr, perm, inv_p);  // atomic-free
  k_fillB<<<2048, 256, 0, stream>>>(perm, src, dst, edge_attr, src_p, dst_p, ea4);

  k_node_enc_fin<<<1024, 256, 0, stream>>>(x, w_enc_node_s, b_enc_node_s,
                                           w_enc_node_h, b_enc_node_h,
                                           w_enc_node_e, b_enc_node_e,
                                           w_node_s, Q0b);

  int feb = NE / 256;  // 6250 blocks: 4 waves x 64 edges

  k_fe0_m<<<feb, 256, 0, stream>>>(ea4, Q0b, src_p, dst_p, acc,
                                   w_enc_edge_s, b_enc_edge_s,
                                   w_enc_edge_h, b_enc_edge_h,
                                   w_enc_edge_e, b_enc_edge_e,
                                   w_node_s, h_edge);
  k_fin<<<1024, 256, 0, stream>>>(acc, inv_deg, w_edge_s, w_node_h, R2b, P3b);
  k_fe_t<0><<<feb, 256, 0, stream>>>(h_edge, R2b, P3b, src_p, dst_p, acc,
                                     w_edge_s, b_edge_s, w_node_h, nullptr, nullptr);
  k_fin<<<1024, 256, 0, stream>>>(acc, inv_deg, w_edge_h, w_node_h, R2b, P3b);
  k_fe_t<0><<<feb, 256, 0, stream>>>(h_edge, R2b, P3b, src_p, dst_p, acc,
                                     w_edge_h, b_edge_h, w_node_h, nullptr, nullptr);
  k_fin<<<1024, 256, 0, stream>>>(acc, inv_deg, w_edge_h, w_node_e, R2b, P3b);
  k_fe_t<1><<<feb, 256, 0, stream>>>(h_edge, R2b, P3b, src_p, dst_p, acc,
                                     w_edge_h, b_edge_h, w_node_e, w_edge_e, partialE);
  k_fin4<<<1024, 256, 0, stream>>>(acc, inv_deg, w_edge_e, P2f, P3f);
  k_fe4e<<<(NE + 255) / 256, 256, 0, stream>>>(partialE, inv_p, edge_attr, src, dst,
                                               P2f, P3f, b_edge_e, (float*)d_out);
}

// Round 15
// 577.541 us; speedup vs baseline: 1.8450x; 1.0350x over previous
//
#include <hip/hip_runtime.h>

#define NN 100000
#define NE 1600000
#define D 32

typedef short short8 __attribute__((ext_vector_type(8)));
typedef float f32x4 __attribute__((ext_vector_type(4)));

union ABfrag { int4 i; short8 s; };

// ---------------- bf16 helpers ----------------

__device__ inline unsigned short f2b(float f) {
  unsigned int u = __float_as_uint(f);
  u = (u + 0x7FFFu + ((u >> 16) & 1u)) >> 16;
  return (unsigned short)u;
}
__device__ inline float b2f(unsigned short s) {
  return __uint_as_float(((unsigned int)s) << 16);
}
__device__ inline unsigned cvt_pk_bf16(float lo, float hi) {
  unsigned r;
  asm("v_cvt_pk_bf16_f32 %0, %1, %2" : "=v"(r) : "v"(lo), "v"(hi));
  return r;
}
__device__ inline void splitw(float w, unsigned short& h, unsigned short& l) {
  h = f2b(w);
  l = f2b(w - b2f(h));
}
__device__ inline float unpk_lo(unsigned u) { return b2f((unsigned short)(u & 0xFFFFu)); }
__device__ inline float unpk_hi(unsigned u) { return b2f((unsigned short)(u >> 16)); }

// XCD-aware bijective block swizzle (m204)
__device__ inline int xcd_swz(int bid, int nwg) {
  int q = nwg >> 3, r = nwg & 7;
  int xcd = bid & 7, j = bid >> 3;
  int base = (xcd < r) ? xcd * (q + 1) : r * (q + 1) + (xcd - r) * q;
  return base + j;
}

// ============================ CSR build ============================

// counting pass; ALSO records each edge's rank within its dst bucket (coalesced)
__global__ void k_deg(const int* __restrict__ dst, int* __restrict__ cnt,
                      int* __restrict__ slot) {
  int i = blockIdx.x * blockDim.x + threadIdx.x;
  int stride = gridDim.x * blockDim.x;
  for (int e = i; e < NE; e += stride) slot[e] = atomicAdd(&cnt[dst[e]], 1);
}

__global__ void k_invdeg(const int* __restrict__ cnt, float* __restrict__ inv) {
  int v = blockIdx.x * blockDim.x + threadIdx.x;
  if (v < NN) inv[v] = 1.0f / (float)max(cnt[v], 1);
}

__global__ __launch_bounds__(1024) void k_scanA(const int* __restrict__ cnt,
                                                int* __restrict__ rowptr,
                                                int* __restrict__ partial) {
  __shared__ int lds[1024];
  int t = threadIdx.x;
  int i = blockIdx.x * 1024 + t;
  int v = (i < NN) ? cnt[i] : 0;
  lds[t] = v;
  __syncthreads();
  for (int off = 1; off < 1024; off <<= 1) {
    int add = (t >= off) ? lds[t - off] : 0;
    __syncthreads();
    lds[t] += add;
    __syncthreads();
  }
  if (i < NN) rowptr[i] = lds[t] - v;
  if (t == 1023) partial[blockIdx.x] = lds[1023];
}

__global__ __launch_bounds__(128) void k_scanB(int* __restrict__ partial, int nb) {
  __shared__ int s[128];
  int t = threadIdx.x;
  int v = (t < nb) ? partial[t] : 0;
  s[t] = v;
  __syncthreads();
  for (int off = 1; off < 128; off <<= 1) {
    int add = (t >= off) ? s[t - off] : 0;
    __syncthreads();
    s[t] += add;
    __syncthreads();
  }
  if (t < nb) partial[t] = s[t] - v;  // exclusive
}

__global__ __launch_bounds__(1024) void k_scanC(int* __restrict__ rowptr,
                                                const int* __restrict__ partial) {
  int t = threadIdx.x;
  int i = blockIdx.x * 1024 + t;
  if (i < NN) rowptr[i] += partial[blockIdx.x];
  if (i == 0) rowptr[NN] = NE;
}

// dst_p needs NO gather: expand from rowptr (coalesced-ish writes)
__global__ void k_expand(const int* __restrict__ rowptr, int* __restrict__ dst_p) {
  int v = blockIdx.x * blockDim.x + threadIdx.x;
  if (v >= NN) return;
  int b = rowptr[v], e = rowptr[v + 1];
  for (int p = b; p < e; p++) dst_p[p] = v;
}

// phase A (ATOMIC-FREE): p = rowptr[dst[e]] + slot[e]; scatter only perm (4B)
__global__ void k_fillA(const int* __restrict__ dst, const int* __restrict__ slot,
                        const int* __restrict__ rowptr,
                        int* __restrict__ perm, int* __restrict__ inv_p) {
  int i = blockIdx.x * blockDim.x + threadIdx.x;
  int stride = gridDim.x * blockDim.x;
  for (int e = i; e < NE; e += stride) {
    int p = rowptr[dst[e]] + slot[e];
    perm[p] = e;
    inv_p[e] = p;
  }
}

// phase B: coalesced writes; scattered READS of src/ea only (dst via k_expand)
__global__ void k_fillB(const int* __restrict__ perm, const int* __restrict__ src,
                        const float* __restrict__ ea,
                        int* __restrict__ src_p, uint2* __restrict__ ea2) {
  int i = blockIdx.x * blockDim.x + threadIdx.x;
  int stride = gridDim.x * blockDim.x;
  for (int p = i; p < NE; p += stride) {
    int e = perm[p];
    src_p[p] = src[e];
    ea2[p] = make_uint2(cvt_pk_bf16(ea[(size_t)e * 3 + 0], ea[(size_t)e * 3 + 1]),
                        cvt_pk_bf16(ea[(size_t)e * 3 + 2], 0.f));
  }
}

// ============================ VALU dot helper (node kernels) ============================

template <int K4>
__device__ inline float dot_lds(const float* __restrict__ lv, const float* __restrict__ Wc) {
  float acc = 0.f;
  const float4* v4 = (const float4*)lv;
#pragma unroll
  for (int kk = 0; kk < K4; kk++) {
    float4 h = v4[kk];
    acc = fmaf(h.x, Wc[4 * kk + 0], acc);
    acc = fmaf(h.y, Wc[4 * kk + 1], acc);
    acc = fmaf(h.z, Wc[4 * kk + 2], acc);
    acc = fmaf(h.w, Wc[4 * kk + 3], acc);
  }
  return acc;
}

// ============ node encoder + Q0 projection (packed bf16 pairs) ============

__global__ __launch_bounds__(256) void k_node_enc_fin(
    const float* __restrict__ x,
    const float* __restrict__ ws, const float* __restrict__ bs,
    const float* __restrict__ wh, const float* __restrict__ bh,
    const float* __restrict__ we, const float* __restrict__ be,
    const float* __restrict__ Wn,  // w_node_s, rows 0..31
    unsigned* __restrict__ Q0b) {  // [NN*16]: pk(q_ch, q_ch+16)
  __shared__ float hrow[8][D];
  int t = threadIdx.x, j = t & 31, g = t >> 5;
  float Ws = ws[j], Bs = bs[j], Bh = bh[j], Be = be[j];
  float Wh[D], We_[D], Wq[D];
#pragma unroll
  for (int k = 0; k < D; k++) {
    Wh[k] = wh[k * D + j];
    We_[k] = we[k * D + j];
    Wq[k] = Wn[k * D + j];
  }
  for (int v = blockIdx.x * 8 + g; v < NN; v += gridDim.x * 8) {
    float h = fmaxf(fmaf(x[v], Ws, Bs), 0.f);
#pragma unroll
    for (int L = 0; L < 2; L++) {
      hrow[g][j] = h;
      h = fmaxf(dot_lds<8>(hrow[g], Wh) + Bh, 0.f);
    }
    hrow[g][j] = h;
    h = fmaxf(dot_lds<8>(hrow[g], We_) + Be, 0.f);
    hrow[g][j] = h;
    float q = dot_lds<8>(hrow[g], Wq);
    hrow[g][j] = q;  // wave-sync staging (dot complete for all lanes)
    if (j < 16) Q0b[(size_t)v * 16 + j] = cvt_pk_bf16(hrow[g][j], hrow[g][j + 16]);
  }
}

// ==== node finalize: h = acc/deg; project P2/Q and P3, packed bf16 ====

__global__ __launch_bounds__(256) void k_fin(
    float* __restrict__ acc, const float* __restrict__ inv_deg,
    const float* __restrict__ We,  // [96][32] NEXT edge layer (rows 32..95 used)
    const float* __restrict__ Wn,  // [64][32] NEXT node msg (rows 0..31 used)
    uint2* __restrict__ R2b,       // [NN*16]: {pk(p2lo,qlo), pk(p2hi,qhi)}
    unsigned* __restrict__ P3b) {  // [NN*16]: pk(p3lo,p3hi)
  __shared__ float hrow[8][D];
  __shared__ float st[8][3][D];
  int t = threadIdx.x, j = t & 31, g = t >> 5;
  float Wp2[D], Wp3[D], Wq[D];
#pragma unroll
  for (int k = 0; k < D; k++) {
    Wp2[k] = We[(32 + k) * D + j];
    Wp3[k] = We[(64 + k) * D + j];
    Wq[k] = Wn[k * D + j];
  }
  for (int v = blockIdx.x * 8 + g; v < NN; v += gridDim.x * 8) {
    float h = acc[(size_t)v * D + j] * inv_deg[v];
    acc[(size_t)v * D + j] = 0.f;
    hrow[g][j] = h;
    float p2 = dot_lds<8>(hrow[g], Wp2);
    float q = dot_lds<8>(hrow[g], Wq);
    float p3 = dot_lds<8>(hrow[g], Wp3);
    st[g][0][j] = p2; st[g][1][j] = q; st[g][2][j] = p3;
    if (j < 16) {
      R2b[(size_t)v * 16 + j] = make_uint2(cvt_pk_bf16(st[g][0][j], st[g][1][j]),
                                           cvt_pk_bf16(st[g][0][j + 16], st[g][1][j + 16]));
      P3b[(size_t)v * 16 + j] = cvt_pk_bf16(st[g][2][j], st[g][2][j + 16]);
    }
  }
}

// ==== final node finalize: P2f/P3f [NN,3] ====

__global__ __launch_bounds__(256) void k_fin4(
    float* __restrict__ acc, const float* __restrict__ inv_deg,
    const float* __restrict__ We,  // w_edge_e [96][3]
    float* __restrict__ P2f, float* __restrict__ P3f) {
  __shared__ float hrow[8][D];
  int t = threadIdx.x, j = t & 31, g = t >> 5;
  for (int v = blockIdx.x * 8 + g; v < NN; v += gridDim.x * 8) {
    float h = acc[(size_t)v * D + j] * inv_deg[v];
    hrow[g][j] = h;
    if (j < 6) {
      int c = j % 3;
      int off = (j < 3) ? 32 : 64;
      float s = 0.f;
#pragma unroll
      for (int k = 0; k < D; k++) s = fmaf(hrow[g][k], We[(off + k) * 3 + c], s);
      if (j < 3) P2f[(size_t)v * 3 + c] = s;
      else       P3f[(size_t)v * 3 + c] = s;
    }
  }
}

// ============================ MFMA helpers ============================
// D layout (mfma_f32_16x16x32_bf16): col = lane&15, row = (lane>>4)*4 + reg
// A layout: row = lane&15, k = (lane>>4)*8 + i ;  B layout: col = lane&15, k = (lane>>4)*8 + i
// h_edge stores channels interleaved: position 2*c+h <-> channel c + 16*h (c=0..15)
// Stripe mapping: tile t, row i  <->  edge p0 + (i>>2)*16 + t*4 + (i&3)
//   => lane group cl's outputs across t = 16 CONSECUTIVE sorted edges.

__device__ inline void ep_xpose_write(float* __restrict__ xw, f32x4 da, f32x4 db,
                                      float ba, float bb, int cl, int ch) {
#pragma unroll
  for (int r = 0; r < 4; r++) {
    xw[(cl * 4 + r) * 36 + ch] = fmaxf(da[r] + ba, 0.f);
    xw[(cl * 4 + r) * 36 + ch + 16] = fmaxf(db[r] + bb, 0.f);
  }
}

__device__ inline ABfrag xpose_read(const float* __restrict__ xw, int lane) {
  const float4* p = (const float4*)(xw + (lane & 15) * 36 + (lane >> 4) * 8);
  float4 v0 = p[0], v1 = p[1];
  ABfrag A;
  A.i = make_int4(cvt_pk_bf16(v0.x, v0.y), cvt_pk_bf16(v0.z, v0.w),
                  cvt_pk_bf16(v1.x, v1.y), cvt_pk_bf16(v1.z, v1.w));
  return A;
}

// gather bundle for one 16-edge tile (packed bf16 node rows)
struct G8 { uint2 r2[4]; unsigned p3[4]; };

__device__ inline void gath(G8& g, const uint2* __restrict__ R2b,
                            const unsigned* __restrict__ P3b, int4 sv, int4 dv, int ch) {
  int sa[4] = {sv.x, sv.y, sv.z, sv.w};
  int da[4] = {dv.x, dv.y, dv.z, dv.w};
#pragma unroll
  for (int r = 0; r < 4; r++) {
    g.r2[r] = R2b[(size_t)sa[r] * 16 + ch];
    g.p3[r] = P3b[(size_t)da[r] * 16 + ch];
  }
}

// ==== MFMA fused: edge encoder + first message + scatter (layer-major, striped) ====

__global__ __launch_bounds__(256) void k_fe0_m(
    const uint2* __restrict__ ea2, const unsigned* __restrict__ Q0b,
    const int* __restrict__ src_p, const int* __restrict__ dst_p,
    float* __restrict__ acc,
    const float* __restrict__ ws, const float* __restrict__ bs,
    const float* __restrict__ wh, const float* __restrict__ bh,
    const float* __restrict__ we, const float* __restrict__ be,
    const float* __restrict__ Wn,  // w_node_s rows 32..63
    unsigned int* __restrict__ h_edge) {  // packed interleaved bf16 pairs
  __shared__ float xp[4][4][16 * 36];  // [wave][tile][...] = 36,864 B
  int lane = threadIdx.x & 63, wid = threadIdx.x >> 6;
  int cl = lane >> 4, ch = lane & 15;
  unsigned wp01[8], wp2b[8];
#pragma unroll
  for (int kk = 0; kk < 8; kk++) {
    int c = cl * 8 + kk;
    wp01[kk] = ((unsigned)f2b(ws[32 + c]) << 16) | f2b(ws[c]);
    wp2b[kk] = ((unsigned)f2b(bs[c]) << 16) | f2b(ws[64 + c]);
  }
  ABfrag wha, whb, wea, web, w2a, w2b;
#pragma unroll
  for (int kk = 0; kk < 8; kk++) {
    int k = cl * 8 + kk;
    wha.s[kk] = (short)f2b(wh[k * 32 + ch]);
    whb.s[kk] = (short)f2b(wh[k * 32 + ch + 16]);
    wea.s[kk] = (short)f2b(we[k * 32 + ch]);
    web.s[kk] = (short)f2b(we[k * 32 + ch + 16]);
    w2a.s[kk] = (short)f2b(Wn[(32 + k) * 32 + ch]);
    w2b.s[kk] = (short)f2b(Wn[(32 + k) * 32 + ch + 16]);
  }
  float bha = bh[ch], bhb = bh[ch + 16], bea = be[ch], beb = be[ch + 16];
  int blk = xcd_swz(blockIdx.x, gridDim.x);
  int p0 = (blk * 4 + wid) * 64;
  f32x4 z = {0.f, 0.f, 0.f, 0.f};
  int echA = ((ch >> 2) << 4) + (ch & 3);  // input-row edge offset (+ t*4)
  // phase 0: all coalesced edge-attr loads (packed bf16)
  uint2 av[4];
#pragma unroll
  for (int t = 0; t < 4; t++) av[t] = ea2[p0 + echA + t * 4];
  // phase 1: layer 1 (3 -> 32) in A-frag layout, all tiles
  ABfrag A[4];
#pragma unroll
  for (int t = 0; t < 4; t++) {
    float a0 = unpk_lo(av[t].x), a1 = unpk_hi(av[t].x), a2 = unpk_lo(av[t].y);
    float h1[8];
#pragma unroll
    for (int kk = 0; kk < 8; kk++) {
      float w0 = unpk_lo(wp01[kk]), w1 = unpk_hi(wp01[kk]);
      float w2 = unpk_lo(wp2b[kk]), bb = unpk_hi(wp2b[kk]);
      h1[kk] = fmaxf(fmaf(a0, w0, fmaf(a1, w1, fmaf(a2, w2, bb))), 0.f);
    }
    A[t].i = make_int4(cvt_pk_bf16(h1[0], h1[1]), cvt_pk_bf16(h1[2], h1[3]),
                       cvt_pk_bf16(h1[4], h1[5]), cvt_pk_bf16(h1[6], h1[7]));
  }
  // phase 2: layer 2 (wh), layer-major
#pragma unroll
  for (int t = 0; t < 4; t++) {
    f32x4 da = __builtin_amdgcn_mfma_f32_16x16x32_bf16(A[t].s, wha.s, z, 0, 0, 0);
    f32x4 db = __builtin_amdgcn_mfma_f32_16x16x32_bf16(A[t].s, whb.s, z, 0, 0, 0);
    ep_xpose_write(xp[wid][t], da, db, bha, bhb, cl, ch);
  }
#pragma unroll
  for (int t = 0; t < 4; t++) A[t] = xpose_read(xp[wid][t], lane);
  // phase 3: layer 3 (wh)
#pragma unroll
  for (int t = 0; t < 4; t++) {
    f32x4 da = __builtin_amdgcn_mfma_f32_16x16x32_bf16(A[t].s, wha.s, z, 0, 0, 0);
    f32x4 db = __builtin_amdgcn_mfma_f32_16x16x32_bf16(A[t].s, whb.s, z, 0, 0, 0);
    ep_xpose_write(xp[wid][t], da, db, bha, bhb, cl, ch);
  }
#pragma unroll
  for (int t = 0; t < 4; t++) A[t] = xpose_read(xp[wid][t], lane);
  // phase 4: issue index + Q gathers early, then layer 4 (we) -> h_edge + xpose
  int4 dv[4];
  unsigned qg[4][4];
#pragma unroll
  for (int t = 0; t < 4; t++) {
    int base = p0 + cl * 16 + t * 4;
    int4 sv = *(const int4*)(src_p + base);
    dv[t] = *(const int4*)(dst_p + base);
    int sa[4] = {sv.x, sv.y, sv.z, sv.w};
#pragma unroll
    for (int r = 0; r < 4; r++) qg[t][r] = Q0b[(size_t)sa[r] * 16 + ch];
  }
#pragma unroll
  for (int t = 0; t < 4; t++) {
    f32x4 da = __builtin_amdgcn_mfma_f32_16x16x32_bf16(A[t].s, wea.s, z, 0, 0, 0);
    f32x4 db = __builtin_amdgcn_mfma_f32_16x16x32_bf16(A[t].s, web.s, z, 0, 0, 0);
#pragma unroll
    for (int r = 0; r < 4; r++) {
      float h0 = fmaxf(da[r] + bea, 0.f);
      float hv = fmaxf(db[r] + beb, 0.f);
      int p = p0 + cl * 16 + t * 4 + r;
      h_edge[(size_t)p * 16 + ch] = cvt_pk_bf16(h0, hv);
      xp[wid][t][(cl * 4 + r) * 36 + ch] = h0;
      xp[wid][t][(cl * 4 + r) * 36 + ch + 16] = hv;
    }
  }
#pragma unroll
  for (int t = 0; t < 4; t++) A[t] = xpose_read(xp[wid][t], lane);
  // phase 5: message + fully-merged scatter (lane's 16 edges are consecutive)
  float va = 0.f, vb = 0.f;
  int cur = dv[0].x;
#pragma unroll
  for (int t = 0; t < 4; t++) {
    f32x4 ma = __builtin_amdgcn_mfma_f32_16x16x32_bf16(A[t].s, w2a.s, z, 0, 0, 0);
    f32x4 mb = __builtin_amdgcn_mfma_f32_16x16x32_bf16(A[t].s, w2b.s, z, 0, 0, 0);
    int dda[4] = {dv[t].x, dv[t].y, dv[t].z, dv[t].w};
#pragma unroll
    for (int r = 0; r < 4; r++) {
      float xa = fmaxf(ma[r] + unpk_lo(qg[t][r]), 0.f);
      float xb = fmaxf(mb[r] + unpk_hi(qg[t][r]), 0.f);
      if (dda[r] != cur) {
        atomicAdd(&acc[(size_t)cur * 32 + ch], va);
        atomicAdd(&acc[(size_t)cur * 32 + ch + 16], vb);
        va = 0.f; vb = 0.f; cur = dda[r];
      }
      va += xa; vb += xb;
    }
  }
  atomicAdd(&acc[(size_t)cur * 32 + ch], va);
  atomicAdd(&acc[(size_t)cur * 32 + ch + 16], vb);
}

// ==== MFMA fused: edge update + message + scatter (striped) ====
// A-frag from interleaved h_edge: frag pos cl*8+kk holds channel kp = cl*4 + (kk>>1) + (kk&1)*16

template <int LAST>
__global__ __launch_bounds__(256) void k_fe_t(
    unsigned int* __restrict__ h_edge, const uint2* __restrict__ R2b,
    const unsigned* __restrict__ P3b, const int* __restrict__ src_p,
    const int* __restrict__ dst_p, float* __restrict__ acc,
    const float* __restrict__ We, const float* __restrict__ be,
    const float* __restrict__ Wn, const float* __restrict__ We3,
    float* __restrict__ partialE) {
  __shared__ float xp[4][16 * 36];
  int lane = threadIdx.x & 63, wid = threadIdx.x >> 6;
  int cl = lane >> 4, ch = lane & 15;
  ABfrag b1a, b1b, b2a, b2b, w3h, w3l;
#pragma unroll
  for (int kk = 0; kk < 8; kk++) {
    int k = cl * 8 + kk;
    int kp = cl * 4 + (kk >> 1) + (kk & 1) * 16;  // interleaved h_edge k-perm
    b1a.s[kk] = (short)f2b(We[kp * 32 + ch]);
    b1b.s[kk] = (short)f2b(We[kp * 32 + ch + 16]);
    b2a.s[kk] = (short)f2b(Wn[(32 + k) * 32 + ch]);
    b2b.s[kk] = (short)f2b(Wn[(32 + k) * 32 + ch + 16]);
    if (LAST) {
      unsigned short hi_, lo_;
      float v = (ch < 3) ? We3[k * 3 + ch] : 0.f;
      splitw(v, hi_, lo_); w3h.s[kk] = (short)hi_; w3l.s[kk] = (short)lo_;
    }
  }
  float bea = be[ch], beb = be[ch + 16];
  int blk = xcd_swz(blockIdx.x, gridDim.x);
  int p0 = (blk * 4 + wid) * 64;
  f32x4 z = {0.f, 0.f, 0.f, 0.f};
  float* xw = xp[wid];
  int echA = ((ch >> 2) << 4) + (ch & 3);  // input-row edge offset (+ t*4)
  float va = 0.f, vb = 0.f;
  int cur = dst_p[p0 + cl * 16];
#pragma unroll
  for (int t = 0; t < 4; ++t) {
    int base = p0 + cl * 16 + t * 4;
    ABfrag A;
    A.i = *(const int4*)(h_edge + (size_t)(p0 + echA + t * 4) * 16 + cl * 4);
    int4 sv = *(const int4*)(src_p + base);
    int4 dv = *(const int4*)(dst_p + base);
    G8 g;
    gath(g, R2b, P3b, sv, dv, ch);
    f32x4 da = __builtin_amdgcn_mfma_f32_16x16x32_bf16(A.s, b1a.s, z, 0, 0, 0);
    f32x4 db = __builtin_amdgcn_mfma_f32_16x16x32_bf16(A.s, b1b.s, z, 0, 0, 0);
#pragma unroll
    for (int r = 0; r < 4; r++) {
      float h0 = fmaxf(da[r] + unpk_lo(g.r2[r].x) + unpk_lo(g.p3[r]) + bea, 0.f);
      float hv = fmaxf(db[r] + unpk_lo(g.r2[r].y) + unpk_hi(g.p3[r]) + beb, 0.f);
      int p = base + r;
      if (!LAST) h_edge[(size_t)p * 16 + ch] = cvt_pk_bf16(h0, hv);
      xw[(cl * 4 + r) * 36 + ch] = h0;
      xw[(cl * 4 + r) * 36 + ch + 16] = hv;
    }
    ABfrag A2 = xpose_read(xw, lane);
    f32x4 ma = __builtin_amdgcn_mfma_f32_16x16x32_bf16(A2.s, b2a.s, z, 0, 0, 0);
    f32x4 mb = __builtin_amdgcn_mfma_f32_16x16x32_bf16(A2.s, b2b.s, z, 0, 0, 0);
    if (LAST) {
      f32x4 dc = __builtin_amdgcn_mfma_f32_16x16x32_bf16(A2.s, w3l.s, z, 0, 0, 0);
      dc = __builtin_amdgcn_mfma_f32_16x16x32_bf16(A2.s, w3h.s, dc, 0, 0, 0);
      if (ch < 3) {
#pragma unroll
        for (int r = 0; r < 4; r++)
          partialE[(size_t)(base + r) * 3 + ch] = dc[r];
      }
    }
    int dda[4] = {dv.x, dv.y, dv.z, dv.w};
#pragma unroll
    for (int r = 0; r < 4; r++) {
      float xa = fmaxf(ma[r] + unpk_hi(g.r2[r].x), 0.f);
      float xb = fmaxf(mb[r] + unpk_hi(g.r2[r].y), 0.f);
      if (dda[r] != cur) {
        atomicAdd(&acc[(size_t)cur * 32 + ch], va);
        atomicAdd(&acc[(size_t)cur * 32 + ch + 16], vb);
        va = 0.f; vb = 0.f; cur = dda[r];
      }
      va += xa; vb += xb;
    }
  }
  atomicAdd(&acc[(size_t)cur * 32 + ch], va);
  atomicAdd(&acc[(size_t)cur * 32 + ch + 16], vb);
}

// ==== final: out[e] = ea[e] + partialE[inv[e]] + P2f[src[e]] + P3f[dst[e]] + b ====

__global__ __launch_bounds__(256) void k_fe4e(
    const float* __restrict__ partialE, const int* __restrict__ inv_p,
    const float* __restrict__ edge_attr, const int* __restrict__ src,
    const int* __restrict__ dstv, const float* __restrict__ P2f,
    const float* __restrict__ P3f, const float* __restrict__ be,
    float* __restrict__ out) {
  int e = blockIdx.x * blockDim.x + threadIdx.x;
  if (e >= NE) return;
  int p = inv_p[e];
  int s = src[e], d = dstv[e];
  float c0 = partialE[(size_t)p * 3 + 0];
  float c1 = partialE[(size_t)p * 3 + 1];
  float c2 = partialE[(size_t)p * 3 + 2];
  out[(size_t)e * 3 + 0] = edge_attr[(size_t)e * 3 + 0] + c0 + P2f[(size_t)s * 3 + 0] + P3f[(size_t)d * 3 + 0] + be[0];
  out[(size_t)e * 3 + 1] = edge_attr[(size_t)e * 3 + 1] + c1 + P2f[(size_t)s * 3 + 1] + P3f[(size_t)d * 3 + 1] + be[1];
  out[(size_t)e * 3 + 2] = edge_attr[(size_t)e * 3 + 2] + c2 + P2f[(size_t)s * 3 + 2] + P3f[(size_t)d * 3 + 2] + be[2];
}

// ============================ launch ============================

extern "C" void kernel_launch(void* const* d_in, const int* in_sizes, int n_in,
                              void* d_out, int out_size, void* d_ws, size_t ws_size,
                              hipStream_t stream) {
  const float* x = (const float*)d_in[0];
  const float* edge_attr = (const float*)d_in[1];
  const int* ei = (const int*)d_in[2];
  const int* src = ei;
  const int* dst = ei + NE;
  const float* w_enc_node_s = (const float*)d_in[3];
  const float* b_enc_node_s = (const float*)d_in[4];
  const float* w_enc_node_h = (const float*)d_in[5];
  const float* b_enc_node_h = (const float*)d_in[6];
  const float* w_enc_node_e = (const float*)d_in[7];
  const float* b_enc_node_e = (const float*)d_in[8];
  const float* w_enc_edge_s = (const float*)d_in[9];
  const float* b_enc_edge_s = (const float*)d_in[10];
  const float* w_enc_edge_h = (const float*)d_in[11];
  const float* b_enc_edge_h = (const float*)d_in[12];
  const float* w_enc_edge_e = (const float*)d_in[13];
  const float* b_enc_edge_e = (const float*)d_in[14];
  const float* w_node_s = (const float*)d_in[15];
  const float* w_node_h = (const float*)d_in[16];
  const float* w_node_e = (const float*)d_in[17];
  const float* w_edge_s = (const float*)d_in[18];
  const float* b_edge_s = (const float*)d_in[19];
  const float* w_edge_h = (const float*)d_in[20];
  const float* b_edge_h = (const float*)d_in[21];
  const float* w_edge_e = (const float*)d_in[22];
  const float* b_edge_e = (const float*)d_in[23];

  // workspace layout (~206 MB; 238 MB proven safe)
  char* w = (char*)d_ws;
  unsigned int* h_edge = (unsigned int*)w; w += (size_t)NE * 16 * 4;  // 102.4 MB
  int* inv_p = (int*)w;       w += (size_t)NE * 4;            // 6.4
  int* src_p = (int*)w;       w += (size_t)NE * 4;            // 6.4
  int* dst_p = (int*)w;       w += (size_t)NE * 4;            // 6.4
  int* perm = (int*)w;        w += (size_t)NE * 4;            // 6.4
  int* slot = (int*)w;        w += (size_t)NE * 4;            // 6.4
  uint2* ea2 = (uint2*)w;     w += (size_t)NE * 8;            // 12.8
  float* partialE = (float*)w; w += (size_t)NE * 3 * 4;       // 19.2
  float* acc = (float*)w;     w += (size_t)NN * D * 4;        // 12.8
  uint2* R2b = (uint2*)w;     w += (size_t)NN * 16 * 8;       // 12.8
  unsigned* P3b = (unsigned*)w; w += (size_t)NN * 16 * 4;     // 6.4 (aliased by P2f/P3f)
  unsigned* Q0b = (unsigned*)w; w += (size_t)NN * 16 * 4;     // 6.4
  float* P2f = (float*)P3b;
  float* P3f = (float*)P3b + (size_t)NN * 3;
  int* cnt = (int*)w;         w += (size_t)NN * 4;
  float* inv_deg = (float*)w; w += (size_t)NN * 4;
  int* rowptr = (int*)w;      w += (size_t)(NN + 1) * 4;
  int* partial = (int*)w;     w += 4096;

  hipMemsetAsync(cnt, 0, (size_t)NN * 4, stream);
  hipMemsetAsync(acc, 0, (size_t)NN * D * 4, stream);

  k_deg<<<1024, 256, 0, stream>>>(dst, cnt, slot);
  k_invdeg<<<(NN + 255) / 256, 256, 0, stream>>>(cnt, inv_deg);
  int nb = (NN + 1023) / 1024;  // 98
  k_scanA<<<nb, 1024, 0, stream>>>(cnt, rowptr, partial);
  k_scanB<<<1, 128, 0, stream>>>(partial, nb);
  k_scanC<<<nb, 1024, 0, stream>>>(rowptr, partial);
  k_expand<<<(NN + 255) / 256, 256, 0, stream>>>(rowptr, dst_p);  // dst_p, no gather
  k_fillA<<<2048, 256, 0, stream>>>(dst, slot, rowptr, perm, inv_p);  // atomic-free
  k_fillB<<<2048, 256, 0, stream>>>(perm, src, edge_attr, src_p, ea2);

  k_node_enc_fin<<<1024, 256, 0, stream>>>(x, w_enc_node_s, b_enc_node_s,
                                           w_enc_node_h, b_enc_node_h,
                                           w_enc_node_e, b_enc_node_e,
                                           w_node_s, Q0b);

  int feb = NE / 256;  // 6250 blocks: 4 waves x 64 edges

  k_fe0_m<<<feb, 256, 0, stream>>>(ea2, Q0b, src_p, dst_p, acc,
                                   w_enc_edge_s, b_enc_edge_s,
                                   w_enc_edge_h, b_enc_edge_h,
                                   w_enc_edge_e, b_enc_edge_e,
                                   w_node_s, h_edge);
  k_fin<<<1024, 256, 0, stream>>>(acc, inv_deg, w_edge_s, w_node_h, R2b, P3b);
  k_fe_t<0><<<feb, 256, 0, stream>>>(h_edge, R2b, P3b, src_p, dst_p, acc,
                                     w_edge_s, b_edge_s, w_node_h, nullptr, nullptr);
  k_fin<<<1024, 256, 0, stream>>>(acc, inv_deg, w_edge_h, w_node_h, R2b, P3b);
  k_fe_t<0><<<feb, 256, 0, stream>>>(h_edge, R2b, P3b, src_p, dst_p, acc,
                                     w_edge_h, b_edge_h, w_node_h, nullptr, nullptr);
  k_fin<<<1024, 256, 0, stream>>>(acc, inv_deg, w_edge_h, w_node_e, R2b, P3b);
  k_fe_t<1><<<feb, 256, 0, stream>>>(h_edge, R2b, P3b, src_p, dst_p, acc,
                                     w_edge_h, b_edge_h, w_node_e, w_edge_e, partialE);
  k_fin4<<<1024, 256, 0, stream>>>(acc, inv_deg, w_edge_e, P2f, P3f);
  k_fe4e<<<(NE + 255) / 256, 256, 0, stream>>>(partialE, inv_p, edge_attr, src, dst,
                                               P2f, P3f, b_edge_e, (float*)d_out);
}

// Round 16
// 558.239 us; speedup vs baseline: 1.9088x; 1.0346x over previous
//
#include <hip/hip_runtime.h>

#define NN 100000
#define NE 1600000
#define D 32

typedef short short8 __attribute__((ext_vector_type(8)));
typedef float f32x4 __attribute__((ext_vector_type(4)));

union ABfrag { int4 i; short8 s; };

// ---------------- bf16 helpers ----------------

__device__ inline unsigned short f2b(float f) {
  unsigned int u = __float_as_uint(f);
  u = (u + 0x7FFFu + ((u >> 16) & 1u)) >> 16;
  return (unsigned short)u;
}
__device__ inline float b2f(unsigned short s) {
  return __uint_as_float(((unsigned int)s) << 16);
}
__device__ inline unsigned cvt_pk_bf16(float lo, float hi) {
  unsigned r;
  asm("v_cvt_pk_bf16_f32 %0, %1, %2" : "=v"(r) : "v"(lo), "v"(hi));
  return r;
}
__device__ inline void splitw(float w, unsigned short& h, unsigned short& l) {
  h = f2b(w);
  l = f2b(w - b2f(h));
}
__device__ inline float unpk_lo(unsigned u) { return b2f((unsigned short)(u & 0xFFFFu)); }
__device__ inline float unpk_hi(unsigned u) { return b2f((unsigned short)(u >> 16)); }

// XCD-aware bijective block swizzle (m204)
__device__ inline int xcd_swz(int bid, int nwg) {
  int q = nwg >> 3, r = nwg & 7;
  int xcd = bid & 7, j = bid >> 3;
  int base = (xcd < r) ? xcd * (q + 1) : r * (q + 1) + (xcd - r) * q;
  return base + j;
}

// ============================ CSR build ============================

// counting pass; ALSO records each edge's rank within its dst bucket (coalesced)
__global__ void k_deg(const int* __restrict__ dst, int* __restrict__ cnt,
                      int* __restrict__ slot) {
  int i = blockIdx.x * blockDim.x + threadIdx.x;
  int stride = gridDim.x * blockDim.x;
  for (int e = i; e < NE; e += stride) slot[e] = atomicAdd(&cnt[dst[e]], 1);
}

__global__ void k_invdeg(const int* __restrict__ cnt, float* __restrict__ inv) {
  int v = blockIdx.x * blockDim.x + threadIdx.x;
  if (v < NN) inv[v] = 1.0f / (float)max(cnt[v], 1);
}

__global__ __launch_bounds__(1024) void k_scanA(const int* __restrict__ cnt,
                                                int* __restrict__ rowptr,
                                                int* __restrict__ partial) {
  __shared__ int lds[1024];
  int t = threadIdx.x;
  int i = blockIdx.x * 1024 + t;
  int v = (i < NN) ? cnt[i] : 0;
  lds[t] = v;
  __syncthreads();
  for (int off = 1; off < 1024; off <<= 1) {
    int add = (t >= off) ? lds[t - off] : 0;
    __syncthreads();
    lds[t] += add;
    __syncthreads();
  }
  if (i < NN) rowptr[i] = lds[t] - v;
  if (t == 1023) partial[blockIdx.x] = lds[1023];
}

__global__ __launch_bounds__(128) void k_scanB(int* __restrict__ partial, int nb) {
  __shared__ int s[128];
  int t = threadIdx.x;
  int v = (t < nb) ? partial[t] : 0;
  s[t] = v;
  __syncthreads();
  for (int off = 1; off < 128; off <<= 1) {
    int add = (t >= off) ? s[t - off] : 0;
    __syncthreads();
    s[t] += add;
    __syncthreads();
  }
  if (t < nb) partial[t] = s[t] - v;  // exclusive
}

__global__ __launch_bounds__(1024) void k_scanC(int* __restrict__ rowptr,
                                                const int* __restrict__ partial) {
  int t = threadIdx.x;
  int i = blockIdx.x * 1024 + t;
  if (i < NN) rowptr[i] += partial[blockIdx.x];
  if (i == 0) rowptr[NN] = NE;
}

// dst_p needs NO gather: expand from rowptr
__global__ void k_expand(const int* __restrict__ rowptr, int* __restrict__ dst_p) {
  int v = blockIdx.x * blockDim.x + threadIdx.x;
  if (v >= NN) return;
  int b = rowptr[v], e = rowptr[v + 1];
  for (int p = b; p < e; p++) dst_p[p] = v;
}

// fully-coalesced pre-pack: sea[e] = {src, pk(ea0,ea1), pk(ea2,0), 0}
__global__ void k_pack(const int* __restrict__ src, const float* __restrict__ ea,
                       int4* __restrict__ sea) {
  int e = blockIdx.x * blockDim.x + threadIdx.x;
  if (e >= NE) return;
  int4 v;
  v.x = src[e];
  v.y = (int)cvt_pk_bf16(ea[(size_t)e * 3 + 0], ea[(size_t)e * 3 + 1]);
  v.z = (int)cvt_pk_bf16(ea[(size_t)e * 3 + 2], 0.f);
  v.w = 0;
  sea[e] = v;
}

// phase A (ATOMIC-FREE): p = rowptr[dst[e]] + slot[e]; scatter only perm (4B)
__global__ void k_fillA(const int* __restrict__ dst, const int* __restrict__ slot,
                        const int* __restrict__ rowptr, int* __restrict__ perm) {
  int i = blockIdx.x * blockDim.x + threadIdx.x;
  int stride = gridDim.x * blockDim.x;
  for (int e = i; e < NE; e += stride) {
    int p = rowptr[dst[e]] + slot[e];
    perm[p] = e;
  }
}

// phase B: ONE 16B gather per edge; coalesced writes
__global__ void k_fillB(const int* __restrict__ perm, const int4* __restrict__ sea,
                        int* __restrict__ src_p, uint2* __restrict__ ea2) {
  int i = blockIdx.x * blockDim.x + threadIdx.x;
  int stride = gridDim.x * blockDim.x;
  for (int p = i; p < NE; p += stride) {
    int4 v = sea[perm[p]];
    src_p[p] = v.x;
    ea2[p] = make_uint2((unsigned)v.y, (unsigned)v.z);
  }
}

// ============================ VALU dot helper (node kernels) ============================

template <int K4>
__device__ inline float dot_lds(const float* __restrict__ lv, const float* __restrict__ Wc) {
  float acc = 0.f;
  const float4* v4 = (const float4*)lv;
#pragma unroll
  for (int kk = 0; kk < K4; kk++) {
    float4 h = v4[kk];
    acc = fmaf(h.x, Wc[4 * kk + 0], acc);
    acc = fmaf(h.y, Wc[4 * kk + 1], acc);
    acc = fmaf(h.z, Wc[4 * kk + 2], acc);
    acc = fmaf(h.w, Wc[4 * kk + 3], acc);
  }
  return acc;
}

// ============ node encoder + Q0 projection (packed bf16 pairs) ============

__global__ __launch_bounds__(256) void k_node_enc_fin(
    const float* __restrict__ x,
    const float* __restrict__ ws, const float* __restrict__ bs,
    const float* __restrict__ wh, const float* __restrict__ bh,
    const float* __restrict__ we, const float* __restrict__ be,
    const float* __restrict__ Wn,  // w_node_s, rows 0..31
    unsigned* __restrict__ Q0b) {  // [NN*16]: pk(q_ch, q_ch+16)
  __shared__ float hrow[8][D];
  int t = threadIdx.x, j = t & 31, g = t >> 5;
  float Ws = ws[j], Bs = bs[j], Bh = bh[j], Be = be[j];
  float Wh[D], We_[D], Wq[D];
#pragma unroll
  for (int k = 0; k < D; k++) {
    Wh[k] = wh[k * D + j];
    We_[k] = we[k * D + j];
    Wq[k] = Wn[k * D + j];
  }
  for (int v = blockIdx.x * 8 + g; v < NN; v += gridDim.x * 8) {
    float h = fmaxf(fmaf(x[v], Ws, Bs), 0.f);
#pragma unroll
    for (int L = 0; L < 2; L++) {
      hrow[g][j] = h;
      h = fmaxf(dot_lds<8>(hrow[g], Wh) + Bh, 0.f);
    }
    hrow[g][j] = h;
    h = fmaxf(dot_lds<8>(hrow[g], We_) + Be, 0.f);
    hrow[g][j] = h;
    float q = dot_lds<8>(hrow[g], Wq);
    hrow[g][j] = q;  // wave-sync staging (dot complete for all lanes)
    if (j < 16) Q0b[(size_t)v * 16 + j] = cvt_pk_bf16(hrow[g][j], hrow[g][j + 16]);
  }
}

// ==== node finalize: h = acc/deg; project P2/Q and P3, packed bf16 ====

__global__ __launch_bounds__(256) void k_fin(
    float* __restrict__ acc, const float* __restrict__ inv_deg,
    const float* __restrict__ We,  // [96][32] NEXT edge layer (rows 32..95 used)
    const float* __restrict__ Wn,  // [64][32] NEXT node msg (rows 0..31 used)
    uint2* __restrict__ R2b,       // [NN*16]: {pk(p2lo,qlo), pk(p2hi,qhi)}
    unsigned* __restrict__ P3b) {  // [NN*16]: pk(p3lo,p3hi)
  __shared__ float hrow[8][D];
  __shared__ float st[8][3][D];
  int t = threadIdx.x, j = t & 31, g = t >> 5;
  float Wp2[D], Wp3[D], Wq[D];
#pragma unroll
  for (int k = 0; k < D; k++) {
    Wp2[k] = We[(32 + k) * D + j];
    Wp3[k] = We[(64 + k) * D + j];
    Wq[k] = Wn[k * D + j];
  }
  for (int v = blockIdx.x * 8 + g; v < NN; v += gridDim.x * 8) {
    float h = acc[(size_t)v * D + j] * inv_deg[v];
    acc[(size_t)v * D + j] = 0.f;
    hrow[g][j] = h;
    float p2 = dot_lds<8>(hrow[g], Wp2);
    float q = dot_lds<8>(hrow[g], Wq);
    float p3 = dot_lds<8>(hrow[g], Wp3);
    st[g][0][j] = p2; st[g][1][j] = q; st[g][2][j] = p3;
    if (j < 16) {
      R2b[(size_t)v * 16 + j] = make_uint2(cvt_pk_bf16(st[g][0][j], st[g][1][j]),
                                           cvt_pk_bf16(st[g][0][j + 16], st[g][1][j + 16]));
      P3b[(size_t)v * 16 + j] = cvt_pk_bf16(st[g][2][j], st[g][2][j + 16]);
    }
  }
}

// ==== final node finalize: P2f/P3f [NN,3] ====

__global__ __launch_bounds__(256) void k_fin4(
    float* __restrict__ acc, const float* __restrict__ inv_deg,
    const float* __restrict__ We,  // w_edge_e [96][3]
    float* __restrict__ P2f, float* __restrict__ P3f) {
  __shared__ float hrow[8][D];
  int t = threadIdx.x, j = t & 31, g = t >> 5;
  for (int v = blockIdx.x * 8 + g; v < NN; v += gridDim.x * 8) {
    float h = acc[(size_t)v * D + j] * inv_deg[v];
    hrow[g][j] = h;
    if (j < 6) {
      int c = j % 3;
      int off = (j < 3) ? 32 : 64;
      float s = 0.f;
#pragma unroll
      for (int k = 0; k < D; k++) s = fmaf(hrow[g][k], We[(off + k) * 3 + c], s);
      if (j < 3) P2f[(size_t)v * 3 + c] = s;
      else       P3f[(size_t)v * 3 + c] = s;
    }
  }
}

// ============================ MFMA helpers ============================
// D layout (mfma_f32_16x16x32_bf16): col = lane&15, row = (lane>>4)*4 + reg
// A layout: row = lane&15, k = (lane>>4)*8 + i ;  B layout: col = lane&15, k = (lane>>4)*8 + i
// h_edge stores channels interleaved: position 2*c+h <-> channel c + 16*h (c=0..15)
// Stripe mapping: tile t, row i  <->  edge p0 + (i>>2)*16 + t*4 + (i&3)

__device__ inline void ep_xpose_write(float* __restrict__ xw, f32x4 da, f32x4 db,
                                      float ba, float bb, int cl, int ch) {
#pragma unroll
  for (int r = 0; r < 4; r++) {
    xw[(cl * 4 + r) * 36 + ch] = fmaxf(da[r] + ba, 0.f);
    xw[(cl * 4 + r) * 36 + ch + 16] = fmaxf(db[r] + bb, 0.f);
  }
}

__device__ inline ABfrag xpose_read(const float* __restrict__ xw, int lane) {
  const float4* p = (const float4*)(xw + (lane & 15) * 36 + (lane >> 4) * 8);
  float4 v0 = p[0], v1 = p[1];
  ABfrag A;
  A.i = make_int4(cvt_pk_bf16(v0.x, v0.y), cvt_pk_bf16(v0.z, v0.w),
                  cvt_pk_bf16(v1.x, v1.y), cvt_pk_bf16(v1.z, v1.w));
  return A;
}

// gather bundle for one 16-edge tile (packed bf16 node rows)
struct G8 { uint2 r2[4]; unsigned p3[4]; };

__device__ inline void gath(G8& g, const uint2* __restrict__ R2b,
                            const unsigned* __restrict__ P3b, int4 sv, int4 dv, int ch) {
  int sa[4] = {sv.x, sv.y, sv.z, sv.w};
  int da[4] = {dv.x, dv.y, dv.z, dv.w};
#pragma unroll
  for (int r = 0; r < 4; r++) {
    g.r2[r] = R2b[(size_t)sa[r] * 16 + ch];
    g.p3[r] = P3b[(size_t)da[r] * 16 + ch];
  }
}

// ==== MFMA fused: edge encoder + first message + scatter (layer-major, striped) ====

__global__ __launch_bounds__(256) void k_fe0_m(
    const uint2* __restrict__ ea2, const unsigned* __restrict__ Q0b,
    const int* __restrict__ src_p, const int* __restrict__ dst_p,
    float* __restrict__ acc,
    const float* __restrict__ ws, const float* __restrict__ bs,
    const float* __restrict__ wh, const float* __restrict__ bh,
    const float* __restrict__ we, const float* __restrict__ be,
    const float* __restrict__ Wn,  // w_node_s rows 32..63
    unsigned int* __restrict__ h_edge) {  // packed interleaved bf16 pairs
  __shared__ float xp[4][4][16 * 36];
  int lane = threadIdx.x & 63, wid = threadIdx.x >> 6;
  int cl = lane >> 4, ch = lane & 15;
  unsigned wp01[8], wp2b[8];
#pragma unroll
  for (int kk = 0; kk < 8; kk++) {
    int c = cl * 8 + kk;
    wp01[kk] = ((unsigned)f2b(ws[32 + c]) << 16) | f2b(ws[c]);
    wp2b[kk] = ((unsigned)f2b(bs[c]) << 16) | f2b(ws[64 + c]);
  }
  ABfrag wha, whb, wea, web, w2a, w2b;
#pragma unroll
  for (int kk = 0; kk < 8; kk++) {
    int k = cl * 8 + kk;
    wha.s[kk] = (short)f2b(wh[k * 32 + ch]);
    whb.s[kk] = (short)f2b(wh[k * 32 + ch + 16]);
    wea.s[kk] = (short)f2b(we[k * 32 + ch]);
    web.s[kk] = (short)f2b(we[k * 32 + ch + 16]);
    w2a.s[kk] = (short)f2b(Wn[(32 + k) * 32 + ch]);
    w2b.s[kk] = (short)f2b(Wn[(32 + k) * 32 + ch + 16]);
  }
  float bha = bh[ch], bhb = bh[ch + 16], bea = be[ch], beb = be[ch + 16];
  int blk = xcd_swz(blockIdx.x, gridDim.x);
  int p0 = (blk * 4 + wid) * 64;
  f32x4 z = {0.f, 0.f, 0.f, 0.f};
  int echA = ((ch >> 2) << 4) + (ch & 3);
  uint2 av[4];
#pragma unroll
  for (int t = 0; t < 4; t++) av[t] = ea2[p0 + echA + t * 4];
  ABfrag A[4];
#pragma unroll
  for (int t = 0; t < 4; t++) {
    float a0 = unpk_lo(av[t].x), a1 = unpk_hi(av[t].x), a2 = unpk_lo(av[t].y);
    float h1[8];
#pragma unroll
    for (int kk = 0; kk < 8; kk++) {
      float w0 = unpk_lo(wp01[kk]), w1 = unpk_hi(wp01[kk]);
      float w2 = unpk_lo(wp2b[kk]), bb = unpk_hi(wp2b[kk]);
      h1[kk] = fmaxf(fmaf(a0, w0, fmaf(a1, w1, fmaf(a2, w2, bb))), 0.f);
    }
    A[t].i = make_int4(cvt_pk_bf16(h1[0], h1[1]), cvt_pk_bf16(h1[2], h1[3]),
                       cvt_pk_bf16(h1[4], h1[5]), cvt_pk_bf16(h1[6], h1[7]));
  }
#pragma unroll
  for (int t = 0; t < 4; t++) {
    f32x4 da = __builtin_amdgcn_mfma_f32_16x16x32_bf16(A[t].s, wha.s, z, 0, 0, 0);
    f32x4 db = __builtin_amdgcn_mfma_f32_16x16x32_bf16(A[t].s, whb.s, z, 0, 0, 0);
    ep_xpose_write(xp[wid][t], da, db, bha, bhb, cl, ch);
  }
#pragma unroll
  for (int t = 0; t < 4; t++) A[t] = xpose_read(xp[wid][t], lane);
#pragma unroll
  for (int t = 0; t < 4; t++) {
    f32x4 da = __builtin_amdgcn_mfma_f32_16x16x32_bf16(A[t].s, wha.s, z, 0, 0, 0);
    f32x4 db = __builtin_amdgcn_mfma_f32_16x16x32_bf16(A[t].s, whb.s, z, 0, 0, 0);
    ep_xpose_write(xp[wid][t], da, db, bha, bhb, cl, ch);
  }
#pragma unroll
  for (int t = 0; t < 4; t++) A[t] = xpose_read(xp[wid][t], lane);
  int4 dv[4];
  unsigned qg[4][4];
#pragma unroll
  for (int t = 0; t < 4; t++) {
    int base = p0 + cl * 16 + t * 4;
    int4 sv = *(const int4*)(src_p + base);
    dv[t] = *(const int4*)(dst_p + base);
    int sa[4] = {sv.x, sv.y, sv.z, sv.w};
#pragma unroll
    for (int r = 0; r < 4; r++) qg[t][r] = Q0b[(size_t)sa[r] * 16 + ch];
  }
#pragma unroll
  for (int t = 0; t < 4; t++) {
    f32x4 da = __builtin_amdgcn_mfma_f32_16x16x32_bf16(A[t].s, wea.s, z, 0, 0, 0);
    f32x4 db = __builtin_amdgcn_mfma_f32_16x16x32_bf16(A[t].s, web.s, z, 0, 0, 0);
#pragma unroll
    for (int r = 0; r < 4; r++) {
      float h0 = fmaxf(da[r] + bea, 0.f);
      float hv = fmaxf(db[r] + beb, 0.f);
      int p = p0 + cl * 16 + t * 4 + r;
      h_edge[(size_t)p * 16 + ch] = cvt_pk_bf16(h0, hv);
      xp[wid][t][(cl * 4 + r) * 36 + ch] = h0;
      xp[wid][t][(cl * 4 + r) * 36 + ch + 16] = hv;
    }
  }
#pragma unroll
  for (int t = 0; t < 4; t++) A[t] = xpose_read(xp[wid][t], lane);
  float va = 0.f, vb = 0.f;
  int cur = dv[0].x;
#pragma unroll
  for (int t = 0; t < 4; t++) {
    f32x4 ma = __builtin_amdgcn_mfma_f32_16x16x32_bf16(A[t].s, w2a.s, z, 0, 0, 0);
    f32x4 mb = __builtin_amdgcn_mfma_f32_16x16x32_bf16(A[t].s, w2b.s, z, 0, 0, 0);
    int dda[4] = {dv[t].x, dv[t].y, dv[t].z, dv[t].w};
#pragma unroll
    for (int r = 0; r < 4; r++) {
      float xa = fmaxf(ma[r] + unpk_lo(qg[t][r]), 0.f);
      float xb = fmaxf(mb[r] + unpk_hi(qg[t][r]), 0.f);
      if (dda[r] != cur) {
        atomicAdd(&acc[(size_t)cur * 32 + ch], va);
        atomicAdd(&acc[(size_t)cur * 32 + ch + 16], vb);
        va = 0.f; vb = 0.f; cur = dda[r];
      }
      va += xa; vb += xb;
    }
  }
  atomicAdd(&acc[(size_t)cur * 32 + ch], va);
  atomicAdd(&acc[(size_t)cur * 32 + ch + 16], vb);
}

// ==== MFMA fused: edge update + message + scatter (striped) ====
// LAST=1: partialE written in ORIGINAL edge order via perm (k_fe4e then fully coalesced)

template <int LAST>
__global__ __launch_bounds__(256) void k_fe_t(
    unsigned int* __restrict__ h_edge, const uint2* __restrict__ R2b,
    const unsigned* __restrict__ P3b, const int* __restrict__ src_p,
    const int* __restrict__ dst_p, float* __restrict__ acc,
    const float* __restrict__ We, const float* __restrict__ be,
    const float* __restrict__ Wn, const float* __restrict__ We3,
    const int* __restrict__ perm, float* __restrict__ partialE) {
  __shared__ float xp[4][16 * 36];
  int lane = threadIdx.x & 63, wid = threadIdx.x >> 6;
  int cl = lane >> 4, ch = lane & 15;
  ABfrag b1a, b1b, b2a, b2b, w3h, w3l;
#pragma unroll
  for (int kk = 0; kk < 8; kk++) {
    int k = cl * 8 + kk;
    int kp = cl * 4 + (kk >> 1) + (kk & 1) * 16;  // interleaved h_edge k-perm
    b1a.s[kk] = (short)f2b(We[kp * 32 + ch]);
    b1b.s[kk] = (short)f2b(We[kp * 32 + ch + 16]);
    b2a.s[kk] = (short)f2b(Wn[(32 + k) * 32 + ch]);
    b2b.s[kk] = (short)f2b(Wn[(32 + k) * 32 + ch + 16]);
    if (LAST) {
      unsigned short hi_, lo_;
      float v = (ch < 3) ? We3[k * 3 + ch] : 0.f;
      splitw(v, hi_, lo_); w3h.s[kk] = (short)hi_; w3l.s[kk] = (short)lo_;
    }
  }
  float bea = be[ch], beb = be[ch + 16];
  int blk = xcd_swz(blockIdx.x, gridDim.x);
  int p0 = (blk * 4 + wid) * 64;
  f32x4 z = {0.f, 0.f, 0.f, 0.f};
  float* xw = xp[wid];
  int echA = ((ch >> 2) << 4) + (ch & 3);
  float va = 0.f, vb = 0.f;
  int cur = dst_p[p0 + cl * 16];
#pragma unroll
  for (int t = 0; t < 4; ++t) {
    int base = p0 + cl * 16 + t * 4;
    ABfrag A;
    A.i = *(const int4*)(h_edge + (size_t)(p0 + echA + t * 4) * 16 + cl * 4);
    int4 sv = *(const int4*)(src_p + base);
    int4 dv = *(const int4*)(dst_p + base);
    G8 g;
    gath(g, R2b, P3b, sv, dv, ch);
    f32x4 da = __builtin_amdgcn_mfma_f32_16x16x32_bf16(A.s, b1a.s, z, 0, 0, 0);
    f32x4 db = __builtin_amdgcn_mfma_f32_16x16x32_bf16(A.s, b1b.s, z, 0, 0, 0);
#pragma unroll
    for (int r = 0; r < 4; r++) {
      float h0 = fmaxf(da[r] + unpk_lo(g.r2[r].x) + unpk_lo(g.p3[r]) + bea, 0.f);
      float hv = fmaxf(db[r] + unpk_lo(g.r2[r].y) + unpk_hi(g.p3[r]) + beb, 0.f);
      int p = base + r;
      if (!LAST) h_edge[(size_t)p * 16 + ch] = cvt_pk_bf16(h0, hv);
      xw[(cl * 4 + r) * 36 + ch] = h0;
      xw[(cl * 4 + r) * 36 + ch + 16] = hv;
    }
    ABfrag A2 = xpose_read(xw, lane);
    f32x4 ma = __builtin_amdgcn_mfma_f32_16x16x32_bf16(A2.s, b2a.s, z, 0, 0, 0);
    f32x4 mb = __builtin_amdgcn_mfma_f32_16x16x32_bf16(A2.s, b2b.s, z, 0, 0, 0);
    if (LAST) {
      f32x4 dc = __builtin_amdgcn_mfma_f32_16x16x32_bf16(A2.s, w3l.s, z, 0, 0, 0);
      dc = __builtin_amdgcn_mfma_f32_16x16x32_bf16(A2.s, w3h.s, dc, 0, 0, 0);
      int4 pv = *(const int4*)(perm + base);
      int eo[4] = {pv.x, pv.y, pv.z, pv.w};
      if (ch < 3) {
#pragma unroll
        for (int r = 0; r < 4; r++)
          partialE[(size_t)eo[r] * 3 + ch] = dc[r];
      }
    }
    int dda[4] = {dv.x, dv.y, dv.z, dv.w};
#pragma unroll
    for (int r = 0; r < 4; r++) {
      float xa = fmaxf(ma[r] + unpk_hi(g.r2[r].x), 0.f);
      float xb = fmaxf(mb[r] + unpk_hi(g.r2[r].y), 0.f);
      if (dda[r] != cur) {
        atomicAdd(&acc[(size_t)cur * 32 + ch], va);
        atomicAdd(&acc[(size_t)cur * 32 + ch + 16], vb);
        va = 0.f; vb = 0.f; cur = dda[r];
      }
      va += xa; vb += xb;
    }
  }
  atomicAdd(&acc[(size_t)cur * 32 + ch], va);
  atomicAdd(&acc[(size_t)cur * 32 + ch + 16], vb);
}

// ==== final (fully coalesced): out[e] = ea[e] + partialE[e] + P2f[src[e]] + P3f[dst[e]] + b ====

__global__ __launch_bounds__(256) void k_fe4e(
    const float* __restrict__ partialE, const float* __restrict__ edge_attr,
    const int* __restrict__ src, const int* __restrict__ dstv,
    const float* __restrict__ P2f, const float* __restrict__ P3f,
    const float* __restrict__ be, float* __restrict__ out) {
  int e = blockIdx.x * blockDim.x + threadIdx.x;
  if (e >= NE) return;
  int s = src[e], d = dstv[e];
  out[(size_t)e * 3 + 0] = edge_attr[(size_t)e * 3 + 0] + partialE[(size_t)e * 3 + 0] + P2f[(size_t)s * 3 + 0] + P3f[(size_t)d * 3 + 0] + be[0];
  out[(size_t)e * 3 + 1] = edge_attr[(size_t)e * 3 + 1] + partialE[(size_t)e * 3 + 1] + P2f[(size_t)s * 3 + 1] + P3f[(size_t)d * 3 + 1] + be[1];
  out[(size_t)e * 3 + 2] = edge_attr[(size_t)e * 3 + 2] + partialE[(size_t)e * 3 + 2] + P2f[(size_t)s * 3 + 2] + P3f[(size_t)d * 3 + 2] + be[2];
}

// ============================ launch ============================

extern "C" void kernel_launch(void* const* d_in, const int* in_sizes, int n_in,
                              void* d_out, int out_size, void* d_ws, size_t ws_size,
                              hipStream_t stream) {
  const float* x = (const float*)d_in[0];
  const float* edge_attr = (const float*)d_in[1];
  const int* ei = (const int*)d_in[2];
  const int* src = ei;
  const int* dst = ei + NE;
  const float* w_enc_node_s = (const float*)d_in[3];
  const float* b_enc_node_s = (const float*)d_in[4];
  const float* w_enc_node_h = (const float*)d_in[5];
  const float* b_enc_node_h = (const float*)d_in[6];
  const float* w_enc_node_e = (const float*)d_in[7];
  const float* b_enc_node_e = (const float*)d_in[8];
  const float* w_enc_edge_s = (const float*)d_in[9];
  const float* b_enc_edge_s = (const float*)d_in[10];
  const float* w_enc_edge_h = (const float*)d_in[11];
  const float* b_enc_edge_h = (const float*)d_in[12];
  const float* w_enc_edge_e = (const float*)d_in[13];
  const float* b_enc_edge_e = (const float*)d_in[14];
  const float* w_node_s = (const float*)d_in[15];
  const float* w_node_h = (const float*)d_in[16];
  const float* w_node_e = (const float*)d_in[17];
  const float* w_edge_s = (const float*)d_in[18];
  const float* b_edge_s = (const float*)d_in[19];
  const float* w_edge_h = (const float*)d_in[20];
  const float* b_edge_h = (const float*)d_in[21];
  const float* w_edge_e = (const float*)d_in[22];
  const float* b_edge_e = (const float*)d_in[23];

  // workspace layout (~206 MB; 238 MB proven safe)
  char* w = (char*)d_ws;
  unsigned int* h_edge = (unsigned int*)w; w += (size_t)NE * 16 * 4;  // 102.4 MB
  int* src_p = (int*)w;       w += (size_t)NE * 4;            // 6.4
  int* dst_p = (int*)w;       w += (size_t)NE * 4;            // 6.4
  int* perm = (int*)w;        w += (size_t)NE * 4;            // 6.4
  int* slot = (int*)w;        w += (size_t)NE * 4;            // 6.4
  int4* sea = (int4*)w;       w += (size_t)NE * 16;           // 25.6 (aliased by partialE)
  uint2* ea2 = (uint2*)w;     w += (size_t)NE * 8;            // 12.8
  float* acc = (float*)w;     w += (size_t)NN * D * 4;        // 12.8
  uint2* R2b = (uint2*)w;     w += (size_t)NN * 16 * 8;       // 12.8
  unsigned* P3b = (unsigned*)w; w += (size_t)NN * 16 * 4;     // 6.4 (aliased by P2f/P3f)
  unsigned* Q0b = (unsigned*)w; w += (size_t)NN * 16 * 4;     // 6.4
  float* P2f = (float*)P3b;
  float* P3f = (float*)P3b + (size_t)NN * 3;
  int* cnt = (int*)w;         w += (size_t)NN * 4;
  float* inv_deg = (float*)w; w += (size_t)NN * 4;
  int* rowptr = (int*)w;      w += (size_t)(NN + 1) * 4;
  int* partial = (int*)w;     w += 4096;
  float* partialE = (float*)sea;  // alias: sea dead after k_fillB

  hipMemsetAsync(cnt, 0, (size_t)NN * 4, stream);
  hipMemsetAsync(acc, 0, (size_t)NN * D * 4, stream);

  k_deg<<<1024, 256, 0, stream>>>(dst, cnt, slot);
  k_pack<<<(NE + 255) / 256, 256, 0, stream>>>(src, edge_attr, sea);
  k_invdeg<<<(NN + 255) / 256, 256, 0, stream>>>(cnt, inv_deg);
  int nb = (NN + 1023) / 1024;  // 98
  k_scanA<<<nb, 1024, 0, stream>>>(cnt, rowptr, partial);
  k_scanB<<<1, 128, 0, stream>>>(partial, nb);
  k_scanC<<<nb, 1024, 0, stream>>>(rowptr, partial);
  k_expand<<<(NN + 255) / 256, 256, 0, stream>>>(rowptr, dst_p);
  k_fillA<<<2048, 256, 0, stream>>>(dst, slot, rowptr, perm);
  k_fillB<<<2048, 256, 0, stream>>>(perm, sea, src_p, ea2);

  k_node_enc_fin<<<1024, 256, 0, stream>>>(x, w_enc_node_s, b_enc_node_s,
                                           w_enc_node_h, b_enc_node_h,
                                           w_enc_node_e, b_enc_node_e,
                                           w_node_s, Q0b);

  int feb = NE / 256;  // 6250 blocks: 4 waves x 64 edges

  k_fe0_m<<<feb, 256, 0, stream>>>(ea2, Q0b, src_p, dst_p, acc,
                                   w_enc_edge_s, b_enc_edge_s,
                                   w_enc_edge_h, b_enc_edge_h,
                                   w_enc_edge_e, b_enc_edge_e,
                                   w_node_s, h_edge);
  k_fin<<<1024, 256, 0, stream>>>(acc, inv_deg, w_edge_s, w_node_h, R2b, P3b);
  k_fe_t<0><<<feb, 256, 0, stream>>>(h_edge, R2b, P3b, src_p, dst_p, acc,
                                     w_edge_s, b_edge_s, w_node_h, nullptr,
                                     nullptr, nullptr);
  k_fin<<<1024, 256, 0, stream>>>(acc, inv_deg, w_edge_h, w_node_h, R2b, P3b);
  k_fe_t<0><<<feb, 256, 0, stream>>>(h_edge, R2b, P3b, src_p, dst_p, acc,
                                     w_edge_h, b_edge_h, w_node_h, nullptr,
                                     nullptr, nullptr);
  k_fin<<<1024, 256, 0, stream>>>(acc, inv_deg, w_edge_h, w_node_e, R2b, P3b);
  k_fe_t<1><<<feb, 256, 0, stream>>>(h_edge, R2b, P3b, src_p, dst_p, acc,
                                     w_edge_h, b_edge_h, w_node_e, w_edge_e,
                                     perm, partialE);
  k_fin4<<<1024, 256, 0, stream>>>(acc, inv_deg, w_edge_e, P2f, P3f);
  k_fe4e<<<(NE + 255) / 256, 256, 0, stream>>>(partialE, edge_attr, src, dst,
                                               P2f, P3f, b_edge_e, (float*)d_out);
}

// Round 17
// 546.563 us; speedup vs baseline: 1.9496x; 1.0214x over previous
//
#include <hip/hip_runtime.h>

#define NN 100000
#define NE 1600000
#define D 32

typedef short short8 __attribute__((ext_vector_type(8)));
typedef float f32x4 __attribute__((ext_vector_type(4)));

union ABfrag { int4 i; short8 s; };

// ---------------- bf16 helpers ----------------

__device__ inline unsigned short f2b(float f) {
  unsigned int u = __float_as_uint(f);
  u = (u + 0x7FFFu + ((u >> 16) & 1u)) >> 16;
  return (unsigned short)u;
}
__device__ inline float b2f(unsigned short s) {
  return __uint_as_float(((unsigned int)s) << 16);
}
__device__ inline unsigned cvt_pk_bf16(float lo, float hi) {
  unsigned r;
  asm("v_cvt_pk_bf16_f32 %0, %1, %2" : "=v"(r) : "v"(lo), "v"(hi));
  return r;
}
__device__ inline void splitw(float w, unsigned short& h, unsigned short& l) {
  h = f2b(w);
  l = f2b(w - b2f(h));
}
__device__ inline float unpk_lo(unsigned u) { return b2f((unsigned short)(u & 0xFFFFu)); }
__device__ inline float unpk_hi(unsigned u) { return b2f((unsigned short)(u >> 16)); }

// XCD-aware bijective block swizzle (m204)
__device__ inline int xcd_swz(int bid, int nwg) {
  int q = nwg >> 3, r = nwg & 7;
  int xcd = bid & 7, j = bid >> 3;
  int base = (xcd < r) ? xcd * (q + 1) : r * (q + 1) + (xcd - r) * q;
  return base + j;
}

// ============================ CSR build ============================

// counting pass (atomic-latency bound) + FUSED coalesced pre-pack:
// slot[e] = rank within dst bucket; sea[e] = {src, pk(ea0,ea1), pk(ea2,0), 0}
__global__ void k_deg(const int* __restrict__ dst, const int* __restrict__ src,
                      const float* __restrict__ ea,
                      int* __restrict__ cnt, int* __restrict__ slot,
                      int4* __restrict__ sea) {
  int i = blockIdx.x * blockDim.x + threadIdx.x;
  int stride = gridDim.x * blockDim.x;
  for (int e = i; e < NE; e += stride) {
    int4 v;
    v.x = src[e];
    v.y = (int)cvt_pk_bf16(ea[(size_t)e * 3 + 0], ea[(size_t)e * 3 + 1]);
    v.z = (int)cvt_pk_bf16(ea[(size_t)e * 3 + 2], 0.f);
    v.w = 0;
    sea[e] = v;
    slot[e] = atomicAdd(&cnt[dst[e]], 1);
  }
}

__global__ __launch_bounds__(1024) void k_scanA(const int* __restrict__ cnt,
                                                int* __restrict__ rowptr,
                                                int* __restrict__ partial,
                                                float* __restrict__ inv_deg) {
  __shared__ int lds[1024];
  int t = threadIdx.x;
  int i = blockIdx.x * 1024 + t;
  int v = (i < NN) ? cnt[i] : 0;
  if (i < NN) inv_deg[i] = 1.0f / (float)max(v, 1);  // fused k_invdeg
  lds[t] = v;
  __syncthreads();
  for (int off = 1; off < 1024; off <<= 1) {
    int add = (t >= off) ? lds[t - off] : 0;
    __syncthreads();
    lds[t] += add;
    __syncthreads();
  }
  if (i < NN) rowptr[i] = lds[t] - v;
  if (t == 1023) partial[blockIdx.x] = lds[1023];
}

__global__ __launch_bounds__(128) void k_scanB(int* __restrict__ partial, int nb) {
  __shared__ int s[128];
  int t = threadIdx.x;
  int v = (t < nb) ? partial[t] : 0;
  s[t] = v;
  __syncthreads();
  for (int off = 1; off < 128; off <<= 1) {
    int add = (t >= off) ? s[t - off] : 0;
    __syncthreads();
    s[t] += add;
    __syncthreads();
  }
  if (t < nb) partial[t] = s[t] - v;  // exclusive
}

__global__ __launch_bounds__(1024) void k_scanC(int* __restrict__ rowptr,
                                                const int* __restrict__ partial) {
  int t = threadIdx.x;
  int i = blockIdx.x * 1024 + t;
  if (i < NN) rowptr[i] += partial[blockIdx.x];
  if (i == 0) rowptr[NN] = NE;
}

// dst_p needs NO gather: expand from rowptr
__global__ void k_expand(const int* __restrict__ rowptr, int* __restrict__ dst_p) {
  int v = blockIdx.x * blockDim.x + threadIdx.x;
  if (v >= NN) return;
  int b = rowptr[v], e = rowptr[v + 1];
  for (int p = b; p < e; p++) dst_p[p] = v;
}

// phase A (ATOMIC-FREE): p = rowptr[dst[e]] + slot[e]; scatter only perm (4B)
__global__ void k_fillA(const int* __restrict__ dst, const int* __restrict__ slot,
                        const int* __restrict__ rowptr, int* __restrict__ perm) {
  int i = blockIdx.x * blockDim.x + threadIdx.x;
  int stride = gridDim.x * blockDim.x;
  for (int e = i; e < NE; e += stride) {
    int p = rowptr[dst[e]] + slot[e];
    perm[p] = e;
  }
}

// phase B: ONE 16B gather per edge; coalesced writes
__global__ void k_fillB(const int* __restrict__ perm, const int4* __restrict__ sea,
                        int* __restrict__ src_p, uint2* __restrict__ ea2) {
  int i = blockIdx.x * blockDim.x + threadIdx.x;
  int stride = gridDim.x * blockDim.x;
  for (int p = i; p < NE; p += stride) {
    int4 v = sea[perm[p]];
    src_p[p] = v.x;
    ea2[p] = make_uint2((unsigned)v.y, (unsigned)v.z);
  }
}

// ============================ VALU dot helper (node kernels) ============================

template <int K4>
__device__ inline float dot_lds(const float* __restrict__ lv, const float* __restrict__ Wc) {
  float acc = 0.f;
  const float4* v4 = (const float4*)lv;
#pragma unroll
  for (int kk = 0; kk < K4; kk++) {
    float4 h = v4[kk];
    acc = fmaf(h.x, Wc[4 * kk + 0], acc);
    acc = fmaf(h.y, Wc[4 * kk + 1], acc);
    acc = fmaf(h.z, Wc[4 * kk + 2], acc);
    acc = fmaf(h.w, Wc[4 * kk + 3], acc);
  }
  return acc;
}

// ============ node encoder + Q0 projection (packed bf16 pairs) ============

__global__ __launch_bounds__(256) void k_node_enc_fin(
    const float* __restrict__ x,
    const float* __restrict__ ws, const float* __restrict__ bs,
    const float* __restrict__ wh, const float* __restrict__ bh,
    const float* __restrict__ we, const float* __restrict__ be,
    const float* __restrict__ Wn,  // w_node_s, rows 0..31
    unsigned* __restrict__ Q0b) {  // [NN*16]: pk(q_ch, q_ch+16)
  __shared__ float hrow[8][D];
  int t = threadIdx.x, j = t & 31, g = t >> 5;
  float Ws = ws[j], Bs = bs[j], Bh = bh[j], Be = be[j];
  float Wh[D], We_[D], Wq[D];
#pragma unroll
  for (int k = 0; k < D; k++) {
    Wh[k] = wh[k * D + j];
    We_[k] = we[k * D + j];
    Wq[k] = Wn[k * D + j];
  }
  for (int v = blockIdx.x * 8 + g; v < NN; v += gridDim.x * 8) {
    float h = fmaxf(fmaf(x[v], Ws, Bs), 0.f);
#pragma unroll
    for (int L = 0; L < 2; L++) {
      hrow[g][j] = h;
      h = fmaxf(dot_lds<8>(hrow[g], Wh) + Bh, 0.f);
    }
    hrow[g][j] = h;
    h = fmaxf(dot_lds<8>(hrow[g], We_) + Be, 0.f);
    hrow[g][j] = h;
    float q = dot_lds<8>(hrow[g], Wq);
    hrow[g][j] = q;  // wave-sync staging (dot complete for all lanes)
    if (j < 16) Q0b[(size_t)v * 16 + j] = cvt_pk_bf16(hrow[g][j], hrow[g][j + 16]);
  }
}

// ==== node finalize: h = acc/deg; project P2/Q and P3, packed bf16 ====

__global__ __launch_bounds__(256) void k_fin(
    float* __restrict__ acc, const float* __restrict__ inv_deg,
    const float* __restrict__ We,  // [96][32] NEXT edge layer (rows 32..95 used)
    const float* __restrict__ Wn,  // [64][32] NEXT node msg (rows 0..31 used)
    uint2* __restrict__ R2b,       // [NN*16]: {pk(p2lo,qlo), pk(p2hi,qhi)}
    unsigned* __restrict__ P3b) {  // [NN*16]: pk(p3lo,p3hi)
  __shared__ float hrow[8][D];
  __shared__ float st[8][3][D];
  int t = threadIdx.x, j = t & 31, g = t >> 5;
  float Wp2[D], Wp3[D], Wq[D];
#pragma unroll
  for (int k = 0; k < D; k++) {
    Wp2[k] = We[(32 + k) * D + j];
    Wp3[k] = We[(64 + k) * D + j];
    Wq[k] = Wn[k * D + j];
  }
  for (int v = blockIdx.x * 8 + g; v < NN; v += gridDim.x * 8) {
    float h = acc[(size_t)v * D + j] * inv_deg[v];
    acc[(size_t)v * D + j] = 0.f;
    hrow[g][j] = h;
    float p2 = dot_lds<8>(hrow[g], Wp2);
    float q = dot_lds<8>(hrow[g], Wq);
    float p3 = dot_lds<8>(hrow[g], Wp3);
    st[g][0][j] = p2; st[g][1][j] = q; st[g][2][j] = p3;
    if (j < 16) {
      R2b[(size_t)v * 16 + j] = make_uint2(cvt_pk_bf16(st[g][0][j], st[g][1][j]),
                                           cvt_pk_bf16(st[g][0][j + 16], st[g][1][j + 16]));
      P3b[(size_t)v * 16 + j] = cvt_pk_bf16(st[g][2][j], st[g][2][j + 16]);
    }
  }
}

// ==== final node finalize: P2f/P3f [NN,3] ====

__global__ __launch_bounds__(256) void k_fin4(
    float* __restrict__ acc, const float* __restrict__ inv_deg,
    const float* __restrict__ We,  // w_edge_e [96][3]
    float* __restrict__ P2f, float* __restrict__ P3f) {
  __shared__ float hrow[8][D];
  int t = threadIdx.x, j = t & 31, g = t >> 5;
  for (int v = blockIdx.x * 8 + g; v < NN; v += gridDim.x * 8) {
    float h = acc[(size_t)v * D + j] * inv_deg[v];
    hrow[g][j] = h;
    if (j < 6) {
      int c = j % 3;
      int off = (j < 3) ? 32 : 64;
      float s = 0.f;
#pragma unroll
      for (int k = 0; k < D; k++) s = fmaf(hrow[g][k], We[(off + k) * 3 + c], s);
      if (j < 3) P2f[(size_t)v * 3 + c] = s;
      else       P3f[(size_t)v * 3 + c] = s;
    }
  }
}

// ============================ MFMA helpers ============================
// D layout (mfma_f32_16x16x32_bf16): col = lane&15, row = (lane>>4)*4 + reg
// A layout: row = lane&15, k = (lane>>4)*8 + i ;  B layout: col = lane&15, k = (lane>>4)*8 + i
// h_edge stores channels interleaved: position 2*c+h <-> channel c + 16*h (c=0..15)
// Stripe mapping: tile t, row i  <->  edge p0 + (i>>2)*16 + t*4 + (i&3)

__device__ inline void ep_xpose_write(float* __restrict__ xw, f32x4 da, f32x4 db,
                                      float ba, float bb, int cl, int ch) {
#pragma unroll
  for (int r = 0; r < 4; r++) {
    xw[(cl * 4 + r) * 36 + ch] = fmaxf(da[r] + ba, 0.f);
    xw[(cl * 4 + r) * 36 + ch + 16] = fmaxf(db[r] + bb, 0.f);
  }
}

__device__ inline ABfrag xpose_read(const float* __restrict__ xw, int lane) {
  const float4* p = (const float4*)(xw + (lane & 15) * 36 + (lane >> 4) * 8);
  float4 v0 = p[0], v1 = p[1];
  ABfrag A;
  A.i = make_int4(cvt_pk_bf16(v0.x, v0.y), cvt_pk_bf16(v0.z, v0.w),
                  cvt_pk_bf16(v1.x, v1.y), cvt_pk_bf16(v1.z, v1.w));
  return A;
}

// gather bundle for one 16-edge tile (packed bf16 node rows)
struct G8 { uint2 r2[4]; unsigned p3[4]; };

__device__ inline void gath(G8& g, const uint2* __restrict__ R2b,
                            const unsigned* __restrict__ P3b, int4 sv, int4 dv, int ch) {
  int sa[4] = {sv.x, sv.y, sv.z, sv.w};
  int da[4] = {dv.x, dv.y, dv.z, dv.w};
#pragma unroll
  for (int r = 0; r < 4; r++) {
    g.r2[r] = R2b[(size_t)sa[r] * 16 + ch];
    g.p3[r] = P3b[(size_t)da[r] * 16 + ch];
  }
}

// ==== MFMA fused: edge encoder + first message + scatter (layer-major, striped) ====

__global__ __launch_bounds__(256) void k_fe0_m(
    const uint2* __restrict__ ea2, const unsigned* __restrict__ Q0b,
    const int* __restrict__ src_p, const int* __restrict__ dst_p,
    float* __restrict__ acc,
    const float* __restrict__ ws, const float* __restrict__ bs,
    const float* __restrict__ wh, const float* __restrict__ bh,
    const float* __restrict__ we, const float* __restrict__ be,
    const float* __restrict__ Wn,  // w_node_s rows 32..63
    unsigned int* __restrict__ h_edge) {  // packed interleaved bf16 pairs
  __shared__ float xp[4][4][16 * 36];
  int lane = threadIdx.x & 63, wid = threadIdx.x >> 6;
  int cl = lane >> 4, ch = lane & 15;
  unsigned wp01[8], wp2b[8];
#pragma unroll
  for (int kk = 0; kk < 8; kk++) {
    int c = cl * 8 + kk;
    wp01[kk] = ((unsigned)f2b(ws[32 + c]) << 16) | f2b(ws[c]);
    wp2b[kk] = ((unsigned)f2b(bs[c]) << 16) | f2b(ws[64 + c]);
  }
  ABfrag wha, whb, wea, web, w2a, w2b;
#pragma unroll
  for (int kk = 0; kk < 8; kk++) {
    int k = cl * 8 + kk;
    wha.s[kk] = (short)f2b(wh[k * 32 + ch]);
    whb.s[kk] = (short)f2b(wh[k * 32 + ch + 16]);
    wea.s[kk] = (short)f2b(we[k * 32 + ch]);
    web.s[kk] = (short)f2b(we[k * 32 + ch + 16]);
    w2a.s[kk] = (short)f2b(Wn[(32 + k) * 32 + ch]);
    w2b.s[kk] = (short)f2b(Wn[(32 + k) * 32 + ch + 16]);
  }
  float bha = bh[ch], bhb = bh[ch + 16], bea = be[ch], beb = be[ch + 16];
  int blk = xcd_swz(blockIdx.x, gridDim.x);
  int p0 = (blk * 4 + wid) * 64;
  f32x4 z = {0.f, 0.f, 0.f, 0.f};
  int echA = ((ch >> 2) << 4) + (ch & 3);
  uint2 av[4];
#pragma unroll
  for (int t = 0; t < 4; t++) av[t] = ea2[p0 + echA + t * 4];
  ABfrag A[4];
#pragma unroll
  for (int t = 0; t < 4; t++) {
    float a0 = unpk_lo(av[t].x), a1 = unpk_hi(av[t].x), a2 = unpk_lo(av[t].y);
    float h1[8];
#pragma unroll
    for (int kk = 0; kk < 8; kk++) {
      float w0 = unpk_lo(wp01[kk]), w1 = unpk_hi(wp01[kk]);
      float w2 = unpk_lo(wp2b[kk]), bb = unpk_hi(wp2b[kk]);
      h1[kk] = fmaxf(fmaf(a0, w0, fmaf(a1, w1, fmaf(a2, w2, bb))), 0.f);
    }
    A[t].i = make_int4(cvt_pk_bf16(h1[0], h1[1]), cvt_pk_bf16(h1[2], h1[3]),
                       cvt_pk_bf16(h1[4], h1[5]), cvt_pk_bf16(h1[6], h1[7]));
  }
#pragma unroll
  for (int t = 0; t < 4; t++) {
    f32x4 da = __builtin_amdgcn_mfma_f32_16x16x32_bf16(A[t].s, wha.s, z, 0, 0, 0);
    f32x4 db = __builtin_amdgcn_mfma_f32_16x16x32_bf16(A[t].s, whb.s, z, 0, 0, 0);
    ep_xpose_write(xp[wid][t], da, db, bha, bhb, cl, ch);
  }
#pragma unroll
  for (int t = 0; t < 4; t++) A[t] = xpose_read(xp[wid][t], lane);
#pragma unroll
  for (int t = 0; t < 4; t++) {
    f32x4 da = __builtin_amdgcn_mfma_f32_16x16x32_bf16(A[t].s, wha.s, z, 0, 0, 0);
    f32x4 db = __builtin_amdgcn_mfma_f32_16x16x32_bf16(A[t].s, whb.s, z, 0, 0, 0);
    ep_xpose_write(xp[wid][t], da, db, bha, bhb, cl, ch);
  }
#pragma unroll
  for (int t = 0; t < 4; t++) A[t] = xpose_read(xp[wid][t], lane);
  int4 dv[4];
  unsigned qg[4][4];
#pragma unroll
  for (int t = 0; t < 4; t++) {
    int base = p0 + cl * 16 + t * 4;
    int4 sv = *(const int4*)(src_p + base);
    dv[t] = *(const int4*)(dst_p + base);
    int sa[4] = {sv.x, sv.y, sv.z, sv.w};
#pragma unroll
    for (int r = 0; r < 4; r++) qg[t][r] = Q0b[(size_t)sa[r] * 16 + ch];
  }
#pragma unroll
  for (int t = 0; t < 4; t++) {
    f32x4 da = __builtin_amdgcn_mfma_f32_16x16x32_bf16(A[t].s, wea.s, z, 0, 0, 0);
    f32x4 db = __builtin_amdgcn_mfma_f32_16x16x32_bf16(A[t].s, web.s, z, 0, 0, 0);
#pragma unroll
    for (int r = 0; r < 4; r++) {
      float h0 = fmaxf(da[r] + bea, 0.f);
      float hv = fmaxf(db[r] + beb, 0.f);
      int p = p0 + cl * 16 + t * 4 + r;
      h_edge[(size_t)p * 16 + ch] = cvt_pk_bf16(h0, hv);
      xp[wid][t][(cl * 4 + r) * 36 + ch] = h0;
      xp[wid][t][(cl * 4 + r) * 36 + ch + 16] = hv;
    }
  }
#pragma unroll
  for (int t = 0; t < 4; t++) A[t] = xpose_read(xp[wid][t], lane);
  float va = 0.f, vb = 0.f;
  int cur = dv[0].x;
#pragma unroll
  for (int t = 0; t < 4; t++) {
    f32x4 ma = __builtin_amdgcn_mfma_f32_16x16x32_bf16(A[t].s, w2a.s, z, 0, 0, 0);
    f32x4 mb = __builtin_amdgcn_mfma_f32_16x16x32_bf16(A[t].s, w2b.s, z, 0, 0, 0);
    int dda[4] = {dv[t].x, dv[t].y, dv[t].z, dv[t].w};
#pragma unroll
    for (int r = 0; r < 4; r++) {
      float xa = fmaxf(ma[r] + unpk_lo(qg[t][r]), 0.f);
      float xb = fmaxf(mb[r] + unpk_hi(qg[t][r]), 0.f);
      if (dda[r] != cur) {
        atomicAdd(&acc[(size_t)cur * 32 + ch], va);
        atomicAdd(&acc[(size_t)cur * 32 + ch + 16], vb);
        va = 0.f; vb = 0.f; cur = dda[r];
      }
      va += xa; vb += xb;
    }
  }
  atomicAdd(&acc[(size_t)cur * 32 + ch], va);
  atomicAdd(&acc[(size_t)cur * 32 + ch + 16], vb);
}

// ==== MFMA fused: edge update + message + scatter (striped) ====
// LAST=1: partialE written in ORIGINAL edge order via perm (k_fe4e then fully coalesced)

template <int LAST>
__global__ __launch_bounds__(256) void k_fe_t(
    unsigned int* __restrict__ h_edge, const uint2* __restrict__ R2b,
    const unsigned* __restrict__ P3b, const int* __restrict__ src_p,
    const int* __restrict__ dst_p, float* __restrict__ acc,
    const float* __restrict__ We, const float* __restrict__ be,
    const float* __restrict__ Wn, const float* __restrict__ We3,
    const int* __restrict__ perm, float* __restrict__ partialE) {
  __shared__ float xp[4][16 * 36];
  int lane = threadIdx.x & 63, wid = threadIdx.x >> 6;
  int cl = lane >> 4, ch = lane & 15;
  ABfrag b1a, b1b, b2a, b2b, w3h, w3l;
#pragma unroll
  for (int kk = 0; kk < 8; kk++) {
    int k = cl * 8 + kk;
    int kp = cl * 4 + (kk >> 1) + (kk & 1) * 16;  // interleaved h_edge k-perm
    b1a.s[kk] = (short)f2b(We[kp * 32 + ch]);
    b1b.s[kk] = (short)f2b(We[kp * 32 + ch + 16]);
    b2a.s[kk] = (short)f2b(Wn[(32 + k) * 32 + ch]);
    b2b.s[kk] = (short)f2b(Wn[(32 + k) * 32 + ch + 16]);
    if (LAST) {
      unsigned short hi_, lo_;
      float v = (ch < 3) ? We3[k * 3 + ch] : 0.f;
      splitw(v, hi_, lo_); w3h.s[kk] = (short)hi_; w3l.s[kk] = (short)lo_;
    }
  }
  float bea = be[ch], beb = be[ch + 16];
  int blk = xcd_swz(blockIdx.x, gridDim.x);
  int p0 = (blk * 4 + wid) * 64;
  f32x4 z = {0.f, 0.f, 0.f, 0.f};
  float* xw = xp[wid];
  int echA = ((ch >> 2) << 4) + (ch & 3);
  float va = 0.f, vb = 0.f;
  int cur = dst_p[p0 + cl * 16];
#pragma unroll
  for (int t = 0; t < 4; ++t) {
    int base = p0 + cl * 16 + t * 4;
    ABfrag A;
    A.i = *(const int4*)(h_edge + (size_t)(p0 + echA + t * 4) * 16 + cl * 4);
    int4 sv = *(const int4*)(src_p + base);
    int4 dv = *(const int4*)(dst_p + base);
    G8 g;
    gath(g, R2b, P3b, sv, dv, ch);
    f32x4 da = __builtin_amdgcn_mfma_f32_16x16x32_bf16(A.s, b1a.s, z, 0, 0, 0);
    f32x4 db = __builtin_amdgcn_mfma_f32_16x16x32_bf16(A.s, b1b.s, z, 0, 0, 0);
#pragma unroll
    for (int r = 0; r < 4; r++) {
      float h0 = fmaxf(da[r] + unpk_lo(g.r2[r].x) + unpk_lo(g.p3[r]) + bea, 0.f);
      float hv = fmaxf(db[r] + unpk_lo(g.r2[r].y) + unpk_hi(g.p3[r]) + beb, 0.f);
      int p = base + r;
      if (!LAST) h_edge[(size_t)p * 16 + ch] = cvt_pk_bf16(h0, hv);
      xw[(cl * 4 + r) * 36 + ch] = h0;
      xw[(cl * 4 + r) * 36 + ch + 16] = hv;
    }
    ABfrag A2 = xpose_read(xw, lane);
    f32x4 ma = __builtin_amdgcn_mfma_f32_16x16x32_bf16(A2.s, b2a.s, z, 0, 0, 0);
    f32x4 mb = __builtin_amdgcn_mfma_f32_16x16x32_bf16(A2.s, b2b.s, z, 0, 0, 0);
    if (LAST) {
      f32x4 dc = __builtin_amdgcn_mfma_f32_16x16x32_bf16(A2.s, w3l.s, z, 0, 0, 0);
      dc = __builtin_amdgcn_mfma_f32_16x16x32_bf16(A2.s, w3h.s, dc, 0, 0, 0);
      int4 pv = *(const int4*)(perm + base);
      int eo[4] = {pv.x, pv.y, pv.z, pv.w};
      if (ch < 3) {
#pragma unroll
        for (int r = 0; r < 4; r++)
          partialE[(size_t)eo[r] * 3 + ch] = dc[r];
      }
    }
    int dda[4] = {dv.x, dv.y, dv.z, dv.w};
#pragma unroll
    for (int r = 0; r < 4; r++) {
      float xa = fmaxf(ma[r] + unpk_hi(g.r2[r].x), 0.f);
      float xb = fmaxf(mb[r] + unpk_hi(g.r2[r].y), 0.f);
      if (dda[r] != cur) {
        atomicAdd(&acc[(size_t)cur * 32 + ch], va);
        atomicAdd(&acc[(size_t)cur * 32 + ch + 16], vb);
        va = 0.f; vb = 0.f; cur = dda[r];
      }
      va += xa; vb += xb;
    }
  }
  atomicAdd(&acc[(size_t)cur * 32 + ch], va);
  atomicAdd(&acc[(size_t)cur * 32 + ch + 16], vb);
}

// ==== final (fully coalesced): out[e] = ea[e] + partialE[e] + P2f[src[e]] + P3f[dst[e]] + b ====

__global__ __launch_bounds__(256) void k_fe4e(
    const float* __restrict__ partialE, const float* __restrict__ edge_attr,
    const int* __restrict__ src, const int* __restrict__ dstv,
    const float* __restrict__ P2f, const float* __restrict__ P3f,
    const float* __restrict__ be, float* __restrict__ out) {
  int e = blockIdx.x * blockDim.x + threadIdx.x;
  if (e >= NE) return;
  int s = src[e], d = dstv[e];
  out[(size_t)e * 3 + 0] = edge_attr[(size_t)e * 3 + 0] + partialE[(size_t)e * 3 + 0] + P2f[(size_t)s * 3 + 0] + P3f[(size_t)d * 3 + 0] + be[0];
  out[(size_t)e * 3 + 1] = edge_attr[(size_t)e * 3 + 1] + partialE[(size_t)e * 3 + 1] + P2f[(size_t)s * 3 + 1] + P3f[(size_t)d * 3 + 1] + be[1];
  out[(size_t)e * 3 + 2] = edge_attr[(size_t)e * 3 + 2] + partialE[(size_t)e * 3 + 2] + P2f[(size_t)s * 3 + 2] + P3f[(size_t)d * 3 + 2] + be[2];
}

// ============================ launch ============================

extern "C" void kernel_launch(void* const* d_in, const int* in_sizes, int n_in,
                              void* d_out, int out_size, void* d_ws, size_t ws_size,
                              hipStream_t stream) {
  const float* x = (const float*)d_in[0];
  const float* edge_attr = (const float*)d_in[1];
  const int* ei = (const int*)d_in[2];
  const int* src = ei;
  const int* dst = ei + NE;
  const float* w_enc_node_s = (const float*)d_in[3];
  const float* b_enc_node_s = (const float*)d_in[4];
  const float* w_enc_node_h = (const float*)d_in[5];
  const float* b_enc_node_h = (const float*)d_in[6];
  const float* w_enc_node_e = (const float*)d_in[7];
  const float* b_enc_node_e = (const float*)d_in[8];
  const float* w_enc_edge_s = (const float*)d_in[9];
  const float* b_enc_edge_s = (const float*)d_in[10];
  const float* w_enc_edge_h = (const float*)d_in[11];
  const float* b_enc_edge_h = (const float*)d_in[12];
  const float* w_enc_edge_e = (const float*)d_in[13];
  const float* b_enc_edge_e = (const float*)d_in[14];
  const float* w_node_s = (const float*)d_in[15];
  const float* w_node_h = (const float*)d_in[16];
  const float* w_node_e = (const float*)d_in[17];
  const float* w_edge_s = (const float*)d_in[18];
  const float* b_edge_s = (const float*)d_in[19];
  const float* w_edge_h = (const float*)d_in[20];
  const float* b_edge_h = (const float*)d_in[21];
  const float* w_edge_e = (const float*)d_in[22];
  const float* b_edge_e = (const float*)d_in[23];

  // workspace layout (~206 MB; 238 MB proven safe)
  char* w = (char*)d_ws;
  unsigned int* h_edge = (unsigned int*)w; w += (size_t)NE * 16 * 4;  // 102.4 MB
  int* src_p = (int*)w;       w += (size_t)NE * 4;            // 6.4
  int* dst_p = (int*)w;       w += (size_t)NE * 4;            // 6.4
  int* perm = (int*)w;        w += (size_t)NE * 4;            // 6.4
  int* slot = (int*)w;        w += (size_t)NE * 4;            // 6.4
  int4* sea = (int4*)w;       w += (size_t)NE * 16;           // 25.6 (aliased by partialE)
  uint2* ea2 = (uint2*)w;     w += (size_t)NE * 8;            // 12.8
  float* acc = (float*)w;     w += (size_t)NN * D * 4;        // 12.8
  uint2* R2b = (uint2*)w;     w += (size_t)NN * 16 * 8;       // 12.8
  unsigned* P3b = (unsigned*)w; w += (size_t)NN * 16 * 4;     // 6.4 (aliased by P2f/P3f)
  unsigned* Q0b = (unsigned*)w; w += (size_t)NN * 16 * 4;     // 6.4
  float* P2f = (float*)P3b;
  float* P3f = (float*)P3b + (size_t)NN * 3;
  int* cnt = (int*)w;         w += (size_t)NN * 4;
  float* inv_deg = (float*)w; w += (size_t)NN * 4;
  int* rowptr = (int*)w;      w += (size_t)(NN + 1) * 4;
  int* partial = (int*)w;     w += 4096;
  float* partialE = (float*)sea;  // alias: sea dead after k_fillB

  hipMemsetAsync(cnt, 0, (size_t)NN * 4, stream);
  hipMemsetAsync(acc, 0, (size_t)NN * D * 4, stream);

  // fused histogram + pre-pack (atomic latency hidden under coalesced pack I/O)
  k_deg<<<2048, 256, 0, stream>>>(dst, src, edge_attr, cnt, slot, sea);
  int nb = (NN + 1023) / 1024;  // 98
  k_scanA<<<nb, 1024, 0, stream>>>(cnt, rowptr, partial, inv_deg);  // + fused invdeg
  k_scanB<<<1, 128, 0, stream>>>(partial, nb);
  k_scanC<<<nb, 1024, 0, stream>>>(rowptr, partial);
  k_expand<<<(NN + 255) / 256, 256, 0, stream>>>(rowptr, dst_p);
  k_fillA<<<2048, 256, 0, stream>>>(dst, slot, rowptr, perm);
  k_fillB<<<2048, 256, 0, stream>>>(perm, sea, src_p, ea2);

  k_node_enc_fin<<<1024, 256, 0, stream>>>(x, w_enc_node_s, b_enc_node_s,
                                           w_enc_node_h, b_enc_node_h,
                                           w_enc_node_e, b_enc_node_e,
                                           w_node_s, Q0b);

  int feb = NE / 256;  // 6250 blocks: 4 waves x 64 edges

  k_fe0_m<<<feb, 256, 0, stream>>>(ea2, Q0b, src_p, dst_p, acc,
                                   w_enc_edge_s, b_enc_edge_s,
                                   w_enc_edge_h, b_enc_edge_h,
                                   w_enc_edge_e, b_enc_edge_e,
                                   w_node_s, h_edge);
  k_fin<<<1024, 256, 0, stream>>>(acc, inv_deg, w_edge_s, w_node_h, R2b, P3b);
  k_fe_t<0><<<feb, 256, 0, stream>>>(h_edge, R2b, P3b, src_p, dst_p, acc,
                                     w_edge_s, b_edge_s, w_node_h, nullptr,
                                     nullptr, nullptr);
  k_fin<<<1024, 256, 0, stream>>>(acc, inv_deg, w_edge_h, w_node_h, R2b, P3b);
  k_fe_t<0><<<feb, 256, 0, stream>>>(h_edge, R2b, P3b, src_p, dst_p, acc,
                                     w_edge_h, b_edge_h, w_node_h, nullptr,
                                     nullptr, nullptr);
  k_fin<<<1024, 256, 0, stream>>>(acc, inv_deg, w_edge_h, w_node_e, R2b, P3b);
  k_fe_t<1><<<feb, 256, 0, stream>>>(h_edge, R2b, P3b, src_p, dst_p, acc,
                                     w_edge_h, b_edge_h, w_node_e, w_edge_e,
                                     perm, partialE);
  k_fin4<<<1024, 256, 0, stream>>>(acc, inv_deg, w_edge_e, P2f, P3f);
  k_fe4e<<<(NE + 255) / 256, 256, 0, stream>>>(partialE, edge_attr, src, dst,
                                               P2f, P3f, b_edge_e, (float*)d_out);
}